// Round 1
// baseline (2018.864 us; speedup 1.0000x reference)
//
#include <hip/hip_runtime.h>
#include <math.h>

#define N_NODES 50000
#define DIM 256
#define NE 300000
#define NEV 100000

// ---------------------------------------------------------------------------
// scatter: buf[dst] += relu(x[src] + ea[e]); one wave (64 lanes) per edge,
// each lane owns 4 consecutive floats (float4 loads, 4 scalar atomics).
// ---------------------------------------------------------------------------
__global__ __launch_bounds__(256) void scatter_kernel(
    const float* __restrict__ x, const float* __restrict__ ea,
    const int* __restrict__ idx, int E, float* __restrict__ buf)
{
    int wid = blockIdx.x * (blockDim.x >> 6) + (threadIdx.x >> 6);
    int lane = threadIdx.x & 63;
    if (wid >= E) return;
    int s = idx[wid];       // src row
    int d = idx[E + wid];   // dst row
    const float4* xs = (const float4*)(x + (size_t)s * DIM);
    const float4* es = (const float4*)(ea + (size_t)wid * DIM);
    float4 a = xs[lane];
    float4 b = es[lane];
    float4 m;
    m.x = fmaxf(a.x + b.x, 0.0f);
    m.y = fmaxf(a.y + b.y, 0.0f);
    m.z = fmaxf(a.z + b.z, 0.0f);
    m.w = fmaxf(a.w + b.w, 0.0f);
    float* dst = buf + (size_t)d * DIM + lane * 4;
    atomicAdd(dst + 0, m.x);
    atomicAdd(dst + 1, m.y);
    atomicAdd(dst + 2, m.z);
    atomicAdd(dst + 3, m.w);
}

// ---------------------------------------------------------------------------
// GEMM stage 1: t1 = ((1+eps)*x + aggr) @ W1 + b1
// Block computes a 32-row x 256-col stripe (full width -> in-place t1 over
// aggr is safe: all A reads of the block's rows complete before any store,
// and no other block touches those rows).
// BM=32, BN=256 (full), BK=16; 256 threads; 4x8 acc per thread; cols strided
// (col = j*32 + tx) for conflict-free LDS reads & coalesced stores.
// ---------------------------------------------------------------------------
__global__ __launch_bounds__(256) void gemm_stage1(
    const float* __restrict__ x, const float* __restrict__ aggr,
    const float* __restrict__ W, const float* __restrict__ bias,
    const float* __restrict__ eps_p, float* __restrict__ out)
{
    __shared__ float As[16][36];
    __shared__ float Ws[16][256];
    int t = threadIdx.x;
    int tx = t & 31, ty = t >> 5;
    int row0 = blockIdx.x * 32;
    float epsv = 1.0f + eps_p[0];
    float acc[4][8];
    #pragma unroll
    for (int i = 0; i < 4; i++)
        #pragma unroll
        for (int j = 0; j < 8; j++) acc[i][j] = 0.0f;

    int arow = t >> 3, ag = t & 7;   // A-tile load mapping: 32 rows x (8 thr * 2 k)
    for (int k0 = 0; k0 < DIM; k0 += 16) {
        int gr = row0 + arow;
        float2 av = make_float2(0.0f, 0.0f);
        if (gr < N_NODES) {
            size_t base = (size_t)gr * DIM + k0 + ag * 2;
            float2 xv = *(const float2*)(x + base);
            float2 bv = *(const float2*)(aggr + base);
            av.x = epsv * xv.x + bv.x;
            av.y = epsv * xv.y + bv.y;
        }
        As[ag * 2 + 0][arow] = av.x;
        As[ag * 2 + 1][arow] = av.y;
        const float4* wg = (const float4*)(W + (size_t)k0 * DIM);
        float4* wsv = (float4*)(&Ws[0][0]);
        #pragma unroll
        for (int r = 0; r < 4; r++) wsv[t + 256 * r] = wg[t + 256 * r];
        __syncthreads();
        #pragma unroll
        for (int kk = 0; kk < 16; kk++) {
            float a[4], w[8];
            #pragma unroll
            for (int i = 0; i < 4; i++) a[i] = As[kk][ty * 4 + i];
            #pragma unroll
            for (int j = 0; j < 8; j++) w[j] = Ws[kk][j * 32 + tx];
            #pragma unroll
            for (int i = 0; i < 4; i++)
                #pragma unroll
                for (int j = 0; j < 8; j++) acc[i][j] += a[i] * w[j];
        }
        __syncthreads();
    }
    #pragma unroll
    for (int j = 0; j < 8; j++) {
        int col = j * 32 + tx;
        float bv = bias[col];
        #pragma unroll
        for (int i = 0; i < 4; i++) {
            int r = row0 + ty * 4 + i;
            if (r < N_NODES) out[(size_t)r * DIM + col] = acc[i][j] + bv;
        }
    }
}

// ---------------------------------------------------------------------------
// GEMM stage 2: C = relu(t1*scale + shift) @ W2 + b2; out = base + alpha*C
// Same tiling as stage 1; BN+ReLU fused into the A-operand load.
// ---------------------------------------------------------------------------
__global__ __launch_bounds__(256) void gemm_stage2(
    const float* __restrict__ t1, const float* __restrict__ scale,
    const float* __restrict__ shift, const float* __restrict__ W,
    const float* __restrict__ bias, const float* __restrict__ base,
    const float* __restrict__ alpha_p, float* __restrict__ out)
{
    __shared__ float As[16][36];
    __shared__ float Ws[16][256];
    int t = threadIdx.x;
    int tx = t & 31, ty = t >> 5;
    int row0 = blockIdx.x * 32;
    float acc[4][8];
    #pragma unroll
    for (int i = 0; i < 4; i++)
        #pragma unroll
        for (int j = 0; j < 8; j++) acc[i][j] = 0.0f;

    int arow = t >> 3, ag = t & 7;
    for (int k0 = 0; k0 < DIM; k0 += 16) {
        int gr = row0 + arow;
        float2 av = make_float2(0.0f, 0.0f);
        if (gr < N_NODES) {
            size_t basei = (size_t)gr * DIM + k0 + ag * 2;
            float2 tv = *(const float2*)(t1 + basei);
            float2 sc = *(const float2*)(scale + k0 + ag * 2);
            float2 sh = *(const float2*)(shift + k0 + ag * 2);
            av.x = fmaxf(tv.x * sc.x + sh.x, 0.0f);
            av.y = fmaxf(tv.y * sc.y + sh.y, 0.0f);
        }
        As[ag * 2 + 0][arow] = av.x;
        As[ag * 2 + 1][arow] = av.y;
        const float4* wg = (const float4*)(W + (size_t)k0 * DIM);
        float4* wsv = (float4*)(&Ws[0][0]);
        #pragma unroll
        for (int r = 0; r < 4; r++) wsv[t + 256 * r] = wg[t + 256 * r];
        __syncthreads();
        #pragma unroll
        for (int kk = 0; kk < 16; kk++) {
            float a[4], w[8];
            #pragma unroll
            for (int i = 0; i < 4; i++) a[i] = As[kk][ty * 4 + i];
            #pragma unroll
            for (int j = 0; j < 8; j++) w[j] = Ws[kk][j * 32 + tx];
            #pragma unroll
            for (int i = 0; i < 4; i++)
                #pragma unroll
                for (int j = 0; j < 8; j++) acc[i][j] += a[i] * w[j];
        }
        __syncthreads();
    }
    float alphav = alpha_p[0];
    #pragma unroll
    for (int j = 0; j < 8; j++) {
        int col = j * 32 + tx;
        float bv = bias[col];
        #pragma unroll
        for (int i = 0; i < 4; i++) {
            int r = row0 + ty * 4 + i;
            if (r < N_NODES) {
                size_t o = (size_t)r * DIM + col;
                out[o] = base[o] + alphav * (acc[i][j] + bv);
            }
        }
    }
}

// ---------------------------------------------------------------------------
// column stats: ssum[c] += sum_r src[r][c]; ssq[c] += sum_r src[r][c]^2
// 256 threads = 1 thread per column; blocks stride rows; coalesced.
// ---------------------------------------------------------------------------
__global__ __launch_bounds__(256) void colstats_kernel(
    const float* __restrict__ src, float* __restrict__ ssum, float* __restrict__ ssq)
{
    int c = threadIdx.x;
    float s = 0.0f, q = 0.0f;
    for (int r = blockIdx.x; r < N_NODES; r += gridDim.x) {
        float v = src[(size_t)r * DIM + c];
        s += v; q += v * v;
    }
    atomicAdd(&ssum[c], s);
    atomicAdd(&ssq[c], q);
}

// scale[c] = g[c]*rsqrt(var+eps); shift[c] = b[c] - mu*scale[c]
__global__ void finalize_kernel(
    const float* __restrict__ ssum, const float* __restrict__ ssq,
    const float* __restrict__ g, const float* __restrict__ b,
    float* __restrict__ scale, float* __restrict__ shift)
{
    int c = threadIdx.x;
    const float invN = 1.0f / (float)N_NODES;
    float mu = ssum[c] * invN;
    float var = ssq[c] * invN - mu * mu;
    float sc = g[c] * rsqrtf(var + 1e-5f);
    scale[c] = sc;
    shift[c] = b[c] - mu * sc;
}

// out = relu(out*scale + shift), elementwise in place (float4)
__global__ __launch_bounds__(256) void bnrelu_kernel(
    float* __restrict__ out, const float* __restrict__ scale,
    const float* __restrict__ shift)
{
    int idx = blockIdx.x * blockDim.x + threadIdx.x;
    const int total = N_NODES * (DIM / 4);
    for (int f = idx; f < total; f += gridDim.x * blockDim.x) {
        float4 v = ((float4*)out)[f];
        int c = (f * 4) & (DIM - 1);
        float4 sc = *(const float4*)(scale + c);
        float4 sh = *(const float4*)(shift + c);
        v.x = fmaxf(v.x * sc.x + sh.x, 0.0f);
        v.y = fmaxf(v.y * sc.y + sh.y, 0.0f);
        v.z = fmaxf(v.z * sc.z + sh.z, 0.0f);
        v.w = fmaxf(v.w * sc.w + sh.w, 0.0f);
        ((float4*)out)[f] = v;
    }
}

extern "C" void kernel_launch(void* const* d_in, const int* in_sizes, int n_in,
                              void* d_out, int out_size, void* d_ws, size_t ws_size,
                              hipStream_t stream)
{
    const float* x    = (const float*)d_in[0];
    const int*   ei   = (const int*)  d_in[1];
    const float* ea   = (const float*)d_in[2];
    const int*   vi   = (const int*)  d_in[3];
    const float* vea  = (const float*)d_in[4];
    const float* epsd = (const float*)d_in[5];
    const float* W1d  = (const float*)d_in[6];
    const float* b1d  = (const float*)d_in[7];
    const float* g1d  = (const float*)d_in[8];
    const float* bt1d = (const float*)d_in[9];
    const float* W2d  = (const float*)d_in[10];
    const float* b2d  = (const float*)d_in[11];
    const float* epsu = (const float*)d_in[12];
    const float* W1u  = (const float*)d_in[13];
    const float* b1u  = (const float*)d_in[14];
    const float* g1u  = (const float*)d_in[15];
    const float* bt1u = (const float*)d_in[16];
    const float* W2u  = (const float*)d_in[17];
    const float* b2u  = (const float*)d_in[18];
    const float* bng  = (const float*)d_in[19];
    const float* bnb  = (const float*)d_in[20];
    const float* a1   = (const float*)d_in[21];
    const float* a2   = (const float*)d_in[22];

    float* out = (float*)d_out;
    float* buf = (float*)d_ws;                       // [N, D] scratch (aggr / t1 in place)
    float* ssum   = buf + (size_t)N_NODES * DIM;     // [D]
    float* ssq    = ssum + DIM;                      // [D]
    float* sscale = ssq + DIM;                       // [D]
    float* sshift = sscale + DIM;                    // [D]

    const int gemm_grid = (N_NODES + 31) / 32;
    const size_t zero_bytes = ((size_t)N_NODES * DIM + 2 * DIM) * sizeof(float);

    // ---- DOWN path ----
    hipMemsetAsync(buf, 0, zero_bytes, stream);
    scatter_kernel<<<(NE + 3) / 4, 256, 0, stream>>>(x, ea, ei, NE, buf);
    gemm_stage1<<<gemm_grid, 256, 0, stream>>>(x, buf, W1d, b1d, epsd, buf);
    colstats_kernel<<<1024, 256, 0, stream>>>(buf, ssum, ssq);
    finalize_kernel<<<1, 256, 0, stream>>>(ssum, ssq, g1d, bt1d, sscale, sshift);
    gemm_stage2<<<gemm_grid, 256, 0, stream>>>(buf, sscale, sshift, W2d, b2d, x, a1, out);

    // ---- UP path ----
    hipMemsetAsync(buf, 0, zero_bytes, stream);
    scatter_kernel<<<(NEV + 3) / 4, 256, 0, stream>>>(x, vea, vi, NEV, buf);
    gemm_stage1<<<gemm_grid, 256, 0, stream>>>(x, buf, W1u, b1u, epsu, buf);
    colstats_kernel<<<1024, 256, 0, stream>>>(buf, ssum, ssq);
    finalize_kernel<<<1, 256, 0, stream>>>(ssum, ssq, g1u, bt1u, sscale, sshift);
    gemm_stage2<<<gemm_grid, 256, 0, stream>>>(buf, sscale, sshift, W2u, b2u, out, a2, out);

    // ---- final BN + ReLU ----
    hipMemsetAsync(ssum, 0, 2 * DIM * sizeof(float), stream);
    colstats_kernel<<<1024, 256, 0, stream>>>(out, ssum, ssq);
    finalize_kernel<<<1, 256, 0, stream>>>(ssum, ssq, bng, bnb, sscale, sshift);
    bnrelu_kernel<<<2048, 256, 0, stream>>>(out, sscale, sshift);
}

// Round 2
// 1069.872 us; speedup vs baseline: 1.8870x; 1.8870x over previous
//
#include <hip/hip_runtime.h>
#include <math.h>

#define N_NODES 50000
#define DIM 256
#define NE 300000
#define NEV 100000

// ---------------------------------------------------------------------------
// FALLBACK scatter (atomic): buf[dst] += relu(x[src] + ea[e])
// ---------------------------------------------------------------------------
__global__ __launch_bounds__(256) void scatter_kernel(
    const float* __restrict__ x, const float* __restrict__ ea,
    const int* __restrict__ idx, int E, float* __restrict__ buf)
{
    int wid = blockIdx.x * (blockDim.x >> 6) + (threadIdx.x >> 6);
    int lane = threadIdx.x & 63;
    if (wid >= E) return;
    int s = idx[wid];
    int d = idx[E + wid];
    const float4* xs = (const float4*)(x + (size_t)s * DIM);
    const float4* es = (const float4*)(ea + (size_t)wid * DIM);
    float4 a = xs[lane];
    float4 b = es[lane];
    float4 m;
    m.x = fmaxf(a.x + b.x, 0.0f);
    m.y = fmaxf(a.y + b.y, 0.0f);
    m.z = fmaxf(a.z + b.z, 0.0f);
    m.w = fmaxf(a.w + b.w, 0.0f);
    float* dst = buf + (size_t)d * DIM + lane * 4;
    atomicAdd(dst + 0, m.x);
    atomicAdd(dst + 1, m.y);
    atomicAdd(dst + 2, m.z);
    atomicAdd(dst + 3, m.w);
}

// ---------------------------------------------------------------------------
// CSR build: histogram of dst into deg (in-place scanned to offsets later)
// ---------------------------------------------------------------------------
__global__ __launch_bounds__(256) void hist_kernel(
    const int* __restrict__ idx, int E, int* __restrict__ deg)
{
    int i = blockIdx.x * blockDim.x + threadIdx.x;
    if (i < E) atomicAdd(&deg[idx[E + i]], 1);
}

// single-block exclusive scan of deg[0..N) -> offsets (in place OK) + cursor
__global__ __launch_bounds__(1024) void scan_kernel(
    int* __restrict__ deg_offsets, int* __restrict__ cursor, int E)
{
    __shared__ int part[1024];
    int t = threadIdx.x;
    const int CH = (N_NODES + 1023) / 1024;   // 49
    int beg = t * CH;
    int end = min(beg + CH, N_NODES);
    int s = 0;
    for (int i = beg; i < end; i++) s += deg_offsets[i];
    part[t] = s;
    __syncthreads();
    for (int off = 1; off < 1024; off <<= 1) {
        int v = part[t];
        int u = (t >= off) ? part[t - off] : 0;
        __syncthreads();
        part[t] = v + u;
        __syncthreads();
    }
    int run = (t > 0) ? part[t - 1] : 0;   // exclusive base for this chunk
    for (int i = beg; i < end; i++) {
        int dv = deg_offsets[i];           // read BEFORE overwrite (in-place)
        deg_offsets[i] = run;
        cursor[i] = run;
        run += dv;
    }
    if (t == 1023) deg_offsets[N_NODES] = E;
}

__global__ __launch_bounds__(256) void fill_kernel(
    const int* __restrict__ idx, int E, int* __restrict__ cursor,
    int* __restrict__ sorted)
{
    int i = blockIdx.x * blockDim.x + threadIdx.x;
    if (i < E) {
        int d = idx[E + i];
        int pos = atomicAdd(&cursor[d], 1);
        sorted[pos] = i;
    }
}

// ---------------------------------------------------------------------------
// gather-accumulate: one wave per node; lane owns 4 cols. No fp atomics.
// buf[node] = sum_{e: dst(e)=node} relu(x[src(e)] + ea[e])
// ---------------------------------------------------------------------------
__global__ __launch_bounds__(256) void gather_kernel(
    const float* __restrict__ x, const float* __restrict__ ea,
    const int* __restrict__ idx, const int* __restrict__ offsets,
    const int* __restrict__ sorted, float* __restrict__ buf)
{
    int node = blockIdx.x * (blockDim.x >> 6) + (threadIdx.x >> 6);
    int lane = threadIdx.x & 63;
    if (node >= N_NODES) return;
    int beg = offsets[node], end = offsets[node + 1];
    float4 acc = make_float4(0.0f, 0.0f, 0.0f, 0.0f);
    for (int p = beg; p < end; p++) {
        int e = sorted[p];
        int s = idx[e];   // src row
        float4 a = ((const float4*)(x + (size_t)s * DIM))[lane];
        float4 b = ((const float4*)(ea + (size_t)e * DIM))[lane];
        acc.x += fmaxf(a.x + b.x, 0.0f);
        acc.y += fmaxf(a.y + b.y, 0.0f);
        acc.z += fmaxf(a.z + b.z, 0.0f);
        acc.w += fmaxf(a.w + b.w, 0.0f);
    }
    ((float4*)(buf + (size_t)node * DIM))[lane] = acc;
}

// ---------------------------------------------------------------------------
// GEMM stage 1: t1 = ((1+eps)*x + aggr) @ W1 + b1   (in-place over aggr OK)
// ---------------------------------------------------------------------------
__global__ __launch_bounds__(256) void gemm_stage1(
    const float* __restrict__ x, const float* __restrict__ aggr,
    const float* __restrict__ W, const float* __restrict__ bias,
    const float* __restrict__ eps_p, float* __restrict__ out)
{
    __shared__ float As[16][36];
    __shared__ float Ws[16][256];
    int t = threadIdx.x;
    int tx = t & 31, ty = t >> 5;
    int row0 = blockIdx.x * 32;
    float epsv = 1.0f + eps_p[0];
    float acc[4][8];
    #pragma unroll
    for (int i = 0; i < 4; i++)
        #pragma unroll
        for (int j = 0; j < 8; j++) acc[i][j] = 0.0f;

    int arow = t >> 3, ag = t & 7;
    for (int k0 = 0; k0 < DIM; k0 += 16) {
        int gr = row0 + arow;
        float2 av = make_float2(0.0f, 0.0f);
        if (gr < N_NODES) {
            size_t base = (size_t)gr * DIM + k0 + ag * 2;
            float2 xv = *(const float2*)(x + base);
            float2 bv = *(const float2*)(aggr + base);
            av.x = epsv * xv.x + bv.x;
            av.y = epsv * xv.y + bv.y;
        }
        As[ag * 2 + 0][arow] = av.x;
        As[ag * 2 + 1][arow] = av.y;
        const float4* wg = (const float4*)(W + (size_t)k0 * DIM);
        float4* wsv = (float4*)(&Ws[0][0]);
        #pragma unroll
        for (int r = 0; r < 4; r++) wsv[t + 256 * r] = wg[t + 256 * r];
        __syncthreads();
        #pragma unroll
        for (int kk = 0; kk < 16; kk++) {
            float a[4], w[8];
            #pragma unroll
            for (int i = 0; i < 4; i++) a[i] = As[kk][ty * 4 + i];
            #pragma unroll
            for (int j = 0; j < 8; j++) w[j] = Ws[kk][j * 32 + tx];
            #pragma unroll
            for (int i = 0; i < 4; i++)
                #pragma unroll
                for (int j = 0; j < 8; j++) acc[i][j] += a[i] * w[j];
        }
        __syncthreads();
    }
    #pragma unroll
    for (int j = 0; j < 8; j++) {
        int col = j * 32 + tx;
        float bv = bias[col];
        #pragma unroll
        for (int i = 0; i < 4; i++) {
            int r = row0 + ty * 4 + i;
            if (r < N_NODES) out[(size_t)r * DIM + col] = acc[i][j] + bv;
        }
    }
}

// ---------------------------------------------------------------------------
// GEMM stage 2: C = relu(t1*scale + shift) @ W2 + b2; out = base + alpha*C
// ---------------------------------------------------------------------------
__global__ __launch_bounds__(256) void gemm_stage2(
    const float* __restrict__ t1, const float* __restrict__ scale,
    const float* __restrict__ shift, const float* __restrict__ W,
    const float* __restrict__ bias, const float* __restrict__ base,
    const float* __restrict__ alpha_p, float* __restrict__ out)
{
    __shared__ float As[16][36];
    __shared__ float Ws[16][256];
    int t = threadIdx.x;
    int tx = t & 31, ty = t >> 5;
    int row0 = blockIdx.x * 32;
    float acc[4][8];
    #pragma unroll
    for (int i = 0; i < 4; i++)
        #pragma unroll
        for (int j = 0; j < 8; j++) acc[i][j] = 0.0f;

    int arow = t >> 3, ag = t & 7;
    for (int k0 = 0; k0 < DIM; k0 += 16) {
        int gr = row0 + arow;
        float2 av = make_float2(0.0f, 0.0f);
        if (gr < N_NODES) {
            size_t basei = (size_t)gr * DIM + k0 + ag * 2;
            float2 tv = *(const float2*)(t1 + basei);
            float2 sc = *(const float2*)(scale + k0 + ag * 2);
            float2 sh = *(const float2*)(shift + k0 + ag * 2);
            av.x = fmaxf(tv.x * sc.x + sh.x, 0.0f);
            av.y = fmaxf(tv.y * sc.y + sh.y, 0.0f);
        }
        As[ag * 2 + 0][arow] = av.x;
        As[ag * 2 + 1][arow] = av.y;
        const float4* wg = (const float4*)(W + (size_t)k0 * DIM);
        float4* wsv = (float4*)(&Ws[0][0]);
        #pragma unroll
        for (int r = 0; r < 4; r++) wsv[t + 256 * r] = wg[t + 256 * r];
        __syncthreads();
        #pragma unroll
        for (int kk = 0; kk < 16; kk++) {
            float a[4], w[8];
            #pragma unroll
            for (int i = 0; i < 4; i++) a[i] = As[kk][ty * 4 + i];
            #pragma unroll
            for (int j = 0; j < 8; j++) w[j] = Ws[kk][j * 32 + tx];
            #pragma unroll
            for (int i = 0; i < 4; i++)
                #pragma unroll
                for (int j = 0; j < 8; j++) acc[i][j] += a[i] * w[j];
        }
        __syncthreads();
    }
    float alphav = alpha_p[0];
    #pragma unroll
    for (int j = 0; j < 8; j++) {
        int col = j * 32 + tx;
        float bv = bias[col];
        #pragma unroll
        for (int i = 0; i < 4; i++) {
            int r = row0 + ty * 4 + i;
            if (r < N_NODES) {
                size_t o = (size_t)r * DIM + col;
                out[o] = base[o] + alphav * (acc[i][j] + bv);
            }
        }
    }
}

// ---------------------------------------------------------------------------
// column stats + finalize + BN/ReLU
// ---------------------------------------------------------------------------
__global__ __launch_bounds__(256) void colstats_kernel(
    const float* __restrict__ src, float* __restrict__ ssum, float* __restrict__ ssq)
{
    int c = threadIdx.x;
    float s = 0.0f, q = 0.0f;
    for (int r = blockIdx.x; r < N_NODES; r += gridDim.x) {
        float v = src[(size_t)r * DIM + c];
        s += v; q += v * v;
    }
    atomicAdd(&ssum[c], s);
    atomicAdd(&ssq[c], q);
}

__global__ void finalize_kernel(
    const float* __restrict__ ssum, const float* __restrict__ ssq,
    const float* __restrict__ g, const float* __restrict__ b,
    float* __restrict__ scale, float* __restrict__ shift)
{
    int c = threadIdx.x;
    const float invN = 1.0f / (float)N_NODES;
    float mu = ssum[c] * invN;
    float var = ssq[c] * invN - mu * mu;
    float sc = g[c] * rsqrtf(var + 1e-5f);
    scale[c] = sc;
    shift[c] = b[c] - mu * sc;
}

__global__ __launch_bounds__(256) void bnrelu_kernel(
    float* __restrict__ out, const float* __restrict__ scale,
    const float* __restrict__ shift)
{
    int idx = blockIdx.x * blockDim.x + threadIdx.x;
    const int total = N_NODES * (DIM / 4);
    for (int f = idx; f < total; f += gridDim.x * blockDim.x) {
        float4 v = ((float4*)out)[f];
        int c = (f * 4) & (DIM - 1);
        float4 sc = *(const float4*)(scale + c);
        float4 sh = *(const float4*)(shift + c);
        v.x = fmaxf(v.x * sc.x + sh.x, 0.0f);
        v.y = fmaxf(v.y * sc.y + sh.y, 0.0f);
        v.z = fmaxf(v.z * sc.z + sh.z, 0.0f);
        v.w = fmaxf(v.w * sc.w + sh.w, 0.0f);
        ((float4*)out)[f] = v;
    }
}

extern "C" void kernel_launch(void* const* d_in, const int* in_sizes, int n_in,
                              void* d_out, int out_size, void* d_ws, size_t ws_size,
                              hipStream_t stream)
{
    const float* x    = (const float*)d_in[0];
    const int*   ei   = (const int*)  d_in[1];
    const float* ea   = (const float*)d_in[2];
    const int*   vi   = (const int*)  d_in[3];
    const float* vea  = (const float*)d_in[4];
    const float* epsd = (const float*)d_in[5];
    const float* W1d  = (const float*)d_in[6];
    const float* b1d  = (const float*)d_in[7];
    const float* g1d  = (const float*)d_in[8];
    const float* bt1d = (const float*)d_in[9];
    const float* W2d  = (const float*)d_in[10];
    const float* b2d  = (const float*)d_in[11];
    const float* epsu = (const float*)d_in[12];
    const float* W1u  = (const float*)d_in[13];
    const float* b1u  = (const float*)d_in[14];
    const float* g1u  = (const float*)d_in[15];
    const float* bt1u = (const float*)d_in[16];
    const float* W2u  = (const float*)d_in[17];
    const float* b2u  = (const float*)d_in[18];
    const float* bng  = (const float*)d_in[19];
    const float* bnb  = (const float*)d_in[20];
    const float* a1   = (const float*)d_in[21];
    const float* a2   = (const float*)d_in[22];

    float* out = (float*)d_out;

    // workspace layout
    float* buf    = (float*)d_ws;                    // [N, D]
    float* ssum   = buf + (size_t)N_NODES * DIM;     // [D]
    float* ssq    = ssum + DIM;                      // [D]
    float* sscale = ssq + DIM;                       // [D]
    float* sshift = sscale + DIM;                    // [D]
    int*   offsets = (int*)(sshift + DIM);           // [N+1]
    int*   cursor  = offsets + (N_NODES + 1);        // [N]
    int*   sorted  = cursor + N_NODES;               // [NE max]
    size_t need = ((size_t)N_NODES * DIM + 4 * DIM) * sizeof(float)
                + ((size_t)(N_NODES + 1) + N_NODES + NE) * sizeof(int);
    bool use_csr = ws_size >= need;

    const int gemm_grid = (N_NODES + 31) / 32;
    const int gather_grid = (N_NODES + 3) / 4;

    for (int path = 0; path < 2; path++) {
        const int*   idx = path == 0 ? ei   : vi;
        const float* eat = path == 0 ? ea   : vea;
        const int    E   = path == 0 ? NE   : NEV;
        const float* eps = path == 0 ? epsd : epsu;
        const float* W1  = path == 0 ? W1d  : W1u;
        const float* b1  = path == 0 ? b1d  : b1u;
        const float* g1  = path == 0 ? g1d  : g1u;
        const float* bt1 = path == 0 ? bt1d : bt1u;
        const float* W2  = path == 0 ? W2d  : W2u;
        const float* b2  = path == 0 ? b2d  : b2u;
        const float* bse = path == 0 ? x    : out;
        const float* alp = path == 0 ? a1   : a2;

        if (use_csr) {
            hipMemsetAsync(offsets, 0, (N_NODES + 1) * sizeof(int), stream);
            hist_kernel<<<(E + 255) / 256, 256, 0, stream>>>(idx, E, offsets);
            scan_kernel<<<1, 1024, 0, stream>>>(offsets, cursor, E);
            fill_kernel<<<(E + 255) / 256, 256, 0, stream>>>(idx, E, cursor, sorted);
            gather_kernel<<<gather_grid, 256, 0, stream>>>(x, eat, idx, offsets, sorted, buf);
        } else {
            hipMemsetAsync(buf, 0, (size_t)N_NODES * DIM * sizeof(float), stream);
            scatter_kernel<<<(E + 3) / 4, 256, 0, stream>>>(x, eat, idx, E, buf);
        }
        gemm_stage1<<<gemm_grid, 256, 0, stream>>>(x, buf, W1, b1, eps, buf);
        hipMemsetAsync(ssum, 0, 2 * DIM * sizeof(float), stream);
        colstats_kernel<<<1024, 256, 0, stream>>>(buf, ssum, ssq);
        finalize_kernel<<<1, 256, 0, stream>>>(ssum, ssq, g1, bt1, sscale, sshift);
        gemm_stage2<<<gemm_grid, 256, 0, stream>>>(buf, sscale, sshift, W2, b2, bse, alp, out);
    }

    // ---- final BN + ReLU ----
    hipMemsetAsync(ssum, 0, 2 * DIM * sizeof(float), stream);
    colstats_kernel<<<1024, 256, 0, stream>>>(out, ssum, ssq);
    finalize_kernel<<<1, 256, 0, stream>>>(ssum, ssq, bng, bnb, sscale, sshift);
    bnrelu_kernel<<<2048, 256, 0, stream>>>(out, sscale, sshift);
}

// Round 3
// 1066.302 us; speedup vs baseline: 1.8933x; 1.0033x over previous
//
#include <hip/hip_runtime.h>
#include <math.h>

#define N_NODES 50000
#define DIM 256
#define NE 300000
#define NEV 100000

typedef float f32x4 __attribute__((ext_vector_type(4)));
typedef short s16x8 __attribute__((ext_vector_type(8)));

__device__ inline unsigned short f2bf(float f) {
    unsigned u = __float_as_uint(f);
    u += 0x7FFF + ((u >> 16) & 1);            // round-to-nearest-even
    return (unsigned short)(u >> 16);
}
__device__ inline float bf2f(unsigned short s) {
    return __uint_as_float(((unsigned)s) << 16);
}

// ---------------------------------------------------------------------------
// W [K][N] fp32 -> Wt [N][K] bf16  (one block per output row n)
// ---------------------------------------------------------------------------
__global__ __launch_bounds__(256) void prepw_kernel(
    const float* __restrict__ W, unsigned short* __restrict__ Wt)
{
    int n = blockIdx.x;
    int k = threadIdx.x;
    Wt[(size_t)n * DIM + k] = f2bf(W[(size_t)k * DIM + n]);
}

// ---------------------------------------------------------------------------
// FALLBACK scatter (atomic): aggr[dst] += relu(x[src] + ea[e])
// ---------------------------------------------------------------------------
__global__ __launch_bounds__(256) void scatter_kernel(
    const float* __restrict__ x, const float* __restrict__ ea,
    const int* __restrict__ idx, int E, float* __restrict__ buf)
{
    int wid = blockIdx.x * (blockDim.x >> 6) + (threadIdx.x >> 6);
    int lane = threadIdx.x & 63;
    if (wid >= E) return;
    int s = idx[wid];
    int d = idx[E + wid];
    const float4* xs = (const float4*)(x + (size_t)s * DIM);
    const float4* es = (const float4*)(ea + (size_t)wid * DIM);
    float4 a = xs[lane];
    float4 b = es[lane];
    float4 m;
    m.x = fmaxf(a.x + b.x, 0.0f);
    m.y = fmaxf(a.y + b.y, 0.0f);
    m.z = fmaxf(a.z + b.z, 0.0f);
    m.w = fmaxf(a.w + b.w, 0.0f);
    float* dst = buf + (size_t)d * DIM + lane * 4;
    atomicAdd(dst + 0, m.x);
    atomicAdd(dst + 1, m.y);
    atomicAdd(dst + 2, m.z);
    atomicAdd(dst + 3, m.w);
}

// ---------------------------------------------------------------------------
// CSR build
// ---------------------------------------------------------------------------
__global__ __launch_bounds__(256) void hist_kernel(
    const int* __restrict__ idx, int E, int* __restrict__ deg)
{
    int i = blockIdx.x * blockDim.x + threadIdx.x;
    if (i < E) atomicAdd(&deg[idx[E + i]], 1);
}

__global__ __launch_bounds__(1024) void scan_kernel(
    int* __restrict__ deg_offsets, int* __restrict__ cursor, int E)
{
    __shared__ int part[1024];
    int t = threadIdx.x;
    const int CH = (N_NODES + 1023) / 1024;
    int beg = t * CH;
    int end = min(beg + CH, N_NODES);
    int s = 0;
    for (int i = beg; i < end; i++) s += deg_offsets[i];
    part[t] = s;
    __syncthreads();
    for (int off = 1; off < 1024; off <<= 1) {
        int v = part[t];
        int u = (t >= off) ? part[t - off] : 0;
        __syncthreads();
        part[t] = v + u;
        __syncthreads();
    }
    int run = (t > 0) ? part[t - 1] : 0;
    for (int i = beg; i < end; i++) {
        int dv = deg_offsets[i];
        deg_offsets[i] = run;
        cursor[i] = run;
        run += dv;
    }
    if (t == 1023) deg_offsets[N_NODES] = E;
}

__global__ __launch_bounds__(256) void fill_kernel(
    const int* __restrict__ idx, int E, int* __restrict__ cursor,
    int* __restrict__ sorted)
{
    int i = blockIdx.x * blockDim.x + threadIdx.x;
    if (i < E) {
        int d = idx[E + i];
        int pos = atomicAdd(&cursor[d], 1);
        sorted[pos] = i;
    }
}

// ---------------------------------------------------------------------------
// gather-accumulate: one wave per node; lane owns 4 cols. No fp atomics.
// ---------------------------------------------------------------------------
__global__ __launch_bounds__(256) void gather_kernel(
    const float* __restrict__ x, const float* __restrict__ ea,
    const int* __restrict__ idx, const int* __restrict__ offsets,
    const int* __restrict__ sorted, float* __restrict__ buf)
{
    int node = blockIdx.x * (blockDim.x >> 6) + (threadIdx.x >> 6);
    int lane = threadIdx.x & 63;
    if (node >= N_NODES) return;
    int beg = offsets[node], end = offsets[node + 1];
    float4 acc = make_float4(0.0f, 0.0f, 0.0f, 0.0f);
    for (int p = beg; p < end; p++) {
        int e = sorted[p];
        int s = idx[e];
        float4 a = ((const float4*)(x + (size_t)s * DIM))[lane];
        float4 b = ((const float4*)(ea + (size_t)e * DIM))[lane];
        acc.x += fmaxf(a.x + b.x, 0.0f);
        acc.y += fmaxf(a.y + b.y, 0.0f);
        acc.z += fmaxf(a.z + b.z, 0.0f);
        acc.w += fmaxf(a.w + b.w, 0.0f);
    }
    ((float4*)(buf + (size_t)node * DIM))[lane] = acc;
}

// ---------------------------------------------------------------------------
// MFMA GEMM stage 1: t1(bf16) = ((1+eps)*x + aggr) @ W1 + b1
// Block = 64 rows x 256 cols; 4 waves, wave w owns rows [w*16, w*16+16).
// Column stats of t1 accumulated into ssum/ssq (valid rows only).
// ---------------------------------------------------------------------------
__global__ __launch_bounds__(256) void gemm1_mfma(
    const float* __restrict__ x, const float* __restrict__ aggr,
    const unsigned short* __restrict__ Wt, const float* __restrict__ bias,
    const float* __restrict__ eps_p, unsigned short* __restrict__ t1,
    float* __restrict__ ssum, float* __restrict__ ssq)
{
    __shared__ unsigned short Asm[64][DIM];   // 32 KB bf16 A-tile
    int t = threadIdx.x;
    int row0 = blockIdx.x * 64;
    float epsv = 1.0f + eps_p[0];

    #pragma unroll
    for (int it = 0; it < 8; ++it) {
        int c = it * 256 + t;
        int row = c >> 5, kg = c & 31;
        int gr = row0 + row;
        s16x8 pack = {0, 0, 0, 0, 0, 0, 0, 0};
        if (gr < N_NODES) {
            const float4* xp = (const float4*)(x + (size_t)gr * DIM + kg * 8);
            const float4* ap = (const float4*)(aggr + (size_t)gr * DIM + kg * 8);
            float4 x0 = xp[0], x1 = xp[1], a0 = ap[0], a1 = ap[1];
            pack[0] = f2bf(fmaf(epsv, x0.x, a0.x));
            pack[1] = f2bf(fmaf(epsv, x0.y, a0.y));
            pack[2] = f2bf(fmaf(epsv, x0.z, a0.z));
            pack[3] = f2bf(fmaf(epsv, x0.w, a0.w));
            pack[4] = f2bf(fmaf(epsv, x1.x, a1.x));
            pack[5] = f2bf(fmaf(epsv, x1.y, a1.y));
            pack[6] = f2bf(fmaf(epsv, x1.z, a1.z));
            pack[7] = f2bf(fmaf(epsv, x1.w, a1.w));
        }
        *(s16x8*)&Asm[row][kg * 8] = pack;
    }
    __syncthreads();

    int w = t >> 6, l = t & 63;
    int lrow = l & 15, kgrp = l >> 4;
    s16x8 afrag[8];
    #pragma unroll
    for (int ks = 0; ks < 8; ++ks)
        afrag[ks] = *(const s16x8*)&Asm[w * 16 + lrow][ks * 32 + kgrp * 8];

    for (int nt = 0; nt < 16; ++nt) {
        f32x4 acc = {0.f, 0.f, 0.f, 0.f};
        const unsigned short* bp = Wt + (size_t)(nt * 16 + lrow) * DIM + kgrp * 8;
        #pragma unroll
        for (int ks = 0; ks < 8; ++ks) {
            s16x8 bfrag = *(const s16x8*)(bp + ks * 32);
            acc = __builtin_amdgcn_mfma_f32_16x16x32_bf16(afrag[ks], bfrag, acc, 0, 0, 0);
        }
        int col = nt * 16 + lrow;
        float bv = bias[col];
        float s = 0.f, q = 0.f;
        #pragma unroll
        for (int r = 0; r < 4; ++r) {
            int grow = row0 + w * 16 + kgrp * 4 + r;
            if (grow < N_NODES) {
                float v = acc[r] + bv;
                t1[(size_t)grow * DIM + col] = f2bf(v);
                s += v; q += v * v;
            }
        }
        s += __shfl_xor(s, 16); q += __shfl_xor(q, 16);
        s += __shfl_xor(s, 32); q += __shfl_xor(q, 32);
        if (kgrp == 0) { atomicAdd(&ssum[col], s); atomicAdd(&ssq[col], q); }
    }
}

// ---------------------------------------------------------------------------
// MFMA GEMM stage 2: C = relu(t1*scale+shift) @ W2 + b2; out = base + alpha*C
// Optional final-BN stats accumulation (do_stats).
// ---------------------------------------------------------------------------
__global__ __launch_bounds__(256) void gemm2_mfma(
    const unsigned short* __restrict__ t1, const float* __restrict__ scale,
    const float* __restrict__ shift, const unsigned short* __restrict__ Wt,
    const float* __restrict__ bias, const float* __restrict__ base,
    const float* __restrict__ alpha_p, float* __restrict__ out, int do_stats,
    float* __restrict__ ssum, float* __restrict__ ssq)
{
    __shared__ unsigned short Asm[64][DIM];
    int t = threadIdx.x;
    int row0 = blockIdx.x * 64;

    #pragma unroll
    for (int it = 0; it < 8; ++it) {
        int c = it * 256 + t;
        int row = c >> 5, kg = c & 31;
        int gr = row0 + row;
        s16x8 pack = {0, 0, 0, 0, 0, 0, 0, 0};
        if (gr < N_NODES) {
            s16x8 tv = *(const s16x8*)(t1 + (size_t)gr * DIM + kg * 8);
            const float4* scp = (const float4*)(scale + kg * 8);
            const float4* shp = (const float4*)(shift + kg * 8);
            float4 s0 = scp[0], s1 = scp[1], h0 = shp[0], h1 = shp[1];
            pack[0] = f2bf(fmaxf(fmaf(bf2f((unsigned short)tv[0]), s0.x, h0.x), 0.f));
            pack[1] = f2bf(fmaxf(fmaf(bf2f((unsigned short)tv[1]), s0.y, h0.y), 0.f));
            pack[2] = f2bf(fmaxf(fmaf(bf2f((unsigned short)tv[2]), s0.z, h0.z), 0.f));
            pack[3] = f2bf(fmaxf(fmaf(bf2f((unsigned short)tv[3]), s0.w, h0.w), 0.f));
            pack[4] = f2bf(fmaxf(fmaf(bf2f((unsigned short)tv[4]), s1.x, h1.x), 0.f));
            pack[5] = f2bf(fmaxf(fmaf(bf2f((unsigned short)tv[5]), s1.y, h1.y), 0.f));
            pack[6] = f2bf(fmaxf(fmaf(bf2f((unsigned short)tv[6]), s1.z, h1.z), 0.f));
            pack[7] = f2bf(fmaxf(fmaf(bf2f((unsigned short)tv[7]), s1.w, h1.w), 0.f));
        }
        *(s16x8*)&Asm[row][kg * 8] = pack;
    }
    __syncthreads();

    int w = t >> 6, l = t & 63;
    int lrow = l & 15, kgrp = l >> 4;
    s16x8 afrag[8];
    #pragma unroll
    for (int ks = 0; ks < 8; ++ks)
        afrag[ks] = *(const s16x8*)&Asm[w * 16 + lrow][ks * 32 + kgrp * 8];

    float alphav = alpha_p[0];
    for (int nt = 0; nt < 16; ++nt) {
        f32x4 acc = {0.f, 0.f, 0.f, 0.f};
        const unsigned short* bp = Wt + (size_t)(nt * 16 + lrow) * DIM + kgrp * 8;
        #pragma unroll
        for (int ks = 0; ks < 8; ++ks) {
            s16x8 bfrag = *(const s16x8*)(bp + ks * 32);
            acc = __builtin_amdgcn_mfma_f32_16x16x32_bf16(afrag[ks], bfrag, acc, 0, 0, 0);
        }
        int col = nt * 16 + lrow;
        float bv = bias[col];
        float s = 0.f, q = 0.f;
        #pragma unroll
        for (int r = 0; r < 4; ++r) {
            int grow = row0 + w * 16 + kgrp * 4 + r;
            if (grow < N_NODES) {
                size_t o = (size_t)grow * DIM + col;
                float v = fmaf(alphav, acc[r] + bv, base[o]);
                out[o] = v;
                s += v; q += v * v;
            }
        }
        if (do_stats) {
            s += __shfl_xor(s, 16); q += __shfl_xor(q, 16);
            s += __shfl_xor(s, 32); q += __shfl_xor(q, 32);
            if (kgrp == 0) { atomicAdd(&ssum[col], s); atomicAdd(&ssq[col], q); }
        }
    }
}

// ---------------------------------------------------------------------------
// BN finalize + elementwise BN/ReLU
// ---------------------------------------------------------------------------
__global__ void finalize_kernel(
    const float* __restrict__ ssum, const float* __restrict__ ssq,
    const float* __restrict__ g, const float* __restrict__ b,
    float* __restrict__ scale, float* __restrict__ shift)
{
    int c = threadIdx.x;
    const float invN = 1.0f / (float)N_NODES;
    float mu = ssum[c] * invN;
    float var = ssq[c] * invN - mu * mu;
    float sc = g[c] * rsqrtf(var + 1e-5f);
    scale[c] = sc;
    shift[c] = b[c] - mu * sc;
}

__global__ __launch_bounds__(256) void bnrelu_kernel(
    float* __restrict__ out, const float* __restrict__ scale,
    const float* __restrict__ shift)
{
    int idx = blockIdx.x * blockDim.x + threadIdx.x;
    const int total = N_NODES * (DIM / 4);
    for (int f = idx; f < total; f += gridDim.x * blockDim.x) {
        float4 v = ((float4*)out)[f];
        int c = (f * 4) & (DIM - 1);
        float4 sc = *(const float4*)(scale + c);
        float4 sh = *(const float4*)(shift + c);
        v.x = fmaxf(v.x * sc.x + sh.x, 0.0f);
        v.y = fmaxf(v.y * sc.y + sh.y, 0.0f);
        v.z = fmaxf(v.z * sc.z + sh.z, 0.0f);
        v.w = fmaxf(v.w * sc.w + sh.w, 0.0f);
        ((float4*)out)[f] = v;
    }
}

extern "C" void kernel_launch(void* const* d_in, const int* in_sizes, int n_in,
                              void* d_out, int out_size, void* d_ws, size_t ws_size,
                              hipStream_t stream)
{
    const float* x    = (const float*)d_in[0];
    const int*   ei   = (const int*)  d_in[1];
    const float* ea   = (const float*)d_in[2];
    const int*   vi   = (const int*)  d_in[3];
    const float* vea  = (const float*)d_in[4];
    const float* epsd = (const float*)d_in[5];
    const float* W1d  = (const float*)d_in[6];
    const float* b1d  = (const float*)d_in[7];
    const float* g1d  = (const float*)d_in[8];
    const float* bt1d = (const float*)d_in[9];
    const float* W2d  = (const float*)d_in[10];
    const float* b2d  = (const float*)d_in[11];
    const float* epsu = (const float*)d_in[12];
    const float* W1u  = (const float*)d_in[13];
    const float* b1u  = (const float*)d_in[14];
    const float* g1u  = (const float*)d_in[15];
    const float* bt1u = (const float*)d_in[16];
    const float* W2u  = (const float*)d_in[17];
    const float* b2u  = (const float*)d_in[18];
    const float* bng  = (const float*)d_in[19];
    const float* bnb  = (const float*)d_in[20];
    const float* a1   = (const float*)d_in[21];
    const float* a2   = (const float*)d_in[22];

    float* out = (float*)d_out;

    // workspace layout
    float*          aggr   = (float*)d_ws;                                   // [N, D] f32
    unsigned short* t1     = (unsigned short*)(aggr + (size_t)N_NODES * DIM);// [N, D] bf16
    float*          ssum   = (float*)(t1 + (size_t)N_NODES * DIM);           // [D]
    float*          ssq    = ssum + DIM;
    float*          sscale = ssq + DIM;
    float*          sshift = sscale + DIM;
    unsigned short* Wt     = (unsigned short*)(sshift + DIM);                // 4 x [D, D] bf16
    int*            offsets = (int*)(Wt + 4 * (size_t)DIM * DIM);            // [N+1]
    int*            cursor  = offsets + (N_NODES + 1);                       // [N]
    int*            sorted  = cursor + N_NODES;                              // [NE]

    size_t need = (size_t)((char*)(sorted + NE) - (char*)d_ws);
    bool use_csr = ws_size >= need;

    unsigned short* Wt1d = Wt;
    unsigned short* Wt2d = Wt + (size_t)DIM * DIM;
    unsigned short* Wt1u = Wt + 2 * (size_t)DIM * DIM;
    unsigned short* Wt2u = Wt + 3 * (size_t)DIM * DIM;

    // ---- weight prep (bf16 transpose) ----
    prepw_kernel<<<DIM, 256, 0, stream>>>(W1d, Wt1d);
    prepw_kernel<<<DIM, 256, 0, stream>>>(W2d, Wt2d);
    prepw_kernel<<<DIM, 256, 0, stream>>>(W1u, Wt1u);
    prepw_kernel<<<DIM, 256, 0, stream>>>(W2u, Wt2u);

    const int gemm_grid = (N_NODES + 63) / 64;
    const int gather_grid = (N_NODES + 3) / 4;

    for (int path = 0; path < 2; path++) {
        const int*   idx = path == 0 ? ei   : vi;
        const float* eat = path == 0 ? ea   : vea;
        const int    E   = path == 0 ? NE   : NEV;
        const float* eps = path == 0 ? epsd : epsu;
        unsigned short* W1t = path == 0 ? Wt1d : Wt1u;
        const float* b1  = path == 0 ? b1d  : b1u;
        const float* g1  = path == 0 ? g1d  : g1u;
        const float* bt1 = path == 0 ? bt1d : bt1u;
        unsigned short* W2t = path == 0 ? Wt2d : Wt2u;
        const float* b2  = path == 0 ? b2d  : b2u;
        const float* bse = path == 0 ? x    : out;
        const float* alp = path == 0 ? a1   : a2;

        if (use_csr) {
            hipMemsetAsync(offsets, 0, (N_NODES + 1) * sizeof(int), stream);
            hist_kernel<<<(E + 255) / 256, 256, 0, stream>>>(idx, E, offsets);
            scan_kernel<<<1, 1024, 0, stream>>>(offsets, cursor, E);
            fill_kernel<<<(E + 255) / 256, 256, 0, stream>>>(idx, E, cursor, sorted);
            gather_kernel<<<gather_grid, 256, 0, stream>>>(x, eat, idx, offsets, sorted, aggr);
        } else {
            hipMemsetAsync(aggr, 0, (size_t)N_NODES * DIM * sizeof(float), stream);
            scatter_kernel<<<(E + 3) / 4, 256, 0, stream>>>(x, eat, idx, E, aggr);
        }
        hipMemsetAsync(ssum, 0, 2 * DIM * sizeof(float), stream);
        gemm1_mfma<<<gemm_grid, 256, 0, stream>>>(x, aggr, W1t, b1, eps, t1, ssum, ssq);
        finalize_kernel<<<1, 256, 0, stream>>>(ssum, ssq, g1, bt1, sscale, sshift);
        if (path == 1) hipMemsetAsync(ssum, 0, 2 * DIM * sizeof(float), stream);
        gemm2_mfma<<<gemm_grid, 256, 0, stream>>>(t1, sscale, sshift, W2t, b2, bse, alp, out,
                                                  path == 1 ? 1 : 0, ssum, ssq);
    }

    // ---- final BN + ReLU (stats already accumulated by gemm2-up) ----
    finalize_kernel<<<1, 256, 0, stream>>>(ssum, ssq, bng, bnb, sscale, sshift);
    bnrelu_kernel<<<2048, 256, 0, stream>>>(out, sscale, sshift);
}

// Round 4
// 699.120 us; speedup vs baseline: 2.8877x; 1.5252x over previous
//
#include <hip/hip_runtime.h>
#include <math.h>

#define N_NODES 50000
#define DIM 256
#define NE 300000
#define NEV 100000
#define BM 64
#define BK 64
#define NT 16          // DIM/16 col-tiles
#define NSLOT 8

typedef float f32x4 __attribute__((ext_vector_type(4)));
typedef short s16x8 __attribute__((ext_vector_type(8)));

__device__ inline unsigned short f2bf(float f) {
    unsigned u = __float_as_uint(f);
    u += 0x7FFF + ((u >> 16) & 1);            // round-to-nearest-even
    return (unsigned short)(u >> 16);
}
__device__ inline float bf2f(unsigned short s) {
    return __uint_as_float(((unsigned)s) << 16);
}
// swizzled halfword offset inside a [R][64] bf16 tile (16B granules, T2 XOR)
__device__ inline int swz(int row, int kg) {
    return row * BK + ((kg ^ (row & 7)) << 3);
}

// ---------------------------------------------------------------------------
// W [K][N] fp32 -> Wt [N][K] bf16
// ---------------------------------------------------------------------------
__global__ __launch_bounds__(256) void prepw_kernel(
    const float* __restrict__ W, unsigned short* __restrict__ Wt)
{
    int n = blockIdx.x;
    int k = threadIdx.x;
    Wt[(size_t)n * DIM + k] = f2bf(W[(size_t)k * DIM + n]);
}

// ---------------------------------------------------------------------------
// FALLBACK scatter (atomic)
// ---------------------------------------------------------------------------
__global__ __launch_bounds__(256) void scatter_kernel(
    const float* __restrict__ x, const float* __restrict__ ea,
    const int* __restrict__ idx, int E, float* __restrict__ buf)
{
    int wid = blockIdx.x * (blockDim.x >> 6) + (threadIdx.x >> 6);
    int lane = threadIdx.x & 63;
    if (wid >= E) return;
    int s = idx[wid];
    int d = idx[E + wid];
    const float4* xs = (const float4*)(x + (size_t)s * DIM);
    const float4* es = (const float4*)(ea + (size_t)wid * DIM);
    float4 a = xs[lane];
    float4 b = es[lane];
    float4 m;
    m.x = fmaxf(a.x + b.x, 0.0f);
    m.y = fmaxf(a.y + b.y, 0.0f);
    m.z = fmaxf(a.z + b.z, 0.0f);
    m.w = fmaxf(a.w + b.w, 0.0f);
    float* dst = buf + (size_t)d * DIM + lane * 4;
    atomicAdd(dst + 0, m.x);
    atomicAdd(dst + 1, m.y);
    atomicAdd(dst + 2, m.z);
    atomicAdd(dst + 3, m.w);
}

// ---------------------------------------------------------------------------
// CSR build
// ---------------------------------------------------------------------------
__global__ __launch_bounds__(256) void hist_kernel(
    const int* __restrict__ idx, int E, int* __restrict__ deg)
{
    int i = blockIdx.x * blockDim.x + threadIdx.x;
    if (i < E) atomicAdd(&deg[idx[E + i]], 1);
}

__global__ __launch_bounds__(1024) void scan_kernel(
    int* __restrict__ deg_offsets, int* __restrict__ cursor, int E)
{
    __shared__ int part[1024];
    int t = threadIdx.x;
    const int CH = (N_NODES + 1023) / 1024;
    int beg = t * CH;
    int end = min(beg + CH, N_NODES);
    int s = 0;
    for (int i = beg; i < end; i++) s += deg_offsets[i];
    part[t] = s;
    __syncthreads();
    for (int off = 1; off < 1024; off <<= 1) {
        int v = part[t];
        int u = (t >= off) ? part[t - off] : 0;
        __syncthreads();
        part[t] = v + u;
        __syncthreads();
    }
    int run = (t > 0) ? part[t - 1] : 0;
    for (int i = beg; i < end; i++) {
        int dv = deg_offsets[i];
        deg_offsets[i] = run;
        cursor[i] = run;
        run += dv;
    }
    if (t == 1023) deg_offsets[N_NODES] = E;
}

__global__ __launch_bounds__(256) void fill_kernel(
    const int* __restrict__ idx, int E, int* __restrict__ cursor,
    int* __restrict__ sorted, int* __restrict__ srcs)
{
    int i = blockIdx.x * blockDim.x + threadIdx.x;
    if (i < E) {
        int s = idx[i];
        int d = idx[E + i];
        int pos = atomicAdd(&cursor[d], 1);
        sorted[pos] = i;
        srcs[pos] = s;
    }
}

// ---------------------------------------------------------------------------
// gather-accumulate: one wave per node; independent sorted/srcs streams.
// ---------------------------------------------------------------------------
__global__ __launch_bounds__(256) void gather_kernel(
    const float* __restrict__ x, const float* __restrict__ ea,
    const int* __restrict__ offsets, const int* __restrict__ sorted,
    const int* __restrict__ srcs, float* __restrict__ buf)
{
    int node = blockIdx.x * (blockDim.x >> 6) + (threadIdx.x >> 6);
    int lane = threadIdx.x & 63;
    if (node >= N_NODES) return;
    int beg = offsets[node], end = offsets[node + 1];
    float4 acc = make_float4(0.0f, 0.0f, 0.0f, 0.0f);
    for (int p = beg; p < end; p++) {
        int e = sorted[p];
        int s = srcs[p];
        float4 a = ((const float4*)(x + (size_t)s * DIM))[lane];
        float4 b = ((const float4*)(ea + (size_t)e * DIM))[lane];
        acc.x += fmaxf(a.x + b.x, 0.0f);
        acc.y += fmaxf(a.y + b.y, 0.0f);
        acc.z += fmaxf(a.z + b.z, 0.0f);
        acc.w += fmaxf(a.w + b.w, 0.0f);
    }
    ((float4*)(buf + (size_t)node * DIM))[lane] = acc;
}

// ---------------------------------------------------------------------------
// MFMA GEMM stage 1, LDS-staged + swizzled:
//   t1(bf16) = ((1+eps)*x + aggr) @ W1 + b1, col stats into 8-slot ssum/ssq
// Block: 64 rows x 256 cols, 4 waves (wave w = rows w*16..+16), K chunks of 64.
// ---------------------------------------------------------------------------
__global__ __launch_bounds__(256) void gemm1_mfma(
    const float* __restrict__ x, const float* __restrict__ aggr,
    const unsigned short* __restrict__ Wt, const float* __restrict__ bias,
    const float* __restrict__ eps_p, unsigned short* __restrict__ t1,
    float* __restrict__ ssum, float* __restrict__ ssq)
{
    __shared__ unsigned short As[BM * BK];
    __shared__ unsigned short Bs[DIM * BK];
    __shared__ float sLds[4 * DIM];
    __shared__ float qLds[4 * DIM];
    int t = threadIdx.x;
    int w = t >> 6, l = t & 63, lrow = l & 15, kgrp = l >> 4;
    int row0 = blockIdx.x * BM;
    float epsv = 1.0f + eps_p[0];

    f32x4 acc[NT];
    #pragma unroll
    for (int nt = 0; nt < NT; ++nt) acc[nt] = (f32x4){0.f, 0.f, 0.f, 0.f};

    for (int k0 = 0; k0 < DIM; k0 += BK) {
        __syncthreads();
        // A stage: 512 granules of 16B
        #pragma unroll
        for (int it = 0; it < 2; ++it) {
            int g = it * 256 + t, row = g >> 3, kg = g & 7;
            int gr = row0 + row;
            s16x8 pack = {0, 0, 0, 0, 0, 0, 0, 0};
            if (gr < N_NODES) {
                const float4* xp = (const float4*)(x + (size_t)gr * DIM + k0 + kg * 8);
                const float4* ap = (const float4*)(aggr + (size_t)gr * DIM + k0 + kg * 8);
                float4 x0 = xp[0], x1 = xp[1], a0 = ap[0], a1 = ap[1];
                pack[0] = f2bf(fmaf(epsv, x0.x, a0.x));
                pack[1] = f2bf(fmaf(epsv, x0.y, a0.y));
                pack[2] = f2bf(fmaf(epsv, x0.z, a0.z));
                pack[3] = f2bf(fmaf(epsv, x0.w, a0.w));
                pack[4] = f2bf(fmaf(epsv, x1.x, a1.x));
                pack[5] = f2bf(fmaf(epsv, x1.y, a1.y));
                pack[6] = f2bf(fmaf(epsv, x1.z, a1.z));
                pack[7] = f2bf(fmaf(epsv, x1.w, a1.w));
            }
            *(s16x8*)&As[swz(row, kg)] = pack;
        }
        // B stage: 2048 granules of 16B
        #pragma unroll
        for (int it = 0; it < 8; ++it) {
            int g = it * 256 + t, row = g >> 3, kg = g & 7;
            s16x8 v = *(const s16x8*)&Wt[(size_t)row * DIM + k0 + kg * 8];
            *(s16x8*)&Bs[swz(row, kg)] = v;
        }
        __syncthreads();
        int arow = w * 16 + lrow;
        s16x8 af0 = *(const s16x8*)&As[swz(arow, kgrp)];
        s16x8 af1 = *(const s16x8*)&As[swz(arow, 4 + kgrp)];
        #pragma unroll
        for (int nt = 0; nt < NT; ++nt) {
            int col = nt * 16 + lrow;
            s16x8 bf0 = *(const s16x8*)&Bs[swz(col, kgrp)];
            s16x8 bf1 = *(const s16x8*)&Bs[swz(col, 4 + kgrp)];
            acc[nt] = __builtin_amdgcn_mfma_f32_16x16x32_bf16(af0, bf0, acc[nt], 0, 0, 0);
            acc[nt] = __builtin_amdgcn_mfma_f32_16x16x32_bf16(af1, bf1, acc[nt], 0, 0, 0);
        }
    }
    // epilogue: write t1 (bf16) + per-wave stats slices
    #pragma unroll
    for (int nt = 0; nt < NT; ++nt) {
        int col = nt * 16 + lrow;
        float bv = bias[col];
        float s = 0.f, q = 0.f;
        #pragma unroll
        for (int r = 0; r < 4; ++r) {
            int grow = row0 + w * 16 + kgrp * 4 + r;
            if (grow < N_NODES) {
                float v = acc[nt][r] + bv;
                t1[(size_t)grow * DIM + col] = f2bf(v);
                s += v; q += v * v;
            }
        }
        s += __shfl_xor(s, 16); q += __shfl_xor(q, 16);
        s += __shfl_xor(s, 32); q += __shfl_xor(q, 32);
        if (kgrp == 0) { sLds[w * DIM + col] = s; qLds[w * DIM + col] = q; }
    }
    __syncthreads();
    if (t < DIM) {
        float s = sLds[t] + sLds[DIM + t] + sLds[2 * DIM + t] + sLds[3 * DIM + t];
        float q = qLds[t] + qLds[DIM + t] + qLds[2 * DIM + t] + qLds[3 * DIM + t];
        int slot = blockIdx.x & (NSLOT - 1);
        atomicAdd(&ssum[slot * DIM + t], s);
        atomicAdd(&ssq[slot * DIM + t], q);
    }
}

// ---------------------------------------------------------------------------
// MFMA GEMM stage 2, LDS-staged + swizzled:
//   C = relu(t1*scale+shift) @ W2 + b2; out = base + alpha*C
// ---------------------------------------------------------------------------
__global__ __launch_bounds__(256) void gemm2_mfma(
    const unsigned short* __restrict__ t1, const float* __restrict__ scale,
    const float* __restrict__ shift, const unsigned short* __restrict__ Wt,
    const float* __restrict__ bias, const float* __restrict__ base,
    const float* __restrict__ alpha_p, float* __restrict__ out, int do_stats,
    float* __restrict__ ssum, float* __restrict__ ssq)
{
    __shared__ unsigned short As[BM * BK];
    __shared__ unsigned short Bs[DIM * BK];
    __shared__ float sLds[4 * DIM];
    __shared__ float qLds[4 * DIM];
    int t = threadIdx.x;
    int w = t >> 6, l = t & 63, lrow = l & 15, kgrp = l >> 4;
    int row0 = blockIdx.x * BM;

    f32x4 acc[NT];
    #pragma unroll
    for (int nt = 0; nt < NT; ++nt) acc[nt] = (f32x4){0.f, 0.f, 0.f, 0.f};

    for (int k0 = 0; k0 < DIM; k0 += BK) {
        __syncthreads();
        #pragma unroll
        for (int it = 0; it < 2; ++it) {
            int g = it * 256 + t, row = g >> 3, kg = g & 7;
            int gr = row0 + row;
            s16x8 pack = {0, 0, 0, 0, 0, 0, 0, 0};
            if (gr < N_NODES) {
                s16x8 tv = *(const s16x8*)(t1 + (size_t)gr * DIM + k0 + kg * 8);
                const float4* scp = (const float4*)(scale + k0 + kg * 8);
                const float4* shp = (const float4*)(shift + k0 + kg * 8);
                float4 s0 = scp[0], s1 = scp[1], h0 = shp[0], h1 = shp[1];
                pack[0] = f2bf(fmaxf(fmaf(bf2f((unsigned short)tv[0]), s0.x, h0.x), 0.f));
                pack[1] = f2bf(fmaxf(fmaf(bf2f((unsigned short)tv[1]), s0.y, h0.y), 0.f));
                pack[2] = f2bf(fmaxf(fmaf(bf2f((unsigned short)tv[2]), s0.z, h0.z), 0.f));
                pack[3] = f2bf(fmaxf(fmaf(bf2f((unsigned short)tv[3]), s0.w, h0.w), 0.f));
                pack[4] = f2bf(fmaxf(fmaf(bf2f((unsigned short)tv[4]), s1.x, h1.x), 0.f));
                pack[5] = f2bf(fmaxf(fmaf(bf2f((unsigned short)tv[5]), s1.y, h1.y), 0.f));
                pack[6] = f2bf(fmaxf(fmaf(bf2f((unsigned short)tv[6]), s1.z, h1.z), 0.f));
                pack[7] = f2bf(fmaxf(fmaf(bf2f((unsigned short)tv[7]), s1.w, h1.w), 0.f));
            }
            *(s16x8*)&As[swz(row, kg)] = pack;
        }
        #pragma unroll
        for (int it = 0; it < 8; ++it) {
            int g = it * 256 + t, row = g >> 3, kg = g & 7;
            s16x8 v = *(const s16x8*)&Wt[(size_t)row * DIM + k0 + kg * 8];
            *(s16x8*)&Bs[swz(row, kg)] = v;
        }
        __syncthreads();
        int arow = w * 16 + lrow;
        s16x8 af0 = *(const s16x8*)&As[swz(arow, kgrp)];
        s16x8 af1 = *(const s16x8*)&As[swz(arow, 4 + kgrp)];
        #pragma unroll
        for (int nt = 0; nt < NT; ++nt) {
            int col = nt * 16 + lrow;
            s16x8 bf0 = *(const s16x8*)&Bs[swz(col, kgrp)];
            s16x8 bf1 = *(const s16x8*)&Bs[swz(col, 4 + kgrp)];
            acc[nt] = __builtin_amdgcn_mfma_f32_16x16x32_bf16(af0, bf0, acc[nt], 0, 0, 0);
            acc[nt] = __builtin_amdgcn_mfma_f32_16x16x32_bf16(af1, bf1, acc[nt], 0, 0, 0);
        }
    }
    float alphav = alpha_p[0];
    #pragma unroll
    for (int nt = 0; nt < NT; ++nt) {
        int col = nt * 16 + lrow;
        float bv = bias[col];
        float s = 0.f, q = 0.f;
        #pragma unroll
        for (int r = 0; r < 4; ++r) {
            int grow = row0 + w * 16 + kgrp * 4 + r;
            if (grow < N_NODES) {
                size_t o = (size_t)grow * DIM + col;
                float v = fmaf(alphav, acc[nt][r] + bv, base[o]);
                out[o] = v;
                s += v; q += v * v;
            }
        }
        if (do_stats) {
            s += __shfl_xor(s, 16); q += __shfl_xor(q, 16);
            s += __shfl_xor(s, 32); q += __shfl_xor(q, 32);
            if (kgrp == 0) { sLds[w * DIM + col] = s; qLds[w * DIM + col] = q; }
        }
    }
    __syncthreads();
    if (do_stats && t < DIM) {
        float s = sLds[t] + sLds[DIM + t] + sLds[2 * DIM + t] + sLds[3 * DIM + t];
        float q = qLds[t] + qLds[DIM + t] + qLds[2 * DIM + t] + qLds[3 * DIM + t];
        int slot = blockIdx.x & (NSLOT - 1);
        atomicAdd(&ssum[slot * DIM + t], s);
        atomicAdd(&ssq[slot * DIM + t], q);
    }
}

// ---------------------------------------------------------------------------
// BN finalize (sums NSLOT slots) + elementwise BN/ReLU
// ---------------------------------------------------------------------------
__global__ void finalize_kernel(
    const float* __restrict__ ssum, const float* __restrict__ ssq,
    const float* __restrict__ g, const float* __restrict__ b,
    float* __restrict__ scale, float* __restrict__ shift)
{
    int c = threadIdx.x;
    float s = 0.f, q = 0.f;
    #pragma unroll
    for (int k = 0; k < NSLOT; ++k) { s += ssum[k * DIM + c]; q += ssq[k * DIM + c]; }
    const float invN = 1.0f / (float)N_NODES;
    float mu = s * invN;
    float var = q * invN - mu * mu;
    float sc = g[c] * rsqrtf(var + 1e-5f);
    scale[c] = sc;
    shift[c] = b[c] - mu * sc;
}

__global__ __launch_bounds__(256) void bnrelu_kernel(
    float* __restrict__ out, const float* __restrict__ scale,
    const float* __restrict__ shift)
{
    int idx = blockIdx.x * blockDim.x + threadIdx.x;
    const int total = N_NODES * (DIM / 4);
    for (int f = idx; f < total; f += gridDim.x * blockDim.x) {
        float4 v = ((float4*)out)[f];
        int c = (f * 4) & (DIM - 1);
        float4 sc = *(const float4*)(scale + c);
        float4 sh = *(const float4*)(shift + c);
        v.x = fmaxf(v.x * sc.x + sh.x, 0.0f);
        v.y = fmaxf(v.y * sc.y + sh.y, 0.0f);
        v.z = fmaxf(v.z * sc.z + sh.z, 0.0f);
        v.w = fmaxf(v.w * sc.w + sh.w, 0.0f);
        ((float4*)out)[f] = v;
    }
}

extern "C" void kernel_launch(void* const* d_in, const int* in_sizes, int n_in,
                              void* d_out, int out_size, void* d_ws, size_t ws_size,
                              hipStream_t stream)
{
    const float* x    = (const float*)d_in[0];
    const int*   ei   = (const int*)  d_in[1];
    const float* ea   = (const float*)d_in[2];
    const int*   vi   = (const int*)  d_in[3];
    const float* vea  = (const float*)d_in[4];
    const float* epsd = (const float*)d_in[5];
    const float* W1d  = (const float*)d_in[6];
    const float* b1d  = (const float*)d_in[7];
    const float* g1d  = (const float*)d_in[8];
    const float* bt1d = (const float*)d_in[9];
    const float* W2d  = (const float*)d_in[10];
    const float* b2d  = (const float*)d_in[11];
    const float* epsu = (const float*)d_in[12];
    const float* W1u  = (const float*)d_in[13];
    const float* b1u  = (const float*)d_in[14];
    const float* g1u  = (const float*)d_in[15];
    const float* bt1u = (const float*)d_in[16];
    const float* W2u  = (const float*)d_in[17];
    const float* b2u  = (const float*)d_in[18];
    const float* bng  = (const float*)d_in[19];
    const float* bnb  = (const float*)d_in[20];
    const float* a1   = (const float*)d_in[21];
    const float* a2   = (const float*)d_in[22];

    float* out = (float*)d_out;

    // workspace layout
    float*          aggr   = (float*)d_ws;                                   // [N, D] f32
    unsigned short* t1     = (unsigned short*)(aggr + (size_t)N_NODES * DIM);// [N, D] bf16
    float*          ssum   = (float*)(t1 + (size_t)N_NODES * DIM);           // [NSLOT*D]
    float*          ssq    = ssum + NSLOT * DIM;                             // [NSLOT*D]
    float*          sscale = ssq + NSLOT * DIM;                              // [D]
    float*          sshift = sscale + DIM;                                   // [D]
    unsigned short* Wt     = (unsigned short*)(sshift + DIM);                // 4 x [D, D] bf16
    int*            offsets = (int*)(Wt + 4 * (size_t)DIM * DIM);            // [N+1]
    int*            cursor  = offsets + (N_NODES + 1);                       // [N]
    int*            sorted  = cursor + N_NODES;                              // [NE]
    int*            srcs    = sorted + NE;                                   // [NE]

    size_t need = (size_t)((char*)(srcs + NE) - (char*)d_ws);
    bool use_csr = ws_size >= need;

    unsigned short* Wt1d = Wt;
    unsigned short* Wt2d = Wt + (size_t)DIM * DIM;
    unsigned short* Wt1u = Wt + 2 * (size_t)DIM * DIM;
    unsigned short* Wt2u = Wt + 3 * (size_t)DIM * DIM;

    prepw_kernel<<<DIM, 256, 0, stream>>>(W1d, Wt1d);
    prepw_kernel<<<DIM, 256, 0, stream>>>(W2d, Wt2d);
    prepw_kernel<<<DIM, 256, 0, stream>>>(W1u, Wt1u);
    prepw_kernel<<<DIM, 256, 0, stream>>>(W2u, Wt2u);

    const int gemm_grid = (N_NODES + BM - 1) / BM;
    const int gather_grid = (N_NODES + 3) / 4;

    for (int path = 0; path < 2; path++) {
        const int*   idx = path == 0 ? ei   : vi;
        const float* eat = path == 0 ? ea   : vea;
        const int    E   = path == 0 ? NE   : NEV;
        const float* eps = path == 0 ? epsd : epsu;
        unsigned short* W1t = path == 0 ? Wt1d : Wt1u;
        const float* b1  = path == 0 ? b1d  : b1u;
        const float* g1  = path == 0 ? g1d  : g1u;
        const float* bt1 = path == 0 ? bt1d : bt1u;
        unsigned short* W2t = path == 0 ? Wt2d : Wt2u;
        const float* b2  = path == 0 ? b2d  : b2u;
        const float* bse = path == 0 ? x    : out;
        const float* alp = path == 0 ? a1   : a2;

        if (use_csr) {
            hipMemsetAsync(offsets, 0, (N_NODES + 1) * sizeof(int), stream);
            hist_kernel<<<(E + 255) / 256, 256, 0, stream>>>(idx, E, offsets);
            scan_kernel<<<1, 1024, 0, stream>>>(offsets, cursor, E);
            fill_kernel<<<(E + 255) / 256, 256, 0, stream>>>(idx, E, cursor, sorted, srcs);
            gather_kernel<<<gather_grid, 256, 0, stream>>>(x, eat, offsets, sorted, srcs, aggr);
        } else {
            hipMemsetAsync(aggr, 0, (size_t)N_NODES * DIM * sizeof(float), stream);
            scatter_kernel<<<(E + 3) / 4, 256, 0, stream>>>(x, eat, idx, E, aggr);
        }
        hipMemsetAsync(ssum, 0, 2 * NSLOT * DIM * sizeof(float), stream);
        gemm1_mfma<<<gemm_grid, 256, 0, stream>>>(x, aggr, W1t, b1, eps, t1, ssum, ssq);
        finalize_kernel<<<1, 256, 0, stream>>>(ssum, ssq, g1, bt1, sscale, sshift);
        if (path == 1) hipMemsetAsync(ssum, 0, 2 * NSLOT * DIM * sizeof(float), stream);
        gemm2_mfma<<<gemm_grid, 256, 0, stream>>>(t1, sscale, sshift, W2t, b2, bse, alp, out,
                                                  path == 1 ? 1 : 0, ssum, ssq);
    }

    finalize_kernel<<<1, 256, 0, stream>>>(ssum, ssq, bng, bnb, sscale, sshift);
    bnrelu_kernel<<<2048, 256, 0, stream>>>(out, sscale, sshift);
}

// Round 5
// 525.311 us; speedup vs baseline: 3.8432x; 1.3309x over previous
//
#include <hip/hip_runtime.h>
#include <math.h>

#define N_NODES 50000
#define DIM 256
#define NE 300000
#define NEV 100000
#define BM 64
#define BK 64
#define NT 16          // DIM/16 col-tiles
#define NSLOT 8

typedef float f32x4 __attribute__((ext_vector_type(4)));
typedef short s16x8 __attribute__((ext_vector_type(8)));

__device__ inline unsigned short f2bf(float f) {
    unsigned u = __float_as_uint(f);
    u += 0x7FFF + ((u >> 16) & 1);            // round-to-nearest-even
    return (unsigned short)(u >> 16);
}
__device__ inline float bf2f(unsigned short s) {
    return __uint_as_float(((unsigned)s) << 16);
}
// swizzled halfword offset inside a [R][64] bf16 tile (16B granules, T2 XOR)
__device__ inline int swz(int row, int kg) {
    return row * BK + ((kg ^ (row & 7)) << 3);
}

// ---------------------------------------------------------------------------
// all 4 weights: W [K][N] fp32 -> Wt [N][K] bf16, one launch
// ---------------------------------------------------------------------------
__global__ __launch_bounds__(256) void prepw_kernel(
    const float* __restrict__ W1d, const float* __restrict__ W2d,
    const float* __restrict__ W1u, const float* __restrict__ W2u,
    unsigned short* __restrict__ Wt)
{
    int b = blockIdx.x;
    int w = b >> 8, n = b & 255, k = threadIdx.x;
    const float* W = (w == 0) ? W1d : (w == 1) ? W2d : (w == 2) ? W1u : W2u;
    Wt[(size_t)w * DIM * DIM + (size_t)n * DIM + k] = f2bf(W[(size_t)k * DIM + n]);
}

// ---------------------------------------------------------------------------
// CSR build for BOTH edge sets in single launches
// ---------------------------------------------------------------------------
__global__ __launch_bounds__(256) void hist2_kernel(
    const int* __restrict__ ei, const int* __restrict__ vi,
    int* __restrict__ degD, int* __restrict__ degU)
{
    int i = blockIdx.x * blockDim.x + threadIdx.x;
    if (i < NE) atomicAdd(&degD[ei[NE + i]], 1);
    else if (i < NE + NEV) { int j = i - NE; atomicAdd(&degU[vi[NEV + j]], 1); }
}

__global__ __launch_bounds__(1024) void scan2_kernel(
    int* __restrict__ offD, int* __restrict__ curD,
    int* __restrict__ offU, int* __restrict__ curU)
{
    int* deg_offsets = (blockIdx.x == 0) ? offD : offU;
    int* cursor      = (blockIdx.x == 0) ? curD : curU;
    int E            = (blockIdx.x == 0) ? NE : NEV;
    __shared__ int part[1024];
    int t = threadIdx.x;
    const int CH = (N_NODES + 1023) / 1024;
    int beg = t * CH;
    int end = min(beg + CH, N_NODES);
    int s = 0;
    for (int i = beg; i < end; i++) s += deg_offsets[i];
    part[t] = s;
    __syncthreads();
    for (int off = 1; off < 1024; off <<= 1) {
        int v = part[t];
        int u = (t >= off) ? part[t - off] : 0;
        __syncthreads();
        part[t] = v + u;
        __syncthreads();
    }
    int run = (t > 0) ? part[t - 1] : 0;
    for (int i = beg; i < end; i++) {
        int dv = deg_offsets[i];
        deg_offsets[i] = run;
        cursor[i] = run;
        run += dv;
    }
    if (t == 1023) deg_offsets[N_NODES] = E;
}

__global__ __launch_bounds__(256) void fill2_kernel(
    const int* __restrict__ ei, const int* __restrict__ vi,
    int* __restrict__ curD, int* __restrict__ curU,
    int* __restrict__ sortedD, int* __restrict__ srcsD,
    int* __restrict__ sortedU, int* __restrict__ srcsU)
{
    int i = blockIdx.x * blockDim.x + threadIdx.x;
    if (i < NE) {
        int s = ei[i], d = ei[NE + i];
        int pos = atomicAdd(&curD[d], 1);
        sortedD[pos] = i; srcsD[pos] = s;
    } else if (i < NE + NEV) {
        int j = i - NE;
        int s = vi[j], d = vi[NEV + j];
        int pos = atomicAdd(&curU[d], 1);
        sortedU[pos] = j; srcsU[pos] = s;
    }
}

// ---------------------------------------------------------------------------
// combined gather: one wave per (path,node); emits h = bf16((1+eps)x + aggr)
// ---------------------------------------------------------------------------
__global__ __launch_bounds__(256) void gather2_kernel(
    const float* __restrict__ x, const float* __restrict__ ea,
    const float* __restrict__ vea,
    const int* __restrict__ offD, const int* __restrict__ sortedD,
    const int* __restrict__ srcsD,
    const int* __restrict__ offU, const int* __restrict__ sortedU,
    const int* __restrict__ srcsU,
    const float* __restrict__ epsd, const float* __restrict__ epsu,
    unsigned short* __restrict__ hD, unsigned short* __restrict__ hU)
{
    int wid = blockIdx.x * (blockDim.x >> 6) + (threadIdx.x >> 6);
    int lane = threadIdx.x & 63;
    if (wid >= 2 * N_NODES) return;
    bool down = wid < N_NODES;
    int node = down ? wid : wid - N_NODES;
    const int* off      = down ? offD    : offU;
    const int* sorted   = down ? sortedD : sortedU;
    const int* srcs     = down ? srcsD   : srcsU;
    const float* eat    = down ? ea      : vea;
    unsigned short* h   = down ? hD      : hU;
    float epsv = 1.0f + (down ? epsd[0] : epsu[0]);

    int beg = off[node], end = off[node + 1];
    float4 acc = make_float4(0.f, 0.f, 0.f, 0.f);
    int p = beg;
    for (; p + 1 < end; p += 2) {
        int e0 = sorted[p],     s0 = srcs[p];
        int e1 = sorted[p + 1], s1 = srcs[p + 1];
        float4 a0 = ((const float4*)(x + (size_t)s0 * DIM))[lane];
        float4 b0 = ((const float4*)(eat + (size_t)e0 * DIM))[lane];
        float4 a1 = ((const float4*)(x + (size_t)s1 * DIM))[lane];
        float4 b1 = ((const float4*)(eat + (size_t)e1 * DIM))[lane];
        acc.x += fmaxf(a0.x + b0.x, 0.f) + fmaxf(a1.x + b1.x, 0.f);
        acc.y += fmaxf(a0.y + b0.y, 0.f) + fmaxf(a1.y + b1.y, 0.f);
        acc.z += fmaxf(a0.z + b0.z, 0.f) + fmaxf(a1.z + b1.z, 0.f);
        acc.w += fmaxf(a0.w + b0.w, 0.f) + fmaxf(a1.w + b1.w, 0.f);
    }
    if (p < end) {
        int e0 = sorted[p], s0 = srcs[p];
        float4 a0 = ((const float4*)(x + (size_t)s0 * DIM))[lane];
        float4 b0 = ((const float4*)(eat + (size_t)e0 * DIM))[lane];
        acc.x += fmaxf(a0.x + b0.x, 0.f);
        acc.y += fmaxf(a0.y + b0.y, 0.f);
        acc.z += fmaxf(a0.z + b0.z, 0.f);
        acc.w += fmaxf(a0.w + b0.w, 0.f);
    }
    float4 xv = ((const float4*)(x + (size_t)node * DIM))[lane];
    acc.x = fmaf(epsv, xv.x, acc.x);
    acc.y = fmaf(epsv, xv.y, acc.y);
    acc.z = fmaf(epsv, xv.z, acc.z);
    acc.w = fmaf(epsv, xv.w, acc.w);
    ushort4 pk;
    pk.x = f2bf(acc.x); pk.y = f2bf(acc.y);
    pk.z = f2bf(acc.z); pk.w = f2bf(acc.w);
    *(ushort4*)(h + (size_t)node * DIM + lane * 4) = pk;
}

// ---------------------------------------------------------------------------
// FALLBACK: atomic scatter into f32 aggr + convert kernel
// ---------------------------------------------------------------------------
__global__ __launch_bounds__(256) void scatter_kernel(
    const float* __restrict__ x, const float* __restrict__ ea,
    const int* __restrict__ idx, int E, float* __restrict__ buf)
{
    int wid = blockIdx.x * (blockDim.x >> 6) + (threadIdx.x >> 6);
    int lane = threadIdx.x & 63;
    if (wid >= E) return;
    int s = idx[wid];
    int d = idx[E + wid];
    float4 a = ((const float4*)(x + (size_t)s * DIM))[lane];
    float4 b = ((const float4*)(ea + (size_t)wid * DIM))[lane];
    float* dst = buf + (size_t)d * DIM + lane * 4;
    atomicAdd(dst + 0, fmaxf(a.x + b.x, 0.f));
    atomicAdd(dst + 1, fmaxf(a.y + b.y, 0.f));
    atomicAdd(dst + 2, fmaxf(a.z + b.z, 0.f));
    atomicAdd(dst + 3, fmaxf(a.w + b.w, 0.f));
}

__global__ __launch_bounds__(256) void conv_kernel(
    const float* __restrict__ x, const float* __restrict__ aggr,
    const float* __restrict__ eps_p, unsigned short* __restrict__ h)
{
    float epsv = 1.0f + eps_p[0];
    int i = blockIdx.x * blockDim.x + threadIdx.x;
    const int total = N_NODES * (DIM / 4);
    for (int f = i; f < total; f += gridDim.x * blockDim.x) {
        float4 xv = ((const float4*)x)[f];
        float4 av = ((const float4*)aggr)[f];
        ushort4 pk;
        pk.x = f2bf(fmaf(epsv, xv.x, av.x));
        pk.y = f2bf(fmaf(epsv, xv.y, av.y));
        pk.z = f2bf(fmaf(epsv, xv.z, av.z));
        pk.w = f2bf(fmaf(epsv, xv.w, av.w));
        ((ushort4*)h)[f] = pk;
    }
}

// ---------------------------------------------------------------------------
// MFMA GEMM stage 1: t1(bf16) = h @ W1 + b1, col stats into NSLOT ssum/ssq
// A-stage is now a pure bf16 copy (h already holds (1+eps)x + aggr).
// ---------------------------------------------------------------------------
__global__ __launch_bounds__(256) void gemm1_mfma(
    const unsigned short* __restrict__ h,
    const unsigned short* __restrict__ Wt, const float* __restrict__ bias,
    unsigned short* __restrict__ t1,
    float* __restrict__ ssum, float* __restrict__ ssq)
{
    __shared__ unsigned short As[BM * BK];
    __shared__ unsigned short Bs[DIM * BK];
    __shared__ float sLds[4 * DIM];
    __shared__ float qLds[4 * DIM];
    int t = threadIdx.x;
    int w = t >> 6, l = t & 63, lrow = l & 15, kgrp = l >> 4;
    int row0 = blockIdx.x * BM;

    f32x4 acc[NT];
    #pragma unroll
    for (int nt = 0; nt < NT; ++nt) acc[nt] = (f32x4){0.f, 0.f, 0.f, 0.f};

    for (int k0 = 0; k0 < DIM; k0 += BK) {
        __syncthreads();
        #pragma unroll
        for (int it = 0; it < 2; ++it) {
            int g = it * 256 + t, row = g >> 3, kg = g & 7;
            int gr = row0 + row;
            s16x8 v = {0, 0, 0, 0, 0, 0, 0, 0};
            if (gr < N_NODES)
                v = *(const s16x8*)&h[(size_t)gr * DIM + k0 + kg * 8];
            *(s16x8*)&As[swz(row, kg)] = v;
        }
        #pragma unroll
        for (int it = 0; it < 8; ++it) {
            int g = it * 256 + t, row = g >> 3, kg = g & 7;
            s16x8 v = *(const s16x8*)&Wt[(size_t)row * DIM + k0 + kg * 8];
            *(s16x8*)&Bs[swz(row, kg)] = v;
        }
        __syncthreads();
        int arow = w * 16 + lrow;
        s16x8 af0 = *(const s16x8*)&As[swz(arow, kgrp)];
        s16x8 af1 = *(const s16x8*)&As[swz(arow, 4 + kgrp)];
        #pragma unroll
        for (int nt = 0; nt < NT; ++nt) {
            int col = nt * 16 + lrow;
            s16x8 bf0 = *(const s16x8*)&Bs[swz(col, kgrp)];
            s16x8 bf1 = *(const s16x8*)&Bs[swz(col, 4 + kgrp)];
            acc[nt] = __builtin_amdgcn_mfma_f32_16x16x32_bf16(af0, bf0, acc[nt], 0, 0, 0);
            acc[nt] = __builtin_amdgcn_mfma_f32_16x16x32_bf16(af1, bf1, acc[nt], 0, 0, 0);
        }
    }
    #pragma unroll
    for (int nt = 0; nt < NT; ++nt) {
        int col = nt * 16 + lrow;
        float bv = bias[col];
        float s = 0.f, q = 0.f;
        #pragma unroll
        for (int r = 0; r < 4; ++r) {
            int grow = row0 + w * 16 + kgrp * 4 + r;
            if (grow < N_NODES) {
                float v = acc[nt][r] + bv;
                t1[(size_t)grow * DIM + col] = f2bf(v);
                s += v; q += v * v;
            }
        }
        s += __shfl_xor(s, 16); q += __shfl_xor(q, 16);
        s += __shfl_xor(s, 32); q += __shfl_xor(q, 32);
        if (kgrp == 0) { sLds[w * DIM + col] = s; qLds[w * DIM + col] = q; }
    }
    __syncthreads();
    {
        float s = sLds[t] + sLds[DIM + t] + sLds[2 * DIM + t] + sLds[3 * DIM + t];
        float q = qLds[t] + qLds[DIM + t] + qLds[2 * DIM + t] + qLds[3 * DIM + t];
        int slot = blockIdx.x & (NSLOT - 1);
        atomicAdd(&ssum[slot * DIM + t], s);
        atomicAdd(&ssq[slot * DIM + t], q);
    }
}

// ---------------------------------------------------------------------------
// MFMA GEMM stage 2: C = relu(t1*scale+shift) @ W2 + b2; out = base + alpha*C
// ---------------------------------------------------------------------------
__global__ __launch_bounds__(256) void gemm2_mfma(
    const unsigned short* __restrict__ t1, const float* __restrict__ scale,
    const float* __restrict__ shift, const unsigned short* __restrict__ Wt,
    const float* __restrict__ bias, const float* __restrict__ base,
    const float* __restrict__ alpha_p, float* __restrict__ out, int do_stats,
    float* __restrict__ ssum, float* __restrict__ ssq)
{
    __shared__ unsigned short As[BM * BK];
    __shared__ unsigned short Bs[DIM * BK];
    __shared__ float sLds[4 * DIM];
    __shared__ float qLds[4 * DIM];
    int t = threadIdx.x;
    int w = t >> 6, l = t & 63, lrow = l & 15, kgrp = l >> 4;
    int row0 = blockIdx.x * BM;

    f32x4 acc[NT];
    #pragma unroll
    for (int nt = 0; nt < NT; ++nt) acc[nt] = (f32x4){0.f, 0.f, 0.f, 0.f};

    for (int k0 = 0; k0 < DIM; k0 += BK) {
        __syncthreads();
        #pragma unroll
        for (int it = 0; it < 2; ++it) {
            int g = it * 256 + t, row = g >> 3, kg = g & 7;
            int gr = row0 + row;
            s16x8 pack = {0, 0, 0, 0, 0, 0, 0, 0};
            if (gr < N_NODES) {
                s16x8 tv = *(const s16x8*)(t1 + (size_t)gr * DIM + k0 + kg * 8);
                const float4* scp = (const float4*)(scale + k0 + kg * 8);
                const float4* shp = (const float4*)(shift + k0 + kg * 8);
                float4 s0 = scp[0], s1 = scp[1], h0 = shp[0], h1 = shp[1];
                pack[0] = f2bf(fmaxf(fmaf(bf2f((unsigned short)tv[0]), s0.x, h0.x), 0.f));
                pack[1] = f2bf(fmaxf(fmaf(bf2f((unsigned short)tv[1]), s0.y, h0.y), 0.f));
                pack[2] = f2bf(fmaxf(fmaf(bf2f((unsigned short)tv[2]), s0.z, h0.z), 0.f));
                pack[3] = f2bf(fmaxf(fmaf(bf2f((unsigned short)tv[3]), s0.w, h0.w), 0.f));
                pack[4] = f2bf(fmaxf(fmaf(bf2f((unsigned short)tv[4]), s1.x, h1.x), 0.f));
                pack[5] = f2bf(fmaxf(fmaf(bf2f((unsigned short)tv[5]), s1.y, h1.y), 0.f));
                pack[6] = f2bf(fmaxf(fmaf(bf2f((unsigned short)tv[6]), s1.z, h1.z), 0.f));
                pack[7] = f2bf(fmaxf(fmaf(bf2f((unsigned short)tv[7]), s1.w, h1.w), 0.f));
            }
            *(s16x8*)&As[swz(row, kg)] = pack;
        }
        #pragma unroll
        for (int it = 0; it < 8; ++it) {
            int g = it * 256 + t, row = g >> 3, kg = g & 7;
            s16x8 v = *(const s16x8*)&Wt[(size_t)row * DIM + k0 + kg * 8];
            *(s16x8*)&Bs[swz(row, kg)] = v;
        }
        __syncthreads();
        int arow = w * 16 + lrow;
        s16x8 af0 = *(const s16x8*)&As[swz(arow, kgrp)];
        s16x8 af1 = *(const s16x8*)&As[swz(arow, 4 + kgrp)];
        #pragma unroll
        for (int nt = 0; nt < NT; ++nt) {
            int col = nt * 16 + lrow;
            s16x8 bf0 = *(const s16x8*)&Bs[swz(col, kgrp)];
            s16x8 bf1 = *(const s16x8*)&Bs[swz(col, 4 + kgrp)];
            acc[nt] = __builtin_amdgcn_mfma_f32_16x16x32_bf16(af0, bf0, acc[nt], 0, 0, 0);
            acc[nt] = __builtin_amdgcn_mfma_f32_16x16x32_bf16(af1, bf1, acc[nt], 0, 0, 0);
        }
    }
    float alphav = alpha_p[0];
    #pragma unroll
    for (int nt = 0; nt < NT; ++nt) {
        int col = nt * 16 + lrow;
        float bv = bias[col];
        float s = 0.f, q = 0.f;
        #pragma unroll
        for (int r = 0; r < 4; ++r) {
            int grow = row0 + w * 16 + kgrp * 4 + r;
            if (grow < N_NODES) {
                size_t o = (size_t)grow * DIM + col;
                float v = fmaf(alphav, acc[nt][r] + bv, base[o]);
                out[o] = v;
                s += v; q += v * v;
            }
        }
        if (do_stats) {
            s += __shfl_xor(s, 16); q += __shfl_xor(q, 16);
            s += __shfl_xor(s, 32); q += __shfl_xor(q, 32);
            if (kgrp == 0) { sLds[w * DIM + col] = s; qLds[w * DIM + col] = q; }
        }
    }
    if (do_stats) {
        __syncthreads();
        float s = sLds[t] + sLds[DIM + t] + sLds[2 * DIM + t] + sLds[3 * DIM + t];
        float q = qLds[t] + qLds[DIM + t] + qLds[2 * DIM + t] + qLds[3 * DIM + t];
        int slot = blockIdx.x & (NSLOT - 1);
        atomicAdd(&ssum[slot * DIM + t], s);
        atomicAdd(&ssq[slot * DIM + t], q);
    }
}

// ---------------------------------------------------------------------------
// BN finalize (sums NSLOT slots) + elementwise BN/ReLU
// ---------------------------------------------------------------------------
__global__ void finalize_kernel(
    const float* __restrict__ ssum, const float* __restrict__ ssq,
    const float* __restrict__ g, const float* __restrict__ b,
    float* __restrict__ scale, float* __restrict__ shift)
{
    int c = threadIdx.x;
    float s = 0.f, q = 0.f;
    #pragma unroll
    for (int k = 0; k < NSLOT; ++k) { s += ssum[k * DIM + c]; q += ssq[k * DIM + c]; }
    const float invN = 1.0f / (float)N_NODES;
    float mu = s * invN;
    float var = q * invN - mu * mu;
    float sc = g[c] * rsqrtf(var + 1e-5f);
    scale[c] = sc;
    shift[c] = b[c] - mu * sc;
}

__global__ __launch_bounds__(256) void bnrelu_kernel(
    float* __restrict__ out, const float* __restrict__ scale,
    const float* __restrict__ shift)
{
    int idx = blockIdx.x * blockDim.x + threadIdx.x;
    const int total = N_NODES * (DIM / 4);
    for (int f = idx; f < total; f += gridDim.x * blockDim.x) {
        float4 v = ((float4*)out)[f];
        int c = (f * 4) & (DIM - 1);
        float4 sc = *(const float4*)(scale + c);
        float4 sh = *(const float4*)(shift + c);
        v.x = fmaxf(v.x * sc.x + sh.x, 0.0f);
        v.y = fmaxf(v.y * sc.y + sh.y, 0.0f);
        v.z = fmaxf(v.z * sc.z + sh.z, 0.0f);
        v.w = fmaxf(v.w * sc.w + sh.w, 0.0f);
        ((float4*)out)[f] = v;
    }
}

extern "C" void kernel_launch(void* const* d_in, const int* in_sizes, int n_in,
                              void* d_out, int out_size, void* d_ws, size_t ws_size,
                              hipStream_t stream)
{
    const float* x    = (const float*)d_in[0];
    const int*   ei   = (const int*)  d_in[1];
    const float* ea   = (const float*)d_in[2];
    const int*   vi   = (const int*)  d_in[3];
    const float* vea  = (const float*)d_in[4];
    const float* epsd = (const float*)d_in[5];
    const float* W1d  = (const float*)d_in[6];
    const float* b1d  = (const float*)d_in[7];
    const float* g1d  = (const float*)d_in[8];
    const float* bt1d = (const float*)d_in[9];
    const float* W2d  = (const float*)d_in[10];
    const float* b2d  = (const float*)d_in[11];
    const float* epsu = (const float*)d_in[12];
    const float* W1u  = (const float*)d_in[13];
    const float* b1u  = (const float*)d_in[14];
    const float* g1u  = (const float*)d_in[15];
    const float* bt1u = (const float*)d_in[16];
    const float* W2u  = (const float*)d_in[17];
    const float* b2u  = (const float*)d_in[18];
    const float* bng  = (const float*)d_in[19];
    const float* bnb  = (const float*)d_in[20];
    const float* a1   = (const float*)d_in[21];
    const float* a2   = (const float*)d_in[22];

    float* out = (float*)d_out;

    // ---- workspace layout (bytes via char*) ----
    char* p = (char*)d_ws;
    unsigned short* hD = (unsigned short*)p;  p += (size_t)N_NODES * DIM * 2;
    unsigned short* hU = (unsigned short*)p;  p += (size_t)N_NODES * DIM * 2;
    unsigned short* t1 = (unsigned short*)p;  p += (size_t)N_NODES * DIM * 2;
    unsigned short* Wt = (unsigned short*)p;  p += (size_t)4 * DIM * DIM * 2;
    float* sscale = (float*)p;                p += DIM * 4;
    float* sshift = (float*)p;                p += DIM * 4;
    // zeroed region: stats (6 slices) + offsets
    char* zero_base = p;
    float* stats = (float*)p;                 p += (size_t)6 * NSLOT * DIM * 4;
    int* offD = (int*)p;                      p += (size_t)(N_NODES + 1) * 4;
    int* offU = (int*)p;                      p += (size_t)(N_NODES + 1) * 4;
    size_t zero_bytes = (size_t)(p - zero_base);
    int* curD = (int*)p;                      p += (size_t)N_NODES * 4;
    int* curU = (int*)p;                      p += (size_t)N_NODES * 4;
    char* union_base = p;
    int* sortedD = (int*)p;                   p += (size_t)NE * 4;
    int* srcsD = (int*)p;                     p += (size_t)NE * 4;
    int* sortedU = (int*)p;                   p += (size_t)NEV * 4;
    int* srcsU = (int*)p;                     p += (size_t)NEV * 4;
    size_t need_csr = (size_t)(p - (char*)d_ws);
    float* aggr = (float*)union_base;         // fallback-only, overlaps sorted/srcs
    size_t need_fb = (size_t)(union_base - (char*)d_ws) + (size_t)N_NODES * DIM * 4;
    bool use_csr = ws_size >= need_csr;

    float* sumD = stats;
    float* sqD  = stats + 1 * NSLOT * DIM;
    float* sumU = stats + 2 * NSLOT * DIM;
    float* sqU  = stats + 3 * NSLOT * DIM;
    float* sumF = stats + 4 * NSLOT * DIM;
    float* sqF  = stats + 5 * NSLOT * DIM;

    unsigned short* Wt1d = Wt;
    unsigned short* Wt2d = Wt + 1 * (size_t)DIM * DIM;
    unsigned short* Wt1u = Wt + 2 * (size_t)DIM * DIM;
    unsigned short* Wt2u = Wt + 3 * (size_t)DIM * DIM;

    const int gemm_grid = (N_NODES + BM - 1) / BM;

    hipMemsetAsync(zero_base, 0, zero_bytes, stream);
    prepw_kernel<<<4 * DIM, 256, 0, stream>>>(W1d, W2d, W1u, W2u, Wt);

    if (use_csr) {
        hist2_kernel<<<(NE + NEV + 255) / 256, 256, 0, stream>>>(ei, vi, offD, offU);
        scan2_kernel<<<2, 1024, 0, stream>>>(offD, curD, offU, curU);
        fill2_kernel<<<(NE + NEV + 255) / 256, 256, 0, stream>>>(
            ei, vi, curD, curU, sortedD, srcsD, sortedU, srcsU);
        gather2_kernel<<<(2 * N_NODES + 3) / 4, 256, 0, stream>>>(
            x, ea, vea, offD, sortedD, srcsD, offU, sortedU, srcsU,
            epsd, epsu, hD, hU);
    } else if (ws_size >= need_fb) {
        hipMemsetAsync(aggr, 0, (size_t)N_NODES * DIM * 4, stream);
        scatter_kernel<<<(NE + 3) / 4, 256, 0, stream>>>(x, ea, ei, NE, aggr);
        conv_kernel<<<2048, 256, 0, stream>>>(x, aggr, epsd, hD);
        hipMemsetAsync(aggr, 0, (size_t)N_NODES * DIM * 4, stream);
        scatter_kernel<<<(NEV + 3) / 4, 256, 0, stream>>>(x, vea, vi, NEV, aggr);
        conv_kernel<<<2048, 256, 0, stream>>>(x, aggr, epsu, hU);
    }

    // ---- DOWN path ----
    gemm1_mfma<<<gemm_grid, 256, 0, stream>>>(hD, Wt1d, b1d, t1, sumD, sqD);
    finalize_kernel<<<1, 256, 0, stream>>>(sumD, sqD, g1d, bt1d, sscale, sshift);
    gemm2_mfma<<<gemm_grid, 256, 0, stream>>>(t1, sscale, sshift, Wt2d, b2d, x, a1, out,
                                              0, sumF, sqF);
    // ---- UP path ----
    gemm1_mfma<<<gemm_grid, 256, 0, stream>>>(hU, Wt1u, b1u, t1, sumU, sqU);
    finalize_kernel<<<1, 256, 0, stream>>>(sumU, sqU, g1u, bt1u, sscale, sshift);
    gemm2_mfma<<<gemm_grid, 256, 0, stream>>>(t1, sscale, sshift, Wt2u, b2u, out, a2, out,
                                              1, sumF, sqF);
    // ---- final BN + ReLU ----
    finalize_kernel<<<1, 256, 0, stream>>>(sumF, sqF, bng, bnb, sscale, sshift);
    bnrelu_kernel<<<2048, 256, 0, stream>>>(out, sscale, sshift);
}

// Round 6
// 508.151 us; speedup vs baseline: 3.9730x; 1.0338x over previous
//
#include <hip/hip_runtime.h>
#include <math.h>

#define N_NODES 50000
#define DIM 256
#define NE 300000
#define NEV 100000
#define BM 64
#define BK 64
#define NT 16          // DIM/16 col-tiles
#define NSLOT 8
#define GRID_PER ((N_NODES + BM - 1) / BM)   // 782

typedef float f32x4 __attribute__((ext_vector_type(4)));
typedef short s16x8 __attribute__((ext_vector_type(8)));

__device__ inline unsigned short f2bf(float f) {
    unsigned u = __float_as_uint(f);
    u += 0x7FFF + ((u >> 16) & 1);            // round-to-nearest-even
    return (unsigned short)(u >> 16);
}
__device__ inline float bf2f(unsigned short s) {
    return __uint_as_float(((unsigned)s) << 16);
}
// swizzled halfword offset inside a [R][64] bf16 tile (16B granules, T2 XOR)
__device__ inline int swz(int row, int kg) {
    return row * BK + ((kg ^ (row & 7)) << 3);
}

// ---------------------------------------------------------------------------
// all 4 weights: W [K][N] fp32 -> Wt [N][K] bf16, one launch
// ---------------------------------------------------------------------------
__global__ __launch_bounds__(256) void prepw_kernel(
    const float* __restrict__ W1d, const float* __restrict__ W2d,
    const float* __restrict__ W1u, const float* __restrict__ W2u,
    unsigned short* __restrict__ Wt)
{
    int b = blockIdx.x;
    int w = b >> 8, n = b & 255, k = threadIdx.x;
    const float* W = (w == 0) ? W1d : (w == 1) ? W2d : (w == 2) ? W1u : W2u;
    Wt[(size_t)w * DIM * DIM + (size_t)n * DIM + k] = f2bf(W[(size_t)k * DIM + n]);
}

// ---------------------------------------------------------------------------
// CSR build for BOTH edge sets in single launches; fill packs (e,src) int2
// ---------------------------------------------------------------------------
__global__ __launch_bounds__(256) void hist2_kernel(
    const int* __restrict__ ei, const int* __restrict__ vi,
    int* __restrict__ degD, int* __restrict__ degU)
{
    int i = blockIdx.x * blockDim.x + threadIdx.x;
    if (i < NE) atomicAdd(&degD[ei[NE + i]], 1);
    else if (i < NE + NEV) { int j = i - NE; atomicAdd(&degU[vi[NEV + j]], 1); }
}

__global__ __launch_bounds__(1024) void scan2_kernel(
    int* __restrict__ offD, int* __restrict__ curD,
    int* __restrict__ offU, int* __restrict__ curU)
{
    int* deg_offsets = (blockIdx.x == 0) ? offD : offU;
    int* cursor      = (blockIdx.x == 0) ? curD : curU;
    int E            = (blockIdx.x == 0) ? NE : NEV;
    __shared__ int part[1024];
    int t = threadIdx.x;
    const int CH = (N_NODES + 1023) / 1024;
    int beg = t * CH;
    int end = min(beg + CH, N_NODES);
    int s = 0;
    for (int i = beg; i < end; i++) s += deg_offsets[i];
    part[t] = s;
    __syncthreads();
    for (int off = 1; off < 1024; off <<= 1) {
        int v = part[t];
        int u = (t >= off) ? part[t - off] : 0;
        __syncthreads();
        part[t] = v + u;
        __syncthreads();
    }
    int run = (t > 0) ? part[t - 1] : 0;
    for (int i = beg; i < end; i++) {
        int dv = deg_offsets[i];
        deg_offsets[i] = run;
        cursor[i] = run;
        run += dv;
    }
    if (t == 1023) deg_offsets[N_NODES] = E;
}

__global__ __launch_bounds__(256) void fill2_kernel(
    const int* __restrict__ ei, const int* __restrict__ vi,
    int* __restrict__ curD, int* __restrict__ curU,
    int2* __restrict__ pairsD, int2* __restrict__ pairsU)
{
    int i = blockIdx.x * blockDim.x + threadIdx.x;
    if (i < NE) {
        int s = ei[i], d = ei[NE + i];
        int pos = atomicAdd(&curD[d], 1);
        pairsD[pos] = make_int2(i, s);
    } else if (i < NE + NEV) {
        int j = i - NE;
        int s = vi[j], d = vi[NEV + j];
        int pos = atomicAdd(&curU[d], 1);
        pairsU[pos] = make_int2(j, s);
    }
}

// ---------------------------------------------------------------------------
// combined gather: one wave per (path,node); 4-edge unroll for MLP;
// nontemporal loads on the single-use edge stream; emits bf16 h.
// ---------------------------------------------------------------------------
__device__ inline f32x4 ld4(const float* p) { return *(const f32x4*)p; }
__device__ inline f32x4 ldnt4(const float* p) {
    return __builtin_nontemporal_load((const f32x4*)p);
}
__device__ inline void acc_relu(f32x4& acc, f32x4 a, f32x4 b) {
    acc.x += fmaxf(a.x + b.x, 0.f);
    acc.y += fmaxf(a.y + b.y, 0.f);
    acc.z += fmaxf(a.z + b.z, 0.f);
    acc.w += fmaxf(a.w + b.w, 0.f);
}

__global__ __launch_bounds__(256) void gather2_kernel(
    const float* __restrict__ x, const float* __restrict__ ea,
    const float* __restrict__ vea,
    const int* __restrict__ offD, const int2* __restrict__ pairsD,
    const int* __restrict__ offU, const int2* __restrict__ pairsU,
    const float* __restrict__ epsd, const float* __restrict__ epsu,
    unsigned short* __restrict__ hD, unsigned short* __restrict__ hU)
{
    int wid = blockIdx.x * (blockDim.x >> 6) + (threadIdx.x >> 6);
    int lane = threadIdx.x & 63;
    if (wid >= 2 * N_NODES) return;
    bool down = wid < N_NODES;
    int node = down ? wid : wid - N_NODES;
    const int* off      = down ? offD   : offU;
    const int2* pairs   = down ? pairsD : pairsU;
    const float* eat    = down ? ea     : vea;
    unsigned short* h   = down ? hD     : hU;
    float epsv = 1.0f + (down ? epsd[0] : epsu[0]);

    int beg = off[node], end = off[node + 1];
    f32x4 acc = {0.f, 0.f, 0.f, 0.f};
    int cofs = lane * 4;
    int p = beg;
    for (; p + 3 < end; p += 4) {
        int2 q0 = pairs[p], q1 = pairs[p + 1], q2 = pairs[p + 2], q3 = pairs[p + 3];
        f32x4 a0 = ld4(x + (size_t)q0.y * DIM + cofs);
        f32x4 b0 = ldnt4(eat + (size_t)q0.x * DIM + cofs);
        f32x4 a1 = ld4(x + (size_t)q1.y * DIM + cofs);
        f32x4 b1 = ldnt4(eat + (size_t)q1.x * DIM + cofs);
        f32x4 a2 = ld4(x + (size_t)q2.y * DIM + cofs);
        f32x4 b2 = ldnt4(eat + (size_t)q2.x * DIM + cofs);
        f32x4 a3 = ld4(x + (size_t)q3.y * DIM + cofs);
        f32x4 b3 = ldnt4(eat + (size_t)q3.x * DIM + cofs);
        acc_relu(acc, a0, b0);
        acc_relu(acc, a1, b1);
        acc_relu(acc, a2, b2);
        acc_relu(acc, a3, b3);
    }
    for (; p + 1 < end; p += 2) {
        int2 q0 = pairs[p], q1 = pairs[p + 1];
        f32x4 a0 = ld4(x + (size_t)q0.y * DIM + cofs);
        f32x4 b0 = ldnt4(eat + (size_t)q0.x * DIM + cofs);
        f32x4 a1 = ld4(x + (size_t)q1.y * DIM + cofs);
        f32x4 b1 = ldnt4(eat + (size_t)q1.x * DIM + cofs);
        acc_relu(acc, a0, b0);
        acc_relu(acc, a1, b1);
    }
    if (p < end) {
        int2 q0 = pairs[p];
        f32x4 a0 = ld4(x + (size_t)q0.y * DIM + cofs);
        f32x4 b0 = ldnt4(eat + (size_t)q0.x * DIM + cofs);
        acc_relu(acc, a0, b0);
    }
    f32x4 xv = ld4(x + (size_t)node * DIM + cofs);
    acc.x = fmaf(epsv, xv.x, acc.x);
    acc.y = fmaf(epsv, xv.y, acc.y);
    acc.z = fmaf(epsv, xv.z, acc.z);
    acc.w = fmaf(epsv, xv.w, acc.w);
    ushort4 pk;
    pk.x = f2bf(acc.x); pk.y = f2bf(acc.y);
    pk.z = f2bf(acc.z); pk.w = f2bf(acc.w);
    *(ushort4*)(h + (size_t)node * DIM + cofs) = pk;
}

// ---------------------------------------------------------------------------
// FALLBACK: atomic scatter into f32 aggr + convert kernel
// ---------------------------------------------------------------------------
__global__ __launch_bounds__(256) void scatter_kernel(
    const float* __restrict__ x, const float* __restrict__ ea,
    const int* __restrict__ idx, int E, float* __restrict__ buf)
{
    int wid = blockIdx.x * (blockDim.x >> 6) + (threadIdx.x >> 6);
    int lane = threadIdx.x & 63;
    if (wid >= E) return;
    int s = idx[wid];
    int d = idx[E + wid];
    float4 a = ((const float4*)(x + (size_t)s * DIM))[lane];
    float4 b = ((const float4*)(ea + (size_t)wid * DIM))[lane];
    float* dst = buf + (size_t)d * DIM + lane * 4;
    atomicAdd(dst + 0, fmaxf(a.x + b.x, 0.f));
    atomicAdd(dst + 1, fmaxf(a.y + b.y, 0.f));
    atomicAdd(dst + 2, fmaxf(a.z + b.z, 0.f));
    atomicAdd(dst + 3, fmaxf(a.w + b.w, 0.f));
}

__global__ __launch_bounds__(256) void conv_kernel(
    const float* __restrict__ x, const float* __restrict__ aggr,
    const float* __restrict__ eps_p, unsigned short* __restrict__ h)
{
    float epsv = 1.0f + eps_p[0];
    int i = blockIdx.x * blockDim.x + threadIdx.x;
    const int total = N_NODES * (DIM / 4);
    for (int f = i; f < total; f += gridDim.x * blockDim.x) {
        float4 xv = ((const float4*)x)[f];
        float4 av = ((const float4*)aggr)[f];
        ushort4 pk;
        pk.x = f2bf(fmaf(epsv, xv.x, av.x));
        pk.y = f2bf(fmaf(epsv, xv.y, av.y));
        pk.z = f2bf(fmaf(epsv, xv.z, av.z));
        pk.w = f2bf(fmaf(epsv, xv.w, av.w));
        ((ushort4*)h)[f] = pk;
    }
}

// ---------------------------------------------------------------------------
// MFMA GEMM stage 1 (BOTH paths, one launch):
//   t1{D,U}(bf16) = h{D,U} @ W1{d,u} + b1{d,u}, col stats into NSLOT slots
// ---------------------------------------------------------------------------
__global__ __launch_bounds__(256) void gemm1_both(
    const unsigned short* __restrict__ hD, const unsigned short* __restrict__ hU,
    const unsigned short* __restrict__ Wt1d, const unsigned short* __restrict__ Wt1u,
    const float* __restrict__ b1d, const float* __restrict__ b1u,
    unsigned short* __restrict__ t1D, unsigned short* __restrict__ t1U,
    float* __restrict__ sumD, float* __restrict__ sqD,
    float* __restrict__ sumU, float* __restrict__ sqU)
{
    __shared__ unsigned short As[BM * BK];
    __shared__ unsigned short Bs[DIM * BK];
    __shared__ float sLds[4 * DIM];
    __shared__ float qLds[4 * DIM];
    int blk = blockIdx.x;
    bool down = blk < GRID_PER;
    int bb = down ? blk : blk - GRID_PER;
    const unsigned short* h  = down ? hD   : hU;
    const unsigned short* Wt = down ? Wt1d : Wt1u;
    const float* bias        = down ? b1d  : b1u;
    unsigned short* t1       = down ? t1D  : t1U;
    float* ssum              = down ? sumD : sumU;
    float* ssq               = down ? sqD  : sqU;

    int t = threadIdx.x;
    int w = t >> 6, l = t & 63, lrow = l & 15, kgrp = l >> 4;
    int row0 = bb * BM;

    f32x4 acc[NT];
    #pragma unroll
    for (int nt = 0; nt < NT; ++nt) acc[nt] = (f32x4){0.f, 0.f, 0.f, 0.f};

    for (int k0 = 0; k0 < DIM; k0 += BK) {
        __syncthreads();
        #pragma unroll
        for (int it = 0; it < 2; ++it) {
            int g = it * 256 + t, row = g >> 3, kg = g & 7;
            int gr = row0 + row;
            s16x8 v = {0, 0, 0, 0, 0, 0, 0, 0};
            if (gr < N_NODES)
                v = *(const s16x8*)&h[(size_t)gr * DIM + k0 + kg * 8];
            *(s16x8*)&As[swz(row, kg)] = v;
        }
        #pragma unroll
        for (int it = 0; it < 8; ++it) {
            int g = it * 256 + t, row = g >> 3, kg = g & 7;
            s16x8 v = *(const s16x8*)&Wt[(size_t)row * DIM + k0 + kg * 8];
            *(s16x8*)&Bs[swz(row, kg)] = v;
        }
        __syncthreads();
        int arow = w * 16 + lrow;
        s16x8 af0 = *(const s16x8*)&As[swz(arow, kgrp)];
        s16x8 af1 = *(const s16x8*)&As[swz(arow, 4 + kgrp)];
        #pragma unroll
        for (int nt = 0; nt < NT; ++nt) {
            int col = nt * 16 + lrow;
            s16x8 bf0 = *(const s16x8*)&Bs[swz(col, kgrp)];
            s16x8 bf1 = *(const s16x8*)&Bs[swz(col, 4 + kgrp)];
            acc[nt] = __builtin_amdgcn_mfma_f32_16x16x32_bf16(af0, bf0, acc[nt], 0, 0, 0);
            acc[nt] = __builtin_amdgcn_mfma_f32_16x16x32_bf16(af1, bf1, acc[nt], 0, 0, 0);
        }
    }
    #pragma unroll
    for (int nt = 0; nt < NT; ++nt) {
        int col = nt * 16 + lrow;
        float bv = bias[col];
        float s = 0.f, q = 0.f;
        #pragma unroll
        for (int r = 0; r < 4; ++r) {
            int grow = row0 + w * 16 + kgrp * 4 + r;
            if (grow < N_NODES) {
                float v = acc[nt][r] + bv;
                t1[(size_t)grow * DIM + col] = f2bf(v);
                s += v; q += v * v;
            }
        }
        s += __shfl_xor(s, 16); q += __shfl_xor(q, 16);
        s += __shfl_xor(s, 32); q += __shfl_xor(q, 32);
        if (kgrp == 0) { sLds[w * DIM + col] = s; qLds[w * DIM + col] = q; }
    }
    __syncthreads();
    {
        float s = sLds[t] + sLds[DIM + t] + sLds[2 * DIM + t] + sLds[3 * DIM + t];
        float q = qLds[t] + qLds[DIM + t] + qLds[2 * DIM + t] + qLds[3 * DIM + t];
        int slot = bb & (NSLOT - 1);
        atomicAdd(&ssum[slot * DIM + t], s);
        atomicAdd(&ssq[slot * DIM + t], q);
    }
}

// ---------------------------------------------------------------------------
// MFMA GEMM stage 2: C = relu(t1*scale+shift) @ W2 + b2; out = base + alpha*C
// ---------------------------------------------------------------------------
__global__ __launch_bounds__(256) void gemm2_mfma(
    const unsigned short* __restrict__ t1, const float* __restrict__ scale,
    const float* __restrict__ shift, const unsigned short* __restrict__ Wt,
    const float* __restrict__ bias, const float* __restrict__ base,
    const float* __restrict__ alpha_p, float* __restrict__ out, int do_stats,
    float* __restrict__ ssum, float* __restrict__ ssq)
{
    __shared__ unsigned short As[BM * BK];
    __shared__ unsigned short Bs[DIM * BK];
    __shared__ float sLds[4 * DIM];
    __shared__ float qLds[4 * DIM];
    int t = threadIdx.x;
    int w = t >> 6, l = t & 63, lrow = l & 15, kgrp = l >> 4;
    int row0 = blockIdx.x * BM;

    f32x4 acc[NT];
    #pragma unroll
    for (int nt = 0; nt < NT; ++nt) acc[nt] = (f32x4){0.f, 0.f, 0.f, 0.f};

    for (int k0 = 0; k0 < DIM; k0 += BK) {
        __syncthreads();
        #pragma unroll
        for (int it = 0; it < 2; ++it) {
            int g = it * 256 + t, row = g >> 3, kg = g & 7;
            int gr = row0 + row;
            s16x8 pack = {0, 0, 0, 0, 0, 0, 0, 0};
            if (gr < N_NODES) {
                s16x8 tv = *(const s16x8*)(t1 + (size_t)gr * DIM + k0 + kg * 8);
                const float4* scp = (const float4*)(scale + k0 + kg * 8);
                const float4* shp = (const float4*)(shift + k0 + kg * 8);
                float4 s0 = scp[0], s1 = scp[1], h0 = shp[0], h1 = shp[1];
                pack[0] = f2bf(fmaxf(fmaf(bf2f((unsigned short)tv[0]), s0.x, h0.x), 0.f));
                pack[1] = f2bf(fmaxf(fmaf(bf2f((unsigned short)tv[1]), s0.y, h0.y), 0.f));
                pack[2] = f2bf(fmaxf(fmaf(bf2f((unsigned short)tv[2]), s0.z, h0.z), 0.f));
                pack[3] = f2bf(fmaxf(fmaf(bf2f((unsigned short)tv[3]), s0.w, h0.w), 0.f));
                pack[4] = f2bf(fmaxf(fmaf(bf2f((unsigned short)tv[4]), s1.x, h1.x), 0.f));
                pack[5] = f2bf(fmaxf(fmaf(bf2f((unsigned short)tv[5]), s1.y, h1.y), 0.f));
                pack[6] = f2bf(fmaxf(fmaf(bf2f((unsigned short)tv[6]), s1.z, h1.z), 0.f));
                pack[7] = f2bf(fmaxf(fmaf(bf2f((unsigned short)tv[7]), s1.w, h1.w), 0.f));
            }
            *(s16x8*)&As[swz(row, kg)] = pack;
        }
        #pragma unroll
        for (int it = 0; it < 8; ++it) {
            int g = it * 256 + t, row = g >> 3, kg = g & 7;
            s16x8 v = *(const s16x8*)&Wt[(size_t)row * DIM + k0 + kg * 8];
            *(s16x8*)&Bs[swz(row, kg)] = v;
        }
        __syncthreads();
        int arow = w * 16 + lrow;
        s16x8 af0 = *(const s16x8*)&As[swz(arow, kgrp)];
        s16x8 af1 = *(const s16x8*)&As[swz(arow, 4 + kgrp)];
        #pragma unroll
        for (int nt = 0; nt < NT; ++nt) {
            int col = nt * 16 + lrow;
            s16x8 bf0 = *(const s16x8*)&Bs[swz(col, kgrp)];
            s16x8 bf1 = *(const s16x8*)&Bs[swz(col, 4 + kgrp)];
            acc[nt] = __builtin_amdgcn_mfma_f32_16x16x32_bf16(af0, bf0, acc[nt], 0, 0, 0);
            acc[nt] = __builtin_amdgcn_mfma_f32_16x16x32_bf16(af1, bf1, acc[nt], 0, 0, 0);
        }
    }
    float alphav = alpha_p[0];
    #pragma unroll
    for (int nt = 0; nt < NT; ++nt) {
        int col = nt * 16 + lrow;
        float bv = bias[col];
        float s = 0.f, q = 0.f;
        #pragma unroll
        for (int r = 0; r < 4; ++r) {
            int grow = row0 + w * 16 + kgrp * 4 + r;
            if (grow < N_NODES) {
                size_t o = (size_t)grow * DIM + col;
                float v = fmaf(alphav, acc[nt][r] + bv, base[o]);
                out[o] = v;
                s += v; q += v * v;
            }
        }
        if (do_stats) {
            s += __shfl_xor(s, 16); q += __shfl_xor(q, 16);
            s += __shfl_xor(s, 32); q += __shfl_xor(q, 32);
            if (kgrp == 0) { sLds[w * DIM + col] = s; qLds[w * DIM + col] = q; }
        }
    }
    if (do_stats) {
        __syncthreads();
        float s = sLds[t] + sLds[DIM + t] + sLds[2 * DIM + t] + sLds[3 * DIM + t];
        float q = qLds[t] + qLds[DIM + t] + qLds[2 * DIM + t] + qLds[3 * DIM + t];
        int slot = blockIdx.x & (NSLOT - 1);
        atomicAdd(&ssum[slot * DIM + t], s);
        atomicAdd(&ssq[slot * DIM + t], q);
    }
}

// ---------------------------------------------------------------------------
// BN finalize: one (final) or two (both paths) scale/shift sets
// ---------------------------------------------------------------------------
__device__ inline void bn_finalize(
    const float* ssum, const float* ssq, const float* g, const float* b,
    float* scale, float* shift, int c)
{
    float s = 0.f, q = 0.f;
    #pragma unroll
    for (int k = 0; k < NSLOT; ++k) { s += ssum[k * DIM + c]; q += ssq[k * DIM + c]; }
    const float invN = 1.0f / (float)N_NODES;
    float mu = s * invN;
    float var = q * invN - mu * mu;
    float sc = g[c] * rsqrtf(var + 1e-5f);
    scale[c] = sc;
    shift[c] = b[c] - mu * sc;
}

__global__ void finalize2_kernel(
    const float* __restrict__ sumD, const float* __restrict__ sqD,
    const float* __restrict__ g1d, const float* __restrict__ bt1d,
    float* __restrict__ scD, float* __restrict__ shD,
    const float* __restrict__ sumU, const float* __restrict__ sqU,
    const float* __restrict__ g1u, const float* __restrict__ bt1u,
    float* __restrict__ scU, float* __restrict__ shU)
{
    int t = threadIdx.x;
    int c = t & (DIM - 1);
    if (t < DIM) bn_finalize(sumD, sqD, g1d, bt1d, scD, shD, c);
    else         bn_finalize(sumU, sqU, g1u, bt1u, scU, shU, c);
}

__global__ void finalize_kernel(
    const float* __restrict__ ssum, const float* __restrict__ ssq,
    const float* __restrict__ g, const float* __restrict__ b,
    float* __restrict__ scale, float* __restrict__ shift)
{
    bn_finalize(ssum, ssq, g, b, scale, shift, threadIdx.x);
}

__global__ __launch_bounds__(256) void bnrelu_kernel(
    float* __restrict__ out, const float* __restrict__ scale,
    const float* __restrict__ shift)
{
    int idx = blockIdx.x * blockDim.x + threadIdx.x;
    const int total = N_NODES * (DIM / 4);
    for (int f = idx; f < total; f += gridDim.x * blockDim.x) {
        float4 v = ((float4*)out)[f];
        int c = (f * 4) & (DIM - 1);
        float4 sc = *(const float4*)(scale + c);
        float4 sh = *(const float4*)(shift + c);
        v.x = fmaxf(v.x * sc.x + sh.x, 0.0f);
        v.y = fmaxf(v.y * sc.y + sh.y, 0.0f);
        v.z = fmaxf(v.z * sc.z + sh.z, 0.0f);
        v.w = fmaxf(v.w * sc.w + sh.w, 0.0f);
        ((float4*)out)[f] = v;
    }
}

extern "C" void kernel_launch(void* const* d_in, const int* in_sizes, int n_in,
                              void* d_out, int out_size, void* d_ws, size_t ws_size,
                              hipStream_t stream)
{
    const float* x    = (const float*)d_in[0];
    const int*   ei   = (const int*)  d_in[1];
    const float* ea   = (const float*)d_in[2];
    const int*   vi   = (const int*)  d_in[3];
    const float* vea  = (const float*)d_in[4];
    const float* epsd = (const float*)d_in[5];
    const float* W1d  = (const float*)d_in[6];
    const float* b1d  = (const float*)d_in[7];
    const float* g1d  = (const float*)d_in[8];
    const float* bt1d = (const float*)d_in[9];
    const float* W2d  = (const float*)d_in[10];
    const float* b2d  = (const float*)d_in[11];
    const float* epsu = (const float*)d_in[12];
    const float* W1u  = (const float*)d_in[13];
    const float* b1u  = (const float*)d_in[14];
    const float* g1u  = (const float*)d_in[15];
    const float* bt1u = (const float*)d_in[16];
    const float* W2u  = (const float*)d_in[17];
    const float* b2u  = (const float*)d_in[18];
    const float* bng  = (const float*)d_in[19];
    const float* bnb  = (const float*)d_in[20];
    const float* a1   = (const float*)d_in[21];
    const float* a2   = (const float*)d_in[22];

    float* out = (float*)d_out;

    // ---- workspace layout ----
    char* p = (char*)d_ws;
    unsigned short* hD  = (unsigned short*)p;  p += (size_t)N_NODES * DIM * 2;
    unsigned short* hU  = (unsigned short*)p;  p += (size_t)N_NODES * DIM * 2;
    unsigned short* t1D = (unsigned short*)p;  p += (size_t)N_NODES * DIM * 2;
    unsigned short* t1U = (unsigned short*)p;  p += (size_t)N_NODES * DIM * 2;
    unsigned short* Wt  = (unsigned short*)p;  p += (size_t)4 * DIM * DIM * 2;
    float* scD = (float*)p;                    p += DIM * 4;
    float* shD = (float*)p;                    p += DIM * 4;
    float* scU = (float*)p;                    p += DIM * 4;
    float* shU = (float*)p;                    p += DIM * 4;
    // zeroed region: stats (6 slices) + offsets
    char* zero_base = p;
    float* stats = (float*)p;                  p += (size_t)6 * NSLOT * DIM * 4;
    int* offD = (int*)p;                       p += (size_t)(N_NODES + 1) * 4;
    int* offU = (int*)p;                       p += (size_t)(N_NODES + 1) * 4;
    size_t zero_bytes = (size_t)(p - zero_base);
    int* curD = (int*)p;                       p += (size_t)N_NODES * 4;
    int* curU = (int*)p;                       p += (size_t)N_NODES * 4;
    char* union_base = p;
    int2* pairsD = (int2*)p;                   p += (size_t)NE * 8;
    int2* pairsU = (int2*)p;                   p += (size_t)NEV * 8;
    size_t need_csr = (size_t)(p - (char*)d_ws);
    float* aggr = (float*)union_base;          // fallback-only, overlaps pairs
    size_t need_fb = (size_t)(union_base - (char*)d_ws) + (size_t)N_NODES * DIM * 4;
    bool use_csr = ws_size >= need_csr;

    float* sumD = stats;
    float* sqD  = stats + 1 * NSLOT * DIM;
    float* sumU = stats + 2 * NSLOT * DIM;
    float* sqU  = stats + 3 * NSLOT * DIM;
    float* sumF = stats + 4 * NSLOT * DIM;
    float* sqF  = stats + 5 * NSLOT * DIM;

    unsigned short* Wt1d = Wt;
    unsigned short* Wt2d = Wt + 1 * (size_t)DIM * DIM;
    unsigned short* Wt1u = Wt + 2 * (size_t)DIM * DIM;
    unsigned short* Wt2u = Wt + 3 * (size_t)DIM * DIM;

    hipMemsetAsync(zero_base, 0, zero_bytes, stream);
    prepw_kernel<<<4 * DIM, 256, 0, stream>>>(W1d, W2d, W1u, W2u, Wt);

    if (use_csr) {
        hist2_kernel<<<(NE + NEV + 255) / 256, 256, 0, stream>>>(ei, vi, offD, offU);
        scan2_kernel<<<2, 1024, 0, stream>>>(offD, curD, offU, curU);
        fill2_kernel<<<(NE + NEV + 255) / 256, 256, 0, stream>>>(
            ei, vi, curD, curU, pairsD, pairsU);
        gather2_kernel<<<(2 * N_NODES + 3) / 4, 256, 0, stream>>>(
            x, ea, vea, offD, pairsD, offU, pairsU, epsd, epsu, hD, hU);
    } else if (ws_size >= need_fb) {
        hipMemsetAsync(aggr, 0, (size_t)N_NODES * DIM * 4, stream);
        scatter_kernel<<<(NE + 3) / 4, 256, 0, stream>>>(x, ea, ei, NE, aggr);
        conv_kernel<<<2048, 256, 0, stream>>>(x, aggr, epsd, hD);
        hipMemsetAsync(aggr, 0, (size_t)N_NODES * DIM * 4, stream);
        scatter_kernel<<<(NEV + 3) / 4, 256, 0, stream>>>(x, vea, vi, NEV, aggr);
        conv_kernel<<<2048, 256, 0, stream>>>(x, aggr, epsu, hU);
    }

    // ---- BOTH stage-1 GEMMs in one launch ----
    gemm1_both<<<2 * GRID_PER, 256, 0, stream>>>(
        hD, hU, Wt1d, Wt1u, b1d, b1u, t1D, t1U, sumD, sqD, sumU, sqU);
    finalize2_kernel<<<1, 2 * DIM, 0, stream>>>(
        sumD, sqD, g1d, bt1d, scD, shD, sumU, sqU, g1u, bt1u, scU, shU);

    // ---- stage-2 GEMMs (chained through out) ----
    gemm2_mfma<<<GRID_PER, 256, 0, stream>>>(t1D, scD, shD, Wt2d, b2d, x, a1, out,
                                             0, sumF, sqF);
    gemm2_mfma<<<GRID_PER, 256, 0, stream>>>(t1U, scU, shU, Wt2u, b2u, out, a2, out,
                                             1, sumF, sqF);
    // ---- final BN + ReLU ----
    finalize_kernel<<<1, 256, 0, stream>>>(sumF, sqF, bng, bnb, scD, shD);
    bnrelu_kernel<<<2048, 256, 0, stream>>>(out, scD, shD);
}

// Round 7
// 487.209 us; speedup vs baseline: 4.1437x; 1.0430x over previous
//
#include <hip/hip_runtime.h>
#include <math.h>

#define N_NODES 50000
#define DIM 256
#define NE 300000
#define NEV 100000
#define BM 64
#define BK 64
#define NSLOT 8
#define GRID_PER ((N_NODES + BM - 1) / BM)   // 782

typedef float f32x4 __attribute__((ext_vector_type(4)));
typedef short s16x8 __attribute__((ext_vector_type(8)));

__device__ inline unsigned short f2bf(float f) {
    unsigned u = __float_as_uint(f);
    u += 0x7FFF + ((u >> 16) & 1);            // round-to-nearest-even
    return (unsigned short)(u >> 16);
}
__device__ inline float bf2f(unsigned short s) {
    return __uint_as_float(((unsigned)s) << 16);
}
// swizzled halfword offset inside a [R][64] bf16 tile (16B granules, T2 XOR)
__device__ inline int swz(int row, int kg) {
    return row * BK + ((kg ^ (row & 7)) << 3);
}

// ---------------------------------------------------------------------------
// all 4 weights: W [K][N] fp32 -> Wt [N][K] bf16, one launch
// ---------------------------------------------------------------------------
__global__ __launch_bounds__(256) void prepw_kernel(
    const float* __restrict__ W1d, const float* __restrict__ W2d,
    const float* __restrict__ W1u, const float* __restrict__ W2u,
    unsigned short* __restrict__ Wt)
{
    int b = blockIdx.x;
    int w = b >> 8, n = b & 255, k = threadIdx.x;
    const float* W = (w == 0) ? W1d : (w == 1) ? W2d : (w == 2) ? W1u : W2u;
    Wt[(size_t)w * DIM * DIM + (size_t)n * DIM + k] = f2bf(W[(size_t)k * DIM + n]);
}

// ---------------------------------------------------------------------------
// CSR build (both edge sets per launch); fill packs (e,src) int2
// ---------------------------------------------------------------------------
__global__ __launch_bounds__(256) void hist2_kernel(
    const int* __restrict__ ei, const int* __restrict__ vi,
    int* __restrict__ degD, int* __restrict__ degU)
{
    int i = blockIdx.x * blockDim.x + threadIdx.x;
    if (i < NE) atomicAdd(&degD[ei[NE + i]], 1);
    else if (i < NE + NEV) { int j = i - NE; atomicAdd(&degU[vi[NEV + j]], 1); }
}

__global__ __launch_bounds__(1024) void scan2_kernel(
    int* __restrict__ offD, int* __restrict__ curD,
    int* __restrict__ offU, int* __restrict__ curU)
{
    int* deg_offsets = (blockIdx.x == 0) ? offD : offU;
    int* cursor      = (blockIdx.x == 0) ? curD : curU;
    int E            = (blockIdx.x == 0) ? NE : NEV;
    __shared__ int part[1024];
    int t = threadIdx.x;
    const int CH = (N_NODES + 1023) / 1024;
    int beg = t * CH;
    int end = min(beg + CH, N_NODES);
    int s = 0;
    for (int i = beg; i < end; i++) s += deg_offsets[i];
    part[t] = s;
    __syncthreads();
    for (int off = 1; off < 1024; off <<= 1) {
        int v = part[t];
        int u = (t >= off) ? part[t - off] : 0;
        __syncthreads();
        part[t] = v + u;
        __syncthreads();
    }
    int run = (t > 0) ? part[t - 1] : 0;
    for (int i = beg; i < end; i++) {
        int dv = deg_offsets[i];
        deg_offsets[i] = run;
        cursor[i] = run;
        run += dv;
    }
    if (t == 1023) deg_offsets[N_NODES] = E;
}

__global__ __launch_bounds__(256) void fill2_kernel(
    const int* __restrict__ ei, const int* __restrict__ vi,
    int* __restrict__ curD, int* __restrict__ curU,
    int2* __restrict__ pairsD, int2* __restrict__ pairsU)
{
    int i = blockIdx.x * blockDim.x + threadIdx.x;
    if (i < NE) {
        int s = ei[i], d = ei[NE + i];
        int pos = atomicAdd(&curD[d], 1);
        pairsD[pos] = make_int2(i, s);
    } else if (i < NE + NEV) {
        int j = i - NE;
        int s = vi[j], d = vi[NEV + j];
        int pos = atomicAdd(&curU[d], 1);
        pairsU[pos] = make_int2(j, s);
    }
}

// ---------------------------------------------------------------------------
// gather: TWO waves per node (even/odd edge split), partials merged in LDS.
// Block = 256 thr = 4 waves = 2 node-slots. Emits h = bf16((1+eps)x + aggr).
// ---------------------------------------------------------------------------
__device__ inline f32x4 ld4(const float* p) { return *(const f32x4*)p; }
__device__ inline f32x4 ldnt4(const float* p) {
    return __builtin_nontemporal_load((const f32x4*)p);
}
__device__ inline void acc_relu(f32x4& acc, f32x4 a, f32x4 b) {
    acc.x += fmaxf(a.x + b.x, 0.f);
    acc.y += fmaxf(a.y + b.y, 0.f);
    acc.z += fmaxf(a.z + b.z, 0.f);
    acc.w += fmaxf(a.w + b.w, 0.f);
}

__global__ __launch_bounds__(256) void gather2_kernel(
    const float* __restrict__ x, const float* __restrict__ ea,
    const float* __restrict__ vea,
    const int* __restrict__ offD, const int2* __restrict__ pairsD,
    const int* __restrict__ offU, const int2* __restrict__ pairsU,
    const float* __restrict__ epsd, const float* __restrict__ epsu,
    unsigned short* __restrict__ hD, unsigned short* __restrict__ hU)
{
    __shared__ f32x4 part[2][64];
    int warp = threadIdx.x >> 6;          // 0..3
    int lane = threadIdx.x & 63;
    int slotn = warp >> 1;                // node slot within block (0/1)
    int half = warp & 1;                  // edge-parity this wave handles
    int nidx = blockIdx.x * 2 + slotn;    // 0 .. 2*N_NODES-1 (grid exact)
    bool down = nidx < N_NODES;
    int node = down ? nidx : nidx - N_NODES;
    const int* off      = down ? offD   : offU;
    const int2* pairs   = down ? pairsD : pairsU;
    const float* eat    = down ? ea     : vea;
    unsigned short* h   = down ? hD     : hU;
    float epsv = 1.0f + (down ? epsd[0] : epsu[0]);

    int beg = off[node], end = off[node + 1];
    f32x4 acc = {0.f, 0.f, 0.f, 0.f};
    int cofs = lane * 4;
    int p = beg + half;
    for (; p + 2 < end; p += 4) {          // 2-edge unroll (stride-2 stream)
        int2 q0 = pairs[p], q1 = pairs[p + 2];
        f32x4 a0 = ld4(x + (size_t)q0.y * DIM + cofs);
        f32x4 b0 = ldnt4(eat + (size_t)q0.x * DIM + cofs);
        f32x4 a1 = ld4(x + (size_t)q1.y * DIM + cofs);
        f32x4 b1 = ldnt4(eat + (size_t)q1.x * DIM + cofs);
        acc_relu(acc, a0, b0);
        acc_relu(acc, a1, b1);
    }
    if (p < end) {
        int2 q0 = pairs[p];
        f32x4 a0 = ld4(x + (size_t)q0.y * DIM + cofs);
        f32x4 b0 = ldnt4(eat + (size_t)q0.x * DIM + cofs);
        acc_relu(acc, a0, b0);
    }
    if (half == 1) part[slotn][lane] = acc;
    __syncthreads();
    if (half == 0) {
        f32x4 o = part[slotn][lane];
        acc.x += o.x; acc.y += o.y; acc.z += o.z; acc.w += o.w;
        f32x4 xv = ld4(x + (size_t)node * DIM + cofs);
        acc.x = fmaf(epsv, xv.x, acc.x);
        acc.y = fmaf(epsv, xv.y, acc.y);
        acc.z = fmaf(epsv, xv.z, acc.z);
        acc.w = fmaf(epsv, xv.w, acc.w);
        ushort4 pk;
        pk.x = f2bf(acc.x); pk.y = f2bf(acc.y);
        pk.z = f2bf(acc.z); pk.w = f2bf(acc.w);
        *(ushort4*)(h + (size_t)node * DIM + cofs) = pk;
    }
}

// ---------------------------------------------------------------------------
// FALLBACK: atomic scatter into f32 aggr + convert kernel
// ---------------------------------------------------------------------------
__global__ __launch_bounds__(256) void scatter_kernel(
    const float* __restrict__ x, const float* __restrict__ ea,
    const int* __restrict__ idx, int E, float* __restrict__ buf)
{
    int wid = blockIdx.x * (blockDim.x >> 6) + (threadIdx.x >> 6);
    int lane = threadIdx.x & 63;
    if (wid >= E) return;
    int s = idx[wid];
    int d = idx[E + wid];
    float4 a = ((const float4*)(x + (size_t)s * DIM))[lane];
    float4 b = ((const float4*)(ea + (size_t)wid * DIM))[lane];
    float* dst = buf + (size_t)d * DIM + lane * 4;
    atomicAdd(dst + 0, fmaxf(a.x + b.x, 0.f));
    atomicAdd(dst + 1, fmaxf(a.y + b.y, 0.f));
    atomicAdd(dst + 2, fmaxf(a.z + b.z, 0.f));
    atomicAdd(dst + 3, fmaxf(a.w + b.w, 0.f));
}

__global__ __launch_bounds__(256) void conv_kernel(
    const float* __restrict__ x, const float* __restrict__ aggr,
    const float* __restrict__ eps_p, unsigned short* __restrict__ h)
{
    float epsv = 1.0f + eps_p[0];
    int i = blockIdx.x * blockDim.x + threadIdx.x;
    const int total = N_NODES * (DIM / 4);
    for (int f = i; f < total; f += gridDim.x * blockDim.x) {
        float4 xv = ((const float4*)x)[f];
        float4 av = ((const float4*)aggr)[f];
        ushort4 pk;
        pk.x = f2bf(fmaf(epsv, xv.x, av.x));
        pk.y = f2bf(fmaf(epsv, xv.y, av.y));
        pk.z = f2bf(fmaf(epsv, xv.z, av.z));
        pk.w = f2bf(fmaf(epsv, xv.w, av.w));
        ((ushort4*)h)[f] = pk;
    }
}

// ---------------------------------------------------------------------------
// MFMA GEMM stage 1 (BOTH paths): wave owns a 64x64 tile (4x4 MFMA grid).
// Per K-chunk: 16 ds_reads, 32 MFMAs. Stats: wave-private cols -> atomics.
// ---------------------------------------------------------------------------
__global__ __launch_bounds__(256) void gemm1_both(
    const unsigned short* __restrict__ hD, const unsigned short* __restrict__ hU,
    const unsigned short* __restrict__ Wt1d, const unsigned short* __restrict__ Wt1u,
    const float* __restrict__ b1d, const float* __restrict__ b1u,
    unsigned short* __restrict__ t1D, unsigned short* __restrict__ t1U,
    float* __restrict__ sumD, float* __restrict__ sqD,
    float* __restrict__ sumU, float* __restrict__ sqU)
{
    __shared__ unsigned short As[BM * BK];
    __shared__ unsigned short Bs[DIM * BK];
    int blk = blockIdx.x;
    bool down = blk < GRID_PER;
    int bb = down ? blk : blk - GRID_PER;
    const unsigned short* h  = down ? hD   : hU;
    const unsigned short* Wt = down ? Wt1d : Wt1u;
    const float* bias        = down ? b1d  : b1u;
    unsigned short* t1       = down ? t1D  : t1U;
    float* ssum              = down ? sumD : sumU;
    float* ssq               = down ? sqD  : sqU;

    int t = threadIdx.x;
    int w = t >> 6, l = t & 63, lrow = l & 15, kgrp = l >> 4;
    int row0 = bb * BM;

    f32x4 acc[16];
    #pragma unroll
    for (int i = 0; i < 16; ++i) acc[i] = (f32x4){0.f, 0.f, 0.f, 0.f};

    for (int k0 = 0; k0 < DIM; k0 += BK) {
        __syncthreads();
        #pragma unroll
        for (int it = 0; it < 2; ++it) {
            int g = it * 256 + t, row = g >> 3, kg = g & 7;
            int gr = row0 + row;
            s16x8 v = {0, 0, 0, 0, 0, 0, 0, 0};
            if (gr < N_NODES)
                v = *(const s16x8*)&h[(size_t)gr * DIM + k0 + kg * 8];
            *(s16x8*)&As[swz(row, kg)] = v;
        }
        #pragma unroll
        for (int it = 0; it < 8; ++it) {
            int g = it * 256 + t, row = g >> 3, kg = g & 7;
            s16x8 v = *(const s16x8*)&Wt[(size_t)row * DIM + k0 + kg * 8];
            *(s16x8*)&Bs[swz(row, kg)] = v;
        }
        __syncthreads();
        #pragma unroll
        for (int kk = 0; kk < 2; ++kk) {
            s16x8 af[4], bf[4];
            #pragma unroll
            for (int mi = 0; mi < 4; ++mi)
                af[mi] = *(const s16x8*)&As[swz(mi * 16 + lrow, kk * 4 + kgrp)];
            #pragma unroll
            for (int ni = 0; ni < 4; ++ni)
                bf[ni] = *(const s16x8*)&Bs[swz(w * 64 + ni * 16 + lrow, kk * 4 + kgrp)];
            #pragma unroll
            for (int mi = 0; mi < 4; ++mi)
                #pragma unroll
                for (int ni = 0; ni < 4; ++ni)
                    acc[mi * 4 + ni] = __builtin_amdgcn_mfma_f32_16x16x32_bf16(
                        af[mi], bf[ni], acc[mi * 4 + ni], 0, 0, 0);
        }
    }
    int slot = bb & (NSLOT - 1);
    #pragma unroll
    for (int ni = 0; ni < 4; ++ni) {
        int col = w * 64 + ni * 16 + lrow;
        float bv = bias[col];
        float s = 0.f, q = 0.f;
        #pragma unroll
        for (int mi = 0; mi < 4; ++mi) {
            #pragma unroll
            for (int r = 0; r < 4; ++r) {
                int grow = row0 + mi * 16 + kgrp * 4 + r;
                if (grow < N_NODES) {
                    float v = acc[mi * 4 + ni][r] + bv;
                    t1[(size_t)grow * DIM + col] = f2bf(v);
                    s += v; q += v * v;
                }
            }
        }
        s += __shfl_xor(s, 16); q += __shfl_xor(q, 16);
        s += __shfl_xor(s, 32); q += __shfl_xor(q, 32);
        if (kgrp == 0) {
            atomicAdd(&ssum[slot * DIM + col], s);
            atomicAdd(&ssq[slot * DIM + col], q);
        }
    }
}

// ---------------------------------------------------------------------------
// MFMA GEMM stage 2 (BOTH paths, one launch):
//   C{1,2} = alpha * (relu(t1*scale+shift) @ W2 + b2)      (no base chaining)
// ---------------------------------------------------------------------------
__global__ __launch_bounds__(256) void gemm2_both(
    const unsigned short* __restrict__ t1D, const unsigned short* __restrict__ t1U,
    const float* __restrict__ scD, const float* __restrict__ shD,
    const float* __restrict__ scU, const float* __restrict__ shU,
    const unsigned short* __restrict__ Wt2d, const unsigned short* __restrict__ Wt2u,
    const float* __restrict__ b2d, const float* __restrict__ b2u,
    const float* __restrict__ a1, const float* __restrict__ a2,
    float* __restrict__ C1, float* __restrict__ C2)
{
    __shared__ unsigned short As[BM * BK];
    __shared__ unsigned short Bs[DIM * BK];
    int blk = blockIdx.x;
    bool down = blk < GRID_PER;
    int bb = down ? blk : blk - GRID_PER;
    const unsigned short* t1 = down ? t1D  : t1U;
    const float* scale       = down ? scD  : scU;
    const float* shift       = down ? shD  : shU;
    const unsigned short* Wt = down ? Wt2d : Wt2u;
    const float* bias        = down ? b2d  : b2u;
    float alphav             = down ? a1[0] : a2[0];
    float* C                 = down ? C1   : C2;

    int t = threadIdx.x;
    int w = t >> 6, l = t & 63, lrow = l & 15, kgrp = l >> 4;
    int row0 = bb * BM;

    f32x4 acc[16];
    #pragma unroll
    for (int i = 0; i < 16; ++i) acc[i] = (f32x4){0.f, 0.f, 0.f, 0.f};

    for (int k0 = 0; k0 < DIM; k0 += BK) {
        __syncthreads();
        #pragma unroll
        for (int it = 0; it < 2; ++it) {
            int g = it * 256 + t, row = g >> 3, kg = g & 7;
            int gr = row0 + row;
            s16x8 pack = {0, 0, 0, 0, 0, 0, 0, 0};
            if (gr < N_NODES) {
                s16x8 tv = *(const s16x8*)(t1 + (size_t)gr * DIM + k0 + kg * 8);
                const float4* scp = (const float4*)(scale + k0 + kg * 8);
                const float4* shp = (const float4*)(shift + k0 + kg * 8);
                float4 s0 = scp[0], s1 = scp[1], h0 = shp[0], h1 = shp[1];
                pack[0] = f2bf(fmaxf(fmaf(bf2f((unsigned short)tv[0]), s0.x, h0.x), 0.f));
                pack[1] = f2bf(fmaxf(fmaf(bf2f((unsigned short)tv[1]), s0.y, h0.y), 0.f));
                pack[2] = f2bf(fmaxf(fmaf(bf2f((unsigned short)tv[2]), s0.z, h0.z), 0.f));
                pack[3] = f2bf(fmaxf(fmaf(bf2f((unsigned short)tv[3]), s0.w, h0.w), 0.f));
                pack[4] = f2bf(fmaxf(fmaf(bf2f((unsigned short)tv[4]), s1.x, h1.x), 0.f));
                pack[5] = f2bf(fmaxf(fmaf(bf2f((unsigned short)tv[5]), s1.y, h1.y), 0.f));
                pack[6] = f2bf(fmaxf(fmaf(bf2f((unsigned short)tv[6]), s1.z, h1.z), 0.f));
                pack[7] = f2bf(fmaxf(fmaf(bf2f((unsigned short)tv[7]), s1.w, h1.w), 0.f));
            }
            *(s16x8*)&As[swz(row, kg)] = pack;
        }
        #pragma unroll
        for (int it = 0; it < 8; ++it) {
            int g = it * 256 + t, row = g >> 3, kg = g & 7;
            s16x8 v = *(const s16x8*)&Wt[(size_t)row * DIM + k0 + kg * 8];
            *(s16x8*)&Bs[swz(row, kg)] = v;
        }
        __syncthreads();
        #pragma unroll
        for (int kk = 0; kk < 2; ++kk) {
            s16x8 af[4], bf[4];
            #pragma unroll
            for (int mi = 0; mi < 4; ++mi)
                af[mi] = *(const s16x8*)&As[swz(mi * 16 + lrow, kk * 4 + kgrp)];
            #pragma unroll
            for (int ni = 0; ni < 4; ++ni)
                bf[ni] = *(const s16x8*)&Bs[swz(w * 64 + ni * 16 + lrow, kk * 4 + kgrp)];
            #pragma unroll
            for (int mi = 0; mi < 4; ++mi)
                #pragma unroll
                for (int ni = 0; ni < 4; ++ni)
                    acc[mi * 4 + ni] = __builtin_amdgcn_mfma_f32_16x16x32_bf16(
                        af[mi], bf[ni], acc[mi * 4 + ni], 0, 0, 0);
        }
    }
    #pragma unroll
    for (int ni = 0; ni < 4; ++ni) {
        int col = w * 64 + ni * 16 + lrow;
        float bv = bias[col];
        #pragma unroll
        for (int mi = 0; mi < 4; ++mi) {
            #pragma unroll
            for (int r = 0; r < 4; ++r) {
                int grow = row0 + mi * 16 + kgrp * 4 + r;
                if (grow < N_NODES)
                    C[(size_t)grow * DIM + col] = alphav * (acc[mi * 4 + ni][r] + bv);
            }
        }
    }
}

// ---------------------------------------------------------------------------
// combine: out = x + C1 + C2, final-BN col stats fused
// ---------------------------------------------------------------------------
__global__ __launch_bounds__(256) void combine_kernel(
    const float* __restrict__ x, const float* __restrict__ C1,
    const float* __restrict__ C2, float* __restrict__ out,
    float* __restrict__ ssum, float* __restrict__ ssq)
{
    __shared__ f32x4 sS[4][64];
    __shared__ f32x4 sQ[4][64];
    int t = threadIdx.x;
    int cq = t & 63, rg = t >> 6;
    f32x4 s = {0.f, 0.f, 0.f, 0.f}, q = {0.f, 0.f, 0.f, 0.f};
    const int rowstep = gridDim.x * 4;
    for (int row = blockIdx.x * 4 + rg; row < N_NODES; row += rowstep) {
        size_t f = (size_t)row * 64 + cq;
        f32x4 v = ((const f32x4*)x)[f] + ((const f32x4*)C1)[f] + ((const f32x4*)C2)[f];
        ((f32x4*)out)[f] = v;
        s += v; q += v * v;
    }
    sS[rg][cq] = s; sQ[rg][cq] = q;
    __syncthreads();
    if (rg == 0) {
        s = sS[0][cq] + sS[1][cq] + sS[2][cq] + sS[3][cq];
        q = sQ[0][cq] + sQ[1][cq] + sQ[2][cq] + sQ[3][cq];
        int slot = blockIdx.x & (NSLOT - 1);
        int c = cq * 4;
        atomicAdd(&ssum[slot * DIM + c + 0], s.x);
        atomicAdd(&ssum[slot * DIM + c + 1], s.y);
        atomicAdd(&ssum[slot * DIM + c + 2], s.z);
        atomicAdd(&ssum[slot * DIM + c + 3], s.w);
        atomicAdd(&ssq[slot * DIM + c + 0], q.x);
        atomicAdd(&ssq[slot * DIM + c + 1], q.y);
        atomicAdd(&ssq[slot * DIM + c + 2], q.z);
        atomicAdd(&ssq[slot * DIM + c + 3], q.w);
    }
}

// ---------------------------------------------------------------------------
// BN finalize + elementwise BN/ReLU
// ---------------------------------------------------------------------------
__device__ inline void bn_finalize(
    const float* ssum, const float* ssq, const float* g, const float* b,
    float* scale, float* shift, int c)
{
    float s = 0.f, q = 0.f;
    #pragma unroll
    for (int k = 0; k < NSLOT; ++k) { s += ssum[k * DIM + c]; q += ssq[k * DIM + c]; }
    const float invN = 1.0f / (float)N_NODES;
    float mu = s * invN;
    float var = q * invN - mu * mu;
    float sc = g[c] * rsqrtf(var + 1e-5f);
    scale[c] = sc;
    shift[c] = b[c] - mu * sc;
}

__global__ void finalize2_kernel(
    const float* __restrict__ sumD, const float* __restrict__ sqD,
    const float* __restrict__ g1d, const float* __restrict__ bt1d,
    float* __restrict__ scD, float* __restrict__ shD,
    const float* __restrict__ sumU, const float* __restrict__ sqU,
    const float* __restrict__ g1u, const float* __restrict__ bt1u,
    float* __restrict__ scU, float* __restrict__ shU)
{
    int t = threadIdx.x;
    int c = t & (DIM - 1);
    if (t < DIM) bn_finalize(sumD, sqD, g1d, bt1d, scD, shD, c);
    else         bn_finalize(sumU, sqU, g1u, bt1u, scU, shU, c);
}

__global__ void finalize_kernel(
    const float* __restrict__ ssum, const float* __restrict__ ssq,
    const float* __restrict__ g, const float* __restrict__ b,
    float* __restrict__ scale, float* __restrict__ shift)
{
    bn_finalize(ssum, ssq, g, b, scale, shift, threadIdx.x);
}

__global__ __launch_bounds__(256) void bnrelu_kernel(
    float* __restrict__ out, const float* __restrict__ scale,
    const float* __restrict__ shift)
{
    int idx = blockIdx.x * blockDim.x + threadIdx.x;
    const int total = N_NODES * (DIM / 4);
    for (int f = idx; f < total; f += gridDim.x * blockDim.x) {
        float4 v = ((float4*)out)[f];
        int c = (f * 4) & (DIM - 1);
        float4 sc = *(const float4*)(scale + c);
        float4 sh = *(const float4*)(shift + c);
        v.x = fmaxf(v.x * sc.x + sh.x, 0.0f);
        v.y = fmaxf(v.y * sc.y + sh.y, 0.0f);
        v.z = fmaxf(v.z * sc.z + sh.z, 0.0f);
        v.w = fmaxf(v.w * sc.w + sh.w, 0.0f);
        ((float4*)out)[f] = v;
    }
}

extern "C" void kernel_launch(void* const* d_in, const int* in_sizes, int n_in,
                              void* d_out, int out_size, void* d_ws, size_t ws_size,
                              hipStream_t stream)
{
    const float* x    = (const float*)d_in[0];
    const int*   ei   = (const int*)  d_in[1];
    const float* ea   = (const float*)d_in[2];
    const int*   vi   = (const int*)  d_in[3];
    const float* vea  = (const float*)d_in[4];
    const float* epsd = (const float*)d_in[5];
    const float* W1d  = (const float*)d_in[6];
    const float* b1d  = (const float*)d_in[7];
    const float* g1d  = (const float*)d_in[8];
    const float* bt1d = (const float*)d_in[9];
    const float* W2d  = (const float*)d_in[10];
    const float* b2d  = (const float*)d_in[11];
    const float* epsu = (const float*)d_in[12];
    const float* W1u  = (const float*)d_in[13];
    const float* b1u  = (const float*)d_in[14];
    const float* g1u  = (const float*)d_in[15];
    const float* bt1u = (const float*)d_in[16];
    const float* W2u  = (const float*)d_in[17];
    const float* b2u  = (const float*)d_in[18];
    const float* bng  = (const float*)d_in[19];
    const float* bnb  = (const float*)d_in[20];
    const float* a1   = (const float*)d_in[21];
    const float* a2   = (const float*)d_in[22];

    float* out = (float*)d_out;

    // ---- workspace layout ----
    char* p = (char*)d_ws;
    unsigned short* hD  = (unsigned short*)p;  p += (size_t)N_NODES * DIM * 2;
    unsigned short* hU  = (unsigned short*)p;  p += (size_t)N_NODES * DIM * 2;
    unsigned short* t1D = (unsigned short*)p;  p += (size_t)N_NODES * DIM * 2;
    unsigned short* t1U = (unsigned short*)p;  p += (size_t)N_NODES * DIM * 2;
    unsigned short* Wt  = (unsigned short*)p;  p += (size_t)4 * DIM * DIM * 2;
    float* C1 = (float*)p;                     p += (size_t)N_NODES * DIM * 4;
    float* C2 = (float*)p;                     p += (size_t)N_NODES * DIM * 4;
    float* scD = (float*)p;                    p += DIM * 4;
    float* shD = (float*)p;                    p += DIM * 4;
    float* scU = (float*)p;                    p += DIM * 4;
    float* shU = (float*)p;                    p += DIM * 4;
    // zeroed region: stats (6 slices) + offsets
    char* zero_base = p;
    float* stats = (float*)p;                  p += (size_t)6 * NSLOT * DIM * 4;
    int* offD = (int*)p;                       p += (size_t)(N_NODES + 1) * 4;
    int* offU = (int*)p;                       p += (size_t)(N_NODES + 1) * 4;
    size_t zero_bytes = (size_t)(p - zero_base);
    int* curD = (int*)p;                       p += (size_t)N_NODES * 4;
    int* curU = (int*)p;                       p += (size_t)N_NODES * 4;
    char* union_base = p;
    int2* pairsD = (int2*)p;                   p += (size_t)NE * 8;
    int2* pairsU = (int2*)p;                   p += (size_t)NEV * 8;
    size_t need_csr = (size_t)(p - (char*)d_ws);
    float* aggr = (float*)union_base;          // fallback-only, overlaps pairs
    size_t need_fb = (size_t)(union_base - (char*)d_ws) + (size_t)N_NODES * DIM * 4;
    bool use_csr = ws_size >= need_csr;

    float* sumD = stats;
    float* sqD  = stats + 1 * NSLOT * DIM;
    float* sumU = stats + 2 * NSLOT * DIM;
    float* sqU  = stats + 3 * NSLOT * DIM;
    float* sumF = stats + 4 * NSLOT * DIM;
    float* sqF  = stats + 5 * NSLOT * DIM;

    unsigned short* Wt1d = Wt;
    unsigned short* Wt2d = Wt + 1 * (size_t)DIM * DIM;
    unsigned short* Wt1u = Wt + 2 * (size_t)DIM * DIM;
    unsigned short* Wt2u = Wt + 3 * (size_t)DIM * DIM;

    hipMemsetAsync(zero_base, 0, zero_bytes, stream);
    prepw_kernel<<<4 * DIM, 256, 0, stream>>>(W1d, W2d, W1u, W2u, Wt);

    if (use_csr) {
        hist2_kernel<<<(NE + NEV + 255) / 256, 256, 0, stream>>>(ei, vi, offD, offU);
        scan2_kernel<<<2, 1024, 0, stream>>>(offD, curD, offU, curU);
        fill2_kernel<<<(NE + NEV + 255) / 256, 256, 0, stream>>>(
            ei, vi, curD, curU, pairsD, pairsU);
        gather2_kernel<<<N_NODES, 256, 0, stream>>>(
            x, ea, vea, offD, pairsD, offU, pairsU, epsd, epsu, hD, hU);
    } else if (ws_size >= need_fb) {
        hipMemsetAsync(aggr, 0, (size_t)N_NODES * DIM * 4, stream);
        scatter_kernel<<<(NE + 3) / 4, 256, 0, stream>>>(x, ea, ei, NE, aggr);
        conv_kernel<<<2048, 256, 0, stream>>>(x, aggr, epsd, hD);
        hipMemsetAsync(aggr, 0, (size_t)N_NODES * DIM * 4, stream);
        scatter_kernel<<<(NEV + 3) / 4, 256, 0, stream>>>(x, vea, vi, NEV, aggr);
        conv_kernel<<<2048, 256, 0, stream>>>(x, aggr, epsu, hU);
    }

    // ---- BOTH stage-1 GEMMs in one launch ----
    gemm1_both<<<2 * GRID_PER, 256, 0, stream>>>(
        hD, hU, Wt1d, Wt1u, b1d, b1u, t1D, t1U, sumD, sqD, sumU, sqU);
    finalize2_kernel<<<1, 2 * DIM, 0, stream>>>(
        sumD, sqD, g1d, bt1d, scD, shD, sumU, sqU, g1u, bt1u, scU, shU);

    // ---- BOTH stage-2 GEMMs in one launch (independent outputs) ----
    gemm2_both<<<2 * GRID_PER, 256, 0, stream>>>(
        t1D, t1U, scD, shD, scU, shU, Wt2d, Wt2u, b2d, b2u, a1, a2, C1, C2);

    // ---- combine + final stats, finalize, BN/ReLU ----
    combine_kernel<<<1024, 256, 0, stream>>>(x, C1, C2, out, sumF, sqF);
    finalize_kernel<<<1, 256, 0, stream>>>(sumF, sqF, bng, bnb, scD, shD);
    bnrelu_kernel<<<2048, 256, 0, stream>>>(out, scD, shD);
}

// Round 8
// 438.414 us; speedup vs baseline: 4.6049x; 1.1113x over previous
//
#include <hip/hip_runtime.h>
#include <math.h>

#define N_NODES 50000
#define DIM 256
#define NE 300000
#define NEV 100000
#define BM 64
#define BK 64
#define NSLOT 8
#define GRID_PER ((N_NODES + BM - 1) / BM)   // 782

typedef float f32x4 __attribute__((ext_vector_type(4)));
typedef short s16x8 __attribute__((ext_vector_type(8)));

__device__ inline unsigned short f2bf(float f) {
    unsigned u = __float_as_uint(f);
    u += 0x7FFF + ((u >> 16) & 1);            // round-to-nearest-even
    return (unsigned short)(u >> 16);
}
__device__ inline float bf2f(unsigned short s) {
    return __uint_as_float(((unsigned)s) << 16);
}
// swizzled halfword offset inside a [R][64] bf16 tile (16B granules, T2 XOR)
__device__ inline int swz(int row, int kg) {
    return row * BK + ((kg ^ (row & 7)) << 3);
}

// ---------------------------------------------------------------------------
// all 4 weights: W [K][N] fp32 -> Wt [N][K] bf16, one launch
// ---------------------------------------------------------------------------
__global__ __launch_bounds__(256) void prepw_kernel(
    const float* __restrict__ W1d, const float* __restrict__ W2d,
    const float* __restrict__ W1u, const float* __restrict__ W2u,
    unsigned short* __restrict__ Wt)
{
    int b = blockIdx.x;
    int w = b >> 8, n = b & 255, k = threadIdx.x;
    const float* W = (w == 0) ? W1d : (w == 1) ? W2d : (w == 2) ? W1u : W2u;
    Wt[(size_t)w * DIM * DIM + (size_t)n * DIM + k] = f2bf(W[(size_t)k * DIM + n]);
}

// ---------------------------------------------------------------------------
// CSR build (both edge sets per launch); fill packs (e,src) int2
// ---------------------------------------------------------------------------
__global__ __launch_bounds__(256) void hist2_kernel(
    const int* __restrict__ ei, const int* __restrict__ vi,
    int* __restrict__ degD, int* __restrict__ degU)
{
    int i = blockIdx.x * blockDim.x + threadIdx.x;
    if (i < NE) atomicAdd(&degD[ei[NE + i]], 1);
    else if (i < NE + NEV) { int j = i - NE; atomicAdd(&degU[vi[NEV + j]], 1); }
}

__global__ __launch_bounds__(1024) void scan2_kernel(
    int* __restrict__ offD, int* __restrict__ curD,
    int* __restrict__ offU, int* __restrict__ curU)
{
    int* deg_offsets = (blockIdx.x == 0) ? offD : offU;
    int* cursor      = (blockIdx.x == 0) ? curD : curU;
    int E            = (blockIdx.x == 0) ? NE : NEV;
    __shared__ int part[1024];
    int t = threadIdx.x;
    const int CH = (N_NODES + 1023) / 1024;
    int beg = t * CH;
    int end = min(beg + CH, N_NODES);
    int s = 0;
    for (int i = beg; i < end; i++) s += deg_offsets[i];
    part[t] = s;
    __syncthreads();
    for (int off = 1; off < 1024; off <<= 1) {
        int v = part[t];
        int u = (t >= off) ? part[t - off] : 0;
        __syncthreads();
        part[t] = v + u;
        __syncthreads();
    }
    int run = (t > 0) ? part[t - 1] : 0;
    for (int i = beg; i < end; i++) {
        int dv = deg_offsets[i];
        deg_offsets[i] = run;
        cursor[i] = run;
        run += dv;
    }
    if (t == 1023) deg_offsets[N_NODES] = E;
}

__global__ __launch_bounds__(256) void fill2_kernel(
    const int* __restrict__ ei, const int* __restrict__ vi,
    int* __restrict__ curD, int* __restrict__ curU,
    int2* __restrict__ pairsD, int2* __restrict__ pairsU)
{
    int i = blockIdx.x * blockDim.x + threadIdx.x;
    if (i < NE) {
        int s = ei[i], d = ei[NE + i];
        int pos = atomicAdd(&curD[d], 1);
        pairsD[pos] = make_int2(i, s);
    } else if (i < NE + NEV) {
        int j = i - NE;
        int s = vi[j], d = vi[NEV + j];
        int pos = atomicAdd(&curU[d], 1);
        pairsU[pos] = make_int2(j, s);
    }
}

// ---------------------------------------------------------------------------
// gather: TWO waves per node (even/odd edge split), partials merged in LDS.
// ---------------------------------------------------------------------------
__device__ inline f32x4 ld4(const float* p) { return *(const f32x4*)p; }
__device__ inline f32x4 ldnt4(const float* p) {
    return __builtin_nontemporal_load((const f32x4*)p);
}
__device__ inline void acc_relu(f32x4& acc, f32x4 a, f32x4 b) {
    acc.x += fmaxf(a.x + b.x, 0.f);
    acc.y += fmaxf(a.y + b.y, 0.f);
    acc.z += fmaxf(a.z + b.z, 0.f);
    acc.w += fmaxf(a.w + b.w, 0.f);
}

__global__ __launch_bounds__(256) void gather2_kernel(
    const float* __restrict__ x, const float* __restrict__ ea,
    const float* __restrict__ vea,
    const int* __restrict__ offD, const int2* __restrict__ pairsD,
    const int* __restrict__ offU, const int2* __restrict__ pairsU,
    const float* __restrict__ epsd, const float* __restrict__ epsu,
    unsigned short* __restrict__ hD, unsigned short* __restrict__ hU)
{
    __shared__ f32x4 part[2][64];
    int warp = threadIdx.x >> 6;          // 0..3
    int lane = threadIdx.x & 63;
    int slotn = warp >> 1;                // node slot within block (0/1)
    int half = warp & 1;                  // edge-parity this wave handles
    int nidx = blockIdx.x * 2 + slotn;    // 0 .. 2*N_NODES-1 (grid exact)
    bool down = nidx < N_NODES;
    int node = down ? nidx : nidx - N_NODES;
    const int* off      = down ? offD   : offU;
    const int2* pairs   = down ? pairsD : pairsU;
    const float* eat    = down ? ea     : vea;
    unsigned short* h   = down ? hD     : hU;
    float epsv = 1.0f + (down ? epsd[0] : epsu[0]);

    int beg = off[node], end = off[node + 1];
    f32x4 acc = {0.f, 0.f, 0.f, 0.f};
    int cofs = lane * 4;
    int p = beg + half;
    for (; p + 2 < end; p += 4) {          // 2-edge unroll (stride-2 stream)
        int2 q0 = pairs[p], q1 = pairs[p + 2];
        f32x4 a0 = ld4(x + (size_t)q0.y * DIM + cofs);
        f32x4 b0 = ldnt4(eat + (size_t)q0.x * DIM + cofs);
        f32x4 a1 = ld4(x + (size_t)q1.y * DIM + cofs);
        f32x4 b1 = ldnt4(eat + (size_t)q1.x * DIM + cofs);
        acc_relu(acc, a0, b0);
        acc_relu(acc, a1, b1);
    }
    if (p < end) {
        int2 q0 = pairs[p];
        f32x4 a0 = ld4(x + (size_t)q0.y * DIM + cofs);
        f32x4 b0 = ldnt4(eat + (size_t)q0.x * DIM + cofs);
        acc_relu(acc, a0, b0);
    }
    if (half == 1) part[slotn][lane] = acc;
    __syncthreads();
    if (half == 0) {
        f32x4 o = part[slotn][lane];
        acc.x += o.x; acc.y += o.y; acc.z += o.z; acc.w += o.w;
        f32x4 xv = ld4(x + (size_t)node * DIM + cofs);
        acc.x = fmaf(epsv, xv.x, acc.x);
        acc.y = fmaf(epsv, xv.y, acc.y);
        acc.z = fmaf(epsv, xv.z, acc.z);
        acc.w = fmaf(epsv, xv.w, acc.w);
        ushort4 pk;
        pk.x = f2bf(acc.x); pk.y = f2bf(acc.y);
        pk.z = f2bf(acc.z); pk.w = f2bf(acc.w);
        *(ushort4*)(h + (size_t)node * DIM + cofs) = pk;
    }
}

// ---------------------------------------------------------------------------
// FALLBACK: atomic scatter into f32 aggr + convert kernel
// ---------------------------------------------------------------------------
__global__ __launch_bounds__(256) void scatter_kernel(
    const float* __restrict__ x, const float* __restrict__ ea,
    const int* __restrict__ idx, int E, float* __restrict__ buf)
{
    int wid = blockIdx.x * (blockDim.x >> 6) + (threadIdx.x >> 6);
    int lane = threadIdx.x & 63;
    if (wid >= E) return;
    int s = idx[wid];
    int d = idx[E + wid];
    float4 a = ((const float4*)(x + (size_t)s * DIM))[lane];
    float4 b = ((const float4*)(ea + (size_t)wid * DIM))[lane];
    float* dst = buf + (size_t)d * DIM + lane * 4;
    atomicAdd(dst + 0, fmaxf(a.x + b.x, 0.f));
    atomicAdd(dst + 1, fmaxf(a.y + b.y, 0.f));
    atomicAdd(dst + 2, fmaxf(a.z + b.z, 0.f));
    atomicAdd(dst + 3, fmaxf(a.w + b.w, 0.f));
}

__global__ __launch_bounds__(256) void conv_kernel(
    const float* __restrict__ x, const float* __restrict__ aggr,
    const float* __restrict__ eps_p, unsigned short* __restrict__ h)
{
    float epsv = 1.0f + eps_p[0];
    int i = blockIdx.x * blockDim.x + threadIdx.x;
    const int total = N_NODES * (DIM / 4);
    for (int f = i; f < total; f += gridDim.x * blockDim.x) {
        float4 xv = ((const float4*)x)[f];
        float4 av = ((const float4*)aggr)[f];
        ushort4 pk;
        pk.x = f2bf(fmaf(epsv, xv.x, av.x));
        pk.y = f2bf(fmaf(epsv, xv.y, av.y));
        pk.z = f2bf(fmaf(epsv, xv.z, av.z));
        pk.w = f2bf(fmaf(epsv, xv.w, av.w));
        ((ushort4*)h)[f] = pk;
    }
}

// ---------------------------------------------------------------------------
// MFMA GEMM stage 1 (BOTH paths): wave owns a 64x64 tile (4x4 MFMA grid).
// ---------------------------------------------------------------------------
__global__ __launch_bounds__(256) void gemm1_both(
    const unsigned short* __restrict__ hD, const unsigned short* __restrict__ hU,
    const unsigned short* __restrict__ Wt1d, const unsigned short* __restrict__ Wt1u,
    const float* __restrict__ b1d, const float* __restrict__ b1u,
    unsigned short* __restrict__ t1D, unsigned short* __restrict__ t1U,
    float* __restrict__ sumD, float* __restrict__ sqD,
    float* __restrict__ sumU, float* __restrict__ sqU)
{
    __shared__ unsigned short As[BM * BK];
    __shared__ unsigned short Bs[DIM * BK];
    int blk = blockIdx.x;
    bool down = blk < GRID_PER;
    int bb = down ? blk : blk - GRID_PER;
    const unsigned short* h  = down ? hD   : hU;
    const unsigned short* Wt = down ? Wt1d : Wt1u;
    const float* bias        = down ? b1d  : b1u;
    unsigned short* t1       = down ? t1D  : t1U;
    float* ssum              = down ? sumD : sumU;
    float* ssq               = down ? sqD  : sqU;

    int t = threadIdx.x;
    int w = t >> 6, l = t & 63, lrow = l & 15, kgrp = l >> 4;
    int row0 = bb * BM;

    f32x4 acc[16];
    #pragma unroll
    for (int i = 0; i < 16; ++i) acc[i] = (f32x4){0.f, 0.f, 0.f, 0.f};

    for (int k0 = 0; k0 < DIM; k0 += BK) {
        __syncthreads();
        #pragma unroll
        for (int it = 0; it < 2; ++it) {
            int g = it * 256 + t, row = g >> 3, kg = g & 7;
            int gr = row0 + row;
            s16x8 v = {0, 0, 0, 0, 0, 0, 0, 0};
            if (gr < N_NODES)
                v = *(const s16x8*)&h[(size_t)gr * DIM + k0 + kg * 8];
            *(s16x8*)&As[swz(row, kg)] = v;
        }
        #pragma unroll
        for (int it = 0; it < 8; ++it) {
            int g = it * 256 + t, row = g >> 3, kg = g & 7;
            s16x8 v = *(const s16x8*)&Wt[(size_t)row * DIM + k0 + kg * 8];
            *(s16x8*)&Bs[swz(row, kg)] = v;
        }
        __syncthreads();
        #pragma unroll
        for (int kk = 0; kk < 2; ++kk) {
            s16x8 af[4], bf[4];
            #pragma unroll
            for (int mi = 0; mi < 4; ++mi)
                af[mi] = *(const s16x8*)&As[swz(mi * 16 + lrow, kk * 4 + kgrp)];
            #pragma unroll
            for (int ni = 0; ni < 4; ++ni)
                bf[ni] = *(const s16x8*)&Bs[swz(w * 64 + ni * 16 + lrow, kk * 4 + kgrp)];
            #pragma unroll
            for (int mi = 0; mi < 4; ++mi)
                #pragma unroll
                for (int ni = 0; ni < 4; ++ni)
                    acc[mi * 4 + ni] = __builtin_amdgcn_mfma_f32_16x16x32_bf16(
                        af[mi], bf[ni], acc[mi * 4 + ni], 0, 0, 0);
        }
    }
    int slot = bb & (NSLOT - 1);
    #pragma unroll
    for (int ni = 0; ni < 4; ++ni) {
        int col = w * 64 + ni * 16 + lrow;
        float bv = bias[col];
        float s = 0.f, q = 0.f;
        #pragma unroll
        for (int mi = 0; mi < 4; ++mi) {
            #pragma unroll
            for (int r = 0; r < 4; ++r) {
                int grow = row0 + mi * 16 + kgrp * 4 + r;
                if (grow < N_NODES) {
                    float v = acc[mi * 4 + ni][r] + bv;
                    t1[(size_t)grow * DIM + col] = f2bf(v);
                    s += v; q += v * v;
                }
            }
        }
        s += __shfl_xor(s, 16); q += __shfl_xor(q, 16);
        s += __shfl_xor(s, 32); q += __shfl_xor(q, 32);
        if (kgrp == 0) {
            atomicAdd(&ssum[slot * DIM + col], s);
            atomicAdd(&ssq[slot * DIM + col], q);
        }
    }
}

// ---------------------------------------------------------------------------
// per-column BN params from NSLOT-sliced stats
// ---------------------------------------------------------------------------
__device__ inline void bn_finalize(
    const float* ssum, const float* ssq, const float* g, const float* b,
    float* scale, float* shift, int c)
{
    float s = 0.f, q = 0.f;
    #pragma unroll
    for (int k = 0; k < NSLOT; ++k) { s += ssum[k * DIM + c]; q += ssq[k * DIM + c]; }
    const float invN = 1.0f / (float)N_NODES;
    float mu = s * invN;
    float var = q * invN - mu * mu;
    float sc = g[c] * rsqrtf(var + 1e-5f);
    scale[c] = sc;
    shift[c] = b[c] - mu * sc;
}

// ---------------------------------------------------------------------------
// FUSED stage 2: per block (64 rows x 256 cols):
//   prologue: compute BN1 scale/shift for BOTH paths into LDS (from stats)
//   phase D:  accO = a1*(relu(t1D*scD+shD) @ W2d + b2d)
//   phase U:  acc  =      relu(t1U*scU+shU) @ W2u  (+ b2u in epilogue)
//   epilogue: out = x + accO + a2*(acc+b2u); final-BN stats -> sumF/sqF
// ---------------------------------------------------------------------------
__global__ __launch_bounds__(256) void gemm2_fused(
    const unsigned short* __restrict__ t1D, const unsigned short* __restrict__ t1U,
    const float* __restrict__ sumD, const float* __restrict__ sqD,
    const float* __restrict__ g1d, const float* __restrict__ bt1d,
    const float* __restrict__ sumU, const float* __restrict__ sqU,
    const float* __restrict__ g1u, const float* __restrict__ bt1u,
    const unsigned short* __restrict__ Wt2d, const unsigned short* __restrict__ Wt2u,
    const float* __restrict__ b2d, const float* __restrict__ b2u,
    const float* __restrict__ a1, const float* __restrict__ a2,
    const float* __restrict__ x, float* __restrict__ out,
    float* __restrict__ sumF, float* __restrict__ sqF)
{
    __shared__ unsigned short As[BM * BK];
    __shared__ unsigned short Bs[DIM * BK];
    __shared__ float scDl[DIM], shDl[DIM], scUl[DIM], shUl[DIM];
    int t = threadIdx.x;
    int w = t >> 6, l = t & 63, lrow = l & 15, kgrp = l >> 4;
    int bb = blockIdx.x;
    int row0 = bb * BM;

    // prologue: BN1 params for both paths (redundant per block, ~8KB reads)
    bn_finalize(sumD, sqD, g1d, bt1d, scDl, shDl, t);
    bn_finalize(sumU, sqU, g1u, bt1u, scUl, shUl, t);
    float a1v = a1[0], a2v = a2[0];

    f32x4 acc[16], accO[16];
    #pragma unroll
    for (int i = 0; i < 16; ++i) acc[i] = (f32x4){0.f, 0.f, 0.f, 0.f};

    // ---- phase D ----
    for (int k0 = 0; k0 < DIM; k0 += BK) {
        __syncthreads();
        #pragma unroll
        for (int it = 0; it < 2; ++it) {
            int g = it * 256 + t, row = g >> 3, kg = g & 7;
            int gr = row0 + row;
            s16x8 pack = {0, 0, 0, 0, 0, 0, 0, 0};
            if (gr < N_NODES) {
                s16x8 tv = *(const s16x8*)(t1D + (size_t)gr * DIM + k0 + kg * 8);
                #pragma unroll
                for (int j = 0; j < 8; ++j) {
                    int c = k0 + kg * 8 + j;
                    pack[j] = f2bf(fmaxf(fmaf(bf2f((unsigned short)tv[j]), scDl[c], shDl[c]), 0.f));
                }
            }
            *(s16x8*)&As[swz(row, kg)] = pack;
        }
        #pragma unroll
        for (int it = 0; it < 8; ++it) {
            int g = it * 256 + t, row = g >> 3, kg = g & 7;
            s16x8 v = *(const s16x8*)&Wt2d[(size_t)row * DIM + k0 + kg * 8];
            *(s16x8*)&Bs[swz(row, kg)] = v;
        }
        __syncthreads();
        #pragma unroll
        for (int kk = 0; kk < 2; ++kk) {
            s16x8 af[4], bf[4];
            #pragma unroll
            for (int mi = 0; mi < 4; ++mi)
                af[mi] = *(const s16x8*)&As[swz(mi * 16 + lrow, kk * 4 + kgrp)];
            #pragma unroll
            for (int ni = 0; ni < 4; ++ni)
                bf[ni] = *(const s16x8*)&Bs[swz(w * 64 + ni * 16 + lrow, kk * 4 + kgrp)];
            #pragma unroll
            for (int mi = 0; mi < 4; ++mi)
                #pragma unroll
                for (int ni = 0; ni < 4; ++ni)
                    acc[mi * 4 + ni] = __builtin_amdgcn_mfma_f32_16x16x32_bf16(
                        af[mi], bf[ni], acc[mi * 4 + ni], 0, 0, 0);
        }
    }
    // stash path-D result (alpha1 and bias applied), reset acc
    #pragma unroll
    for (int ni = 0; ni < 4; ++ni) {
        float bv = b2d[w * 64 + ni * 16 + lrow];
        #pragma unroll
        for (int mi = 0; mi < 4; ++mi) {
            #pragma unroll
            for (int r = 0; r < 4; ++r)
                accO[mi * 4 + ni][r] = a1v * (acc[mi * 4 + ni][r] + bv);
            acc[mi * 4 + ni] = (f32x4){0.f, 0.f, 0.f, 0.f};
        }
    }

    // ---- phase U ----
    for (int k0 = 0; k0 < DIM; k0 += BK) {
        __syncthreads();
        #pragma unroll
        for (int it = 0; it < 2; ++it) {
            int g = it * 256 + t, row = g >> 3, kg = g & 7;
            int gr = row0 + row;
            s16x8 pack = {0, 0, 0, 0, 0, 0, 0, 0};
            if (gr < N_NODES) {
                s16x8 tv = *(const s16x8*)(t1U + (size_t)gr * DIM + k0 + kg * 8);
                #pragma unroll
                for (int j = 0; j < 8; ++j) {
                    int c = k0 + kg * 8 + j;
                    pack[j] = f2bf(fmaxf(fmaf(bf2f((unsigned short)tv[j]), scUl[c], shUl[c]), 0.f));
                }
            }
            *(s16x8*)&As[swz(row, kg)] = pack;
        }
        #pragma unroll
        for (int it = 0; it < 8; ++it) {
            int g = it * 256 + t, row = g >> 3, kg = g & 7;
            s16x8 v = *(const s16x8*)&Wt2u[(size_t)row * DIM + k0 + kg * 8];
            *(s16x8*)&Bs[swz(row, kg)] = v;
        }
        __syncthreads();
        #pragma unroll
        for (int kk = 0; kk < 2; ++kk) {
            s16x8 af[4], bf[4];
            #pragma unroll
            for (int mi = 0; mi < 4; ++mi)
                af[mi] = *(const s16x8*)&As[swz(mi * 16 + lrow, kk * 4 + kgrp)];
            #pragma unroll
            for (int ni = 0; ni < 4; ++ni)
                bf[ni] = *(const s16x8*)&Bs[swz(w * 64 + ni * 16 + lrow, kk * 4 + kgrp)];
            #pragma unroll
            for (int mi = 0; mi < 4; ++mi)
                #pragma unroll
                for (int ni = 0; ni < 4; ++ni)
                    acc[mi * 4 + ni] = __builtin_amdgcn_mfma_f32_16x16x32_bf16(
                        af[mi], bf[ni], acc[mi * 4 + ni], 0, 0, 0);
        }
    }

    // ---- epilogue: out = x + C1 + C2, final-BN stats ----
    int slot = bb & (NSLOT - 1);
    #pragma unroll
    for (int ni = 0; ni < 4; ++ni) {
        int col = w * 64 + ni * 16 + lrow;
        float bvU = b2u[col];
        float s = 0.f, q = 0.f;
        #pragma unroll
        for (int mi = 0; mi < 4; ++mi) {
            #pragma unroll
            for (int r = 0; r < 4; ++r) {
                int grow = row0 + mi * 16 + kgrp * 4 + r;
                if (grow < N_NODES) {
                    size_t o = (size_t)grow * DIM + col;
                    float v = x[o] + accO[mi * 4 + ni][r]
                            + a2v * (acc[mi * 4 + ni][r] + bvU);
                    out[o] = v;
                    s += v; q += v * v;
                }
            }
        }
        s += __shfl_xor(s, 16); q += __shfl_xor(q, 16);
        s += __shfl_xor(s, 32); q += __shfl_xor(q, 32);
        if (kgrp == 0) {
            atomicAdd(&sumF[slot * DIM + col], s);
            atomicAdd(&sqF[slot * DIM + col], q);
        }
    }
}

// ---------------------------------------------------------------------------
// final BN + ReLU with fused finalize (per-block LDS scale/shift)
// ---------------------------------------------------------------------------
__global__ __launch_bounds__(256) void bnrelu_kernel(
    float* __restrict__ out,
    const float* __restrict__ sumF, const float* __restrict__ sqF,
    const float* __restrict__ bng, const float* __restrict__ bnb)
{
    __shared__ float scl[DIM], shl[DIM];
    bn_finalize(sumF, sqF, bng, bnb, scl, shl, threadIdx.x);
    __syncthreads();
    int idx = blockIdx.x * blockDim.x + threadIdx.x;
    const int total = N_NODES * (DIM / 4);
    for (int f = idx; f < total; f += gridDim.x * blockDim.x) {
        float4 v = ((float4*)out)[f];
        int c = (f * 4) & (DIM - 1);
        float4 sc = *(const float4*)(scl + c);
        float4 sh = *(const float4*)(shl + c);
        v.x = fmaxf(v.x * sc.x + sh.x, 0.0f);
        v.y = fmaxf(v.y * sc.y + sh.y, 0.0f);
        v.z = fmaxf(v.z * sc.z + sh.z, 0.0f);
        v.w = fmaxf(v.w * sc.w + sh.w, 0.0f);
        ((float4*)out)[f] = v;
    }
}

extern "C" void kernel_launch(void* const* d_in, const int* in_sizes, int n_in,
                              void* d_out, int out_size, void* d_ws, size_t ws_size,
                              hipStream_t stream)
{
    const float* x    = (const float*)d_in[0];
    const int*   ei   = (const int*)  d_in[1];
    const float* ea   = (const float*)d_in[2];
    const int*   vi   = (const int*)  d_in[3];
    const float* vea  = (const float*)d_in[4];
    const float* epsd = (const float*)d_in[5];
    const float* W1d  = (const float*)d_in[6];
    const float* b1d  = (const float*)d_in[7];
    const float* g1d  = (const float*)d_in[8];
    const float* bt1d = (const float*)d_in[9];
    const float* W2d  = (const float*)d_in[10];
    const float* b2d  = (const float*)d_in[11];
    const float* epsu = (const float*)d_in[12];
    const float* W1u  = (const float*)d_in[13];
    const float* b1u  = (const float*)d_in[14];
    const float* g1u  = (const float*)d_in[15];
    const float* bt1u = (const float*)d_in[16];
    const float* W2u  = (const float*)d_in[17];
    const float* b2u  = (const float*)d_in[18];
    const float* bng  = (const float*)d_in[19];
    const float* bnb  = (const float*)d_in[20];
    const float* a1   = (const float*)d_in[21];
    const float* a2   = (const float*)d_in[22];

    float* out = (float*)d_out;

    // ---- workspace layout ----
    char* p = (char*)d_ws;
    unsigned short* hD  = (unsigned short*)p;  p += (size_t)N_NODES * DIM * 2;
    unsigned short* hU  = (unsigned short*)p;  p += (size_t)N_NODES * DIM * 2;
    unsigned short* t1D = (unsigned short*)p;  p += (size_t)N_NODES * DIM * 2;
    unsigned short* t1U = (unsigned short*)p;  p += (size_t)N_NODES * DIM * 2;
    unsigned short* Wt  = (unsigned short*)p;  p += (size_t)4 * DIM * DIM * 2;
    // zeroed region: stats (6 slices) + offsets
    char* zero_base = p;
    float* stats = (float*)p;                  p += (size_t)6 * NSLOT * DIM * 4;
    int* offD = (int*)p;                       p += (size_t)(N_NODES + 1) * 4;
    int* offU = (int*)p;                       p += (size_t)(N_NODES + 1) * 4;
    size_t zero_bytes = (size_t)(p - zero_base);
    int* curD = (int*)p;                       p += (size_t)N_NODES * 4;
    int* curU = (int*)p;                       p += (size_t)N_NODES * 4;
    char* union_base = p;
    int2* pairsD = (int2*)p;                   p += (size_t)NE * 8;
    int2* pairsU = (int2*)p;                   p += (size_t)NEV * 8;
    size_t need_csr = (size_t)(p - (char*)d_ws);
    float* aggr = (float*)union_base;          // fallback-only, overlaps pairs
    size_t need_fb = (size_t)(union_base - (char*)d_ws) + (size_t)N_NODES * DIM * 4;
    bool use_csr = ws_size >= need_csr;

    float* sumD = stats;
    float* sqD  = stats + 1 * NSLOT * DIM;
    float* sumU = stats + 2 * NSLOT * DIM;
    float* sqU  = stats + 3 * NSLOT * DIM;
    float* sumF = stats + 4 * NSLOT * DIM;
    float* sqF  = stats + 5 * NSLOT * DIM;

    unsigned short* Wt1d = Wt;
    unsigned short* Wt2d = Wt + 1 * (size_t)DIM * DIM;
    unsigned short* Wt1u = Wt + 2 * (size_t)DIM * DIM;
    unsigned short* Wt2u = Wt + 3 * (size_t)DIM * DIM;

    hipMemsetAsync(zero_base, 0, zero_bytes, stream);
    prepw_kernel<<<4 * DIM, 256, 0, stream>>>(W1d, W2d, W1u, W2u, Wt);

    if (use_csr) {
        hist2_kernel<<<(NE + NEV + 255) / 256, 256, 0, stream>>>(ei, vi, offD, offU);
        scan2_kernel<<<2, 1024, 0, stream>>>(offD, curD, offU, curU);
        fill2_kernel<<<(NE + NEV + 255) / 256, 256, 0, stream>>>(
            ei, vi, curD, curU, pairsD, pairsU);
        gather2_kernel<<<N_NODES, 256, 0, stream>>>(
            x, ea, vea, offD, pairsD, offU, pairsU, epsd, epsu, hD, hU);
    } else if (ws_size >= need_fb) {
        hipMemsetAsync(aggr, 0, (size_t)N_NODES * DIM * 4, stream);
        scatter_kernel<<<(NE + 3) / 4, 256, 0, stream>>>(x, ea, ei, NE, aggr);
        conv_kernel<<<2048, 256, 0, stream>>>(x, aggr, epsd, hD);
        hipMemsetAsync(aggr, 0, (size_t)N_NODES * DIM * 4, stream);
        scatter_kernel<<<(NEV + 3) / 4, 256, 0, stream>>>(x, vea, vi, NEV, aggr);
        conv_kernel<<<2048, 256, 0, stream>>>(x, aggr, epsu, hU);
    }

    // ---- BOTH stage-1 GEMMs in one launch ----
    gemm1_both<<<2 * GRID_PER, 256, 0, stream>>>(
        hD, hU, Wt1d, Wt1u, b1d, b1u, t1D, t1U, sumD, sqD, sumU, sqU);

    // ---- fused stage 2: both paths + residual combine + final stats ----
    gemm2_fused<<<GRID_PER, 256, 0, stream>>>(
        t1D, t1U, sumD, sqD, g1d, bt1d, sumU, sqU, g1u, bt1u,
        Wt2d, Wt2u, b2d, b2u, a1, a2, x, out, sumF, sqF);

    // ---- final BN + ReLU (finalize fused) ----
    bnrelu_kernel<<<2048, 256, 0, stream>>>(out, sumF, sqF, bng, bnb);
}

// Round 9
// 415.114 us; speedup vs baseline: 4.8634x; 1.0561x over previous
//
#include <hip/hip_runtime.h>
#include <math.h>

#define N_NODES 50000
#define DIM 256
#define NE 300000
#define NEV 100000
#define BM 64
#define BK 64
#define NSLOT 8
#define GRID_PER ((N_NODES + BM - 1) / BM)   // 782
#define PREP_W_BLOCKS (4 * DIM)              // 1024
#define PREP_X_BLOCKS 1024
#define HIST_BLOCKS ((NE + NEV + 255) / 256) // 1563

typedef float f32x4 __attribute__((ext_vector_type(4)));
typedef short s16x8 __attribute__((ext_vector_type(8)));

__device__ inline unsigned short f2bf(float f) {
    unsigned u = __float_as_uint(f);
    u += 0x7FFF + ((u >> 16) & 1);            // round-to-nearest-even
    return (unsigned short)(u >> 16);
}
__device__ inline float bf2f(unsigned short s) {
    return __uint_as_float(((unsigned)s) << 16);
}
// swizzled halfword offset inside a [R][64] bf16 tile (16B granules, T2 XOR)
__device__ inline int swz(int row, int kg) {
    return row * BK + ((kg ^ (row & 7)) << 3);
}
// async 16B global->LDS (linear dest; swizzle lives in the SOURCE layout)
__device__ inline void gl16(const unsigned short* g, unsigned short* l) {
    __builtin_amdgcn_global_load_lds(
        (const __attribute__((address_space(1))) void*)g,
        (__attribute__((address_space(3))) void*)l, 16, 0, 0);
}
// pre-swizzled h destination offset for (node, lane) -> lane's 4 cols
__device__ inline int hdst(int node, int lane) {
    return ((lane >> 4) << 6) + (((((lane >> 1) & 7)) ^ (node & 7)) << 3)
         + ((lane & 1) << 2);
}

// ---------------------------------------------------------------------------
// prep: [blocks 0..1023] W [K][N] f32 -> Wt [N][K] bf16 PRE-SWIZZLED
//       [blocks 1024..2047] xb = bf16(x)
//       [blocks 2048..] dst-degree histogram for both edge sets
// ---------------------------------------------------------------------------
__global__ __launch_bounds__(256) void prep_kernel(
    const float* __restrict__ W1d, const float* __restrict__ W2d,
    const float* __restrict__ W1u, const float* __restrict__ W2u,
    unsigned short* __restrict__ Wt,
    const float* __restrict__ x, unsigned short* __restrict__ xb,
    const int* __restrict__ ei, const int* __restrict__ vi,
    int* __restrict__ degD, int* __restrict__ degU)
{
    int b = blockIdx.x, t = threadIdx.x;
    if (b < PREP_W_BLOCKS) {
        int w = b >> 8, n = b & 255;
        const float* W = (w == 0) ? W1d : (w == 1) ? W2d : (w == 2) ? W1u : W2u;
        int k0 = (t >> 6) << 6, kg = (t >> 3) & 7, j = t & 7;
        int src = k0 + ((kg ^ (n & 7)) << 3) + j;     // inverse-XOR source col
        Wt[(size_t)w * DIM * DIM + (size_t)n * DIM + t] =
            f2bf(W[(size_t)src * DIM + n]);
    } else if (b < PREP_W_BLOCKS + PREP_X_BLOCKS) {
        int idx = (b - PREP_W_BLOCKS) * 256 + t;
        const int stride = PREP_X_BLOCKS * 256;
        const int total = N_NODES * (DIM / 8);
        for (int f = idx; f < total; f += stride) {
            float4 v0 = ((const float4*)x)[f * 2];
            float4 v1 = ((const float4*)x)[f * 2 + 1];
            s16x8 pk;
            pk[0] = f2bf(v0.x); pk[1] = f2bf(v0.y);
            pk[2] = f2bf(v0.z); pk[3] = f2bf(v0.w);
            pk[4] = f2bf(v1.x); pk[5] = f2bf(v1.y);
            pk[6] = f2bf(v1.z); pk[7] = f2bf(v1.w);
            *(s16x8*)(xb + (size_t)f * 8) = pk;
        }
    } else {
        int i = (b - PREP_W_BLOCKS - PREP_X_BLOCKS) * 256 + t;
        if (i < NE) atomicAdd(&degD[ei[NE + i]], 1);
        else if (i < NE + NEV) { int j2 = i - NE; atomicAdd(&degU[vi[NEV + j2]], 1); }
    }
}

// ---------------------------------------------------------------------------
// CSR scan + fill (packs (e,src) int2)
// ---------------------------------------------------------------------------
__global__ __launch_bounds__(1024) void scan2_kernel(
    int* __restrict__ offD, int* __restrict__ curD,
    int* __restrict__ offU, int* __restrict__ curU)
{
    int* deg_offsets = (blockIdx.x == 0) ? offD : offU;
    int* cursor      = (blockIdx.x == 0) ? curD : curU;
    int E            = (blockIdx.x == 0) ? NE : NEV;
    __shared__ int part[1024];
    int t = threadIdx.x;
    const int CH = (N_NODES + 1023) / 1024;
    int beg = t * CH;
    int end = min(beg + CH, N_NODES);
    int s = 0;
    for (int i = beg; i < end; i++) s += deg_offsets[i];
    part[t] = s;
    __syncthreads();
    for (int off = 1; off < 1024; off <<= 1) {
        int v = part[t];
        int u = (t >= off) ? part[t - off] : 0;
        __syncthreads();
        part[t] = v + u;
        __syncthreads();
    }
    int run = (t > 0) ? part[t - 1] : 0;
    for (int i = beg; i < end; i++) {
        int dv = deg_offsets[i];
        deg_offsets[i] = run;
        cursor[i] = run;
        run += dv;
    }
    if (t == 1023) deg_offsets[N_NODES] = E;
}

__global__ __launch_bounds__(256) void fill2_kernel(
    const int* __restrict__ ei, const int* __restrict__ vi,
    int* __restrict__ curD, int* __restrict__ curU,
    int2* __restrict__ pairsD, int2* __restrict__ pairsU)
{
    int i = blockIdx.x * blockDim.x + threadIdx.x;
    if (i < NE) {
        int s = ei[i], d = ei[NE + i];
        int pos = atomicAdd(&curD[d], 1);
        pairsD[pos] = make_int2(i, s);
    } else if (i < NE + NEV) {
        int j = i - NE;
        int s = vi[j], d = vi[NEV + j];
        int pos = atomicAdd(&curU[d], 1);
        pairsU[pos] = make_int2(j, s);
    }
}

// ---------------------------------------------------------------------------
// gather: TWO waves per node (even/odd edge split); x rows read as bf16 (xb);
// emits h = bf16((1+eps)x + aggr) in PRE-SWIZZLED layout for gemm1 gl16.
// ---------------------------------------------------------------------------
__device__ inline f32x4 ldnt4(const float* p) {
    return __builtin_nontemporal_load((const f32x4*)p);
}
__device__ inline f32x4 bf4f(ushort4 v) {
    f32x4 r;
    r.x = bf2f(v.x); r.y = bf2f(v.y); r.z = bf2f(v.z); r.w = bf2f(v.w);
    return r;
}
__device__ inline void acc_relu(f32x4& acc, f32x4 a, f32x4 b) {
    acc.x += fmaxf(a.x + b.x, 0.f);
    acc.y += fmaxf(a.y + b.y, 0.f);
    acc.z += fmaxf(a.z + b.z, 0.f);
    acc.w += fmaxf(a.w + b.w, 0.f);
}

__global__ __launch_bounds__(256) void gather2_kernel(
    const unsigned short* __restrict__ xb, const float* __restrict__ ea,
    const float* __restrict__ vea,
    const int* __restrict__ offD, const int2* __restrict__ pairsD,
    const int* __restrict__ offU, const int2* __restrict__ pairsU,
    const float* __restrict__ epsd, const float* __restrict__ epsu,
    unsigned short* __restrict__ hD, unsigned short* __restrict__ hU)
{
    __shared__ f32x4 part[2][64];
    int warp = threadIdx.x >> 6;
    int lane = threadIdx.x & 63;
    int slotn = warp >> 1;
    int half = warp & 1;
    int nidx = blockIdx.x * 2 + slotn;
    bool down = nidx < N_NODES;
    int node = down ? nidx : nidx - N_NODES;
    const int* off      = down ? offD   : offU;
    const int2* pairs   = down ? pairsD : pairsU;
    const float* eat    = down ? ea     : vea;
    unsigned short* h   = down ? hD     : hU;
    float epsv = 1.0f + (down ? epsd[0] : epsu[0]);

    int beg = off[node], end = off[node + 1];
    f32x4 acc = {0.f, 0.f, 0.f, 0.f};
    int cofs = lane * 4;
    int p = beg + half;
    for (; p + 2 < end; p += 4) {          // 2-edge unroll (stride-2 stream)
        int2 q0 = pairs[p], q1 = pairs[p + 2];
        ushort4 a0 = *(const ushort4*)(xb + (size_t)q0.y * DIM + cofs);
        f32x4 b0 = ldnt4(eat + (size_t)q0.x * DIM + cofs);
        ushort4 a1 = *(const ushort4*)(xb + (size_t)q1.y * DIM + cofs);
        f32x4 b1 = ldnt4(eat + (size_t)q1.x * DIM + cofs);
        acc_relu(acc, bf4f(a0), b0);
        acc_relu(acc, bf4f(a1), b1);
    }
    if (p < end) {
        int2 q0 = pairs[p];
        ushort4 a0 = *(const ushort4*)(xb + (size_t)q0.y * DIM + cofs);
        f32x4 b0 = ldnt4(eat + (size_t)q0.x * DIM + cofs);
        acc_relu(acc, bf4f(a0), b0);
    }
    if (half == 1) part[slotn][lane] = acc;
    __syncthreads();
    if (half == 0) {
        f32x4 o = part[slotn][lane];
        acc.x += o.x; acc.y += o.y; acc.z += o.z; acc.w += o.w;
        f32x4 xv = bf4f(*(const ushort4*)(xb + (size_t)node * DIM + cofs));
        acc.x = fmaf(epsv, xv.x, acc.x);
        acc.y = fmaf(epsv, xv.y, acc.y);
        acc.z = fmaf(epsv, xv.z, acc.z);
        acc.w = fmaf(epsv, xv.w, acc.w);
        ushort4 pk;
        pk.x = f2bf(acc.x); pk.y = f2bf(acc.y);
        pk.z = f2bf(acc.z); pk.w = f2bf(acc.w);
        *(ushort4*)(h + (size_t)node * DIM + hdst(node, lane)) = pk;
    }
}

// ---------------------------------------------------------------------------
// FALLBACK: atomic scatter into f32 aggr + convert (pre-swizzled h out)
// ---------------------------------------------------------------------------
__global__ __launch_bounds__(256) void scatter_kernel(
    const float* __restrict__ x, const float* __restrict__ ea,
    const int* __restrict__ idx, int E, float* __restrict__ buf)
{
    int wid = blockIdx.x * (blockDim.x >> 6) + (threadIdx.x >> 6);
    int lane = threadIdx.x & 63;
    if (wid >= E) return;
    int s = idx[wid];
    int d = idx[E + wid];
    float4 a = ((const float4*)(x + (size_t)s * DIM))[lane];
    float4 b = ((const float4*)(ea + (size_t)wid * DIM))[lane];
    float* dst = buf + (size_t)d * DIM + lane * 4;
    atomicAdd(dst + 0, fmaxf(a.x + b.x, 0.f));
    atomicAdd(dst + 1, fmaxf(a.y + b.y, 0.f));
    atomicAdd(dst + 2, fmaxf(a.z + b.z, 0.f));
    atomicAdd(dst + 3, fmaxf(a.w + b.w, 0.f));
}

__global__ __launch_bounds__(256) void conv_kernel(
    const float* __restrict__ x, const float* __restrict__ aggr,
    const float* __restrict__ eps_p, unsigned short* __restrict__ h)
{
    float epsv = 1.0f + eps_p[0];
    int i = blockIdx.x * blockDim.x + threadIdx.x;
    const int total = N_NODES * 64;
    for (int f = i; f < total; f += gridDim.x * blockDim.x) {
        int node = f >> 6, lane = f & 63;
        size_t o = (size_t)node * DIM + lane * 4;
        float4 xv = *(const float4*)(x + o);
        float4 av = *(const float4*)(aggr + o);
        ushort4 pk;
        pk.x = f2bf(fmaf(epsv, xv.x, av.x));
        pk.y = f2bf(fmaf(epsv, xv.y, av.y));
        pk.z = f2bf(fmaf(epsv, xv.z, av.z));
        pk.w = f2bf(fmaf(epsv, xv.w, av.w));
        *(ushort4*)(h + (size_t)node * DIM + hdst(node, lane)) = pk;
    }
}

// ---------------------------------------------------------------------------
// MFMA GEMM stage 1 (BOTH paths): A and B staged via global_load_lds
// (linear LDS dest; h and Wt are pre-swizzled in global memory).
// ---------------------------------------------------------------------------
__global__ __launch_bounds__(256) void gemm1_both(
    const unsigned short* __restrict__ hD, const unsigned short* __restrict__ hU,
    const unsigned short* __restrict__ Wt1d, const unsigned short* __restrict__ Wt1u,
    const float* __restrict__ b1d, const float* __restrict__ b1u,
    unsigned short* __restrict__ t1D, unsigned short* __restrict__ t1U,
    float* __restrict__ sumD, float* __restrict__ sqD,
    float* __restrict__ sumU, float* __restrict__ sqU)
{
    __shared__ unsigned short As[BM * BK];
    __shared__ unsigned short Bs[DIM * BK];
    int blk = blockIdx.x;
    bool down = blk < GRID_PER;
    int bb = down ? blk : blk - GRID_PER;
    const unsigned short* h  = down ? hD   : hU;
    const unsigned short* Wt = down ? Wt1d : Wt1u;
    const float* bias        = down ? b1d  : b1u;
    unsigned short* t1       = down ? t1D  : t1U;
    float* ssum              = down ? sumD : sumU;
    float* ssq               = down ? sqD  : sqU;

    int t = threadIdx.x;
    int w = t >> 6, l = t & 63, lrow = l & 15, kgrp = l >> 4;
    int row0 = bb * BM;

    f32x4 acc[16];
    #pragma unroll
    for (int i = 0; i < 16; ++i) acc[i] = (f32x4){0.f, 0.f, 0.f, 0.f};

    for (int k0 = 0; k0 < DIM; k0 += BK) {
        __syncthreads();
        #pragma unroll
        for (int it = 0; it < 2; ++it) {
            int g = it * 256 + t;
            gl16(h + (size_t)(row0 + (g >> 3)) * DIM + k0 + ((g & 7) << 3),
                 &As[g << 3]);
        }
        #pragma unroll
        for (int it = 0; it < 8; ++it) {
            int g = it * 256 + t;
            gl16(Wt + (size_t)(g >> 3) * DIM + k0 + ((g & 7) << 3),
                 &Bs[g << 3]);
        }
        __syncthreads();
        #pragma unroll
        for (int kk = 0; kk < 2; ++kk) {
            s16x8 af[4], bf[4];
            #pragma unroll
            for (int mi = 0; mi < 4; ++mi)
                af[mi] = *(const s16x8*)&As[swz(mi * 16 + lrow, kk * 4 + kgrp)];
            #pragma unroll
            for (int ni = 0; ni < 4; ++ni)
                bf[ni] = *(const s16x8*)&Bs[swz(w * 64 + ni * 16 + lrow, kk * 4 + kgrp)];
            #pragma unroll
            for (int mi = 0; mi < 4; ++mi)
                #pragma unroll
                for (int ni = 0; ni < 4; ++ni)
                    acc[mi * 4 + ni] = __builtin_amdgcn_mfma_f32_16x16x32_bf16(
                        af[mi], bf[ni], acc[mi * 4 + ni], 0, 0, 0);
        }
    }
    int slot = bb & (NSLOT - 1);
    #pragma unroll
    for (int ni = 0; ni < 4; ++ni) {
        int col = w * 64 + ni * 16 + lrow;
        float bv = bias[col];
        float s = 0.f, q = 0.f;
        #pragma unroll
        for (int mi = 0; mi < 4; ++mi) {
            #pragma unroll
            for (int r = 0; r < 4; ++r) {
                int grow = row0 + mi * 16 + kgrp * 4 + r;
                if (grow < N_NODES) {
                    float v = acc[mi * 4 + ni][r] + bv;
                    t1[(size_t)grow * DIM + col] = f2bf(v);
                    s += v; q += v * v;
                }
            }
        }
        s += __shfl_xor(s, 16); q += __shfl_xor(q, 16);
        s += __shfl_xor(s, 32); q += __shfl_xor(q, 32);
        if (kgrp == 0) {
            atomicAdd(&ssum[slot * DIM + col], s);
            atomicAdd(&ssq[slot * DIM + col], q);
        }
    }
}

// ---------------------------------------------------------------------------
// per-column BN params from NSLOT-sliced stats
// ---------------------------------------------------------------------------
__device__ inline void bn_finalize(
    const float* ssum, const float* ssq, const float* g, const float* b,
    float* scale, float* shift, int c)
{
    float s = 0.f, q = 0.f;
    #pragma unroll
    for (int k = 0; k < NSLOT; ++k) { s += ssum[k * DIM + c]; q += ssq[k * DIM + c]; }
    const float invN = 1.0f / (float)N_NODES;
    float mu = s * invN;
    float var = q * invN - mu * mu;
    float sc = g[c] * rsqrtf(var + 1e-5f);
    scale[c] = sc;
    shift[c] = b[c] - mu * sc;
}

// ---------------------------------------------------------------------------
// FUSED stage 2: BN1(LDS) -> GEMM D -> GEMM U -> out = x + C1 + C2 + stats.
// A reg-staged (BN work) with write-side XOR; B via gl16 (pre-swizzled Wt2).
// ---------------------------------------------------------------------------
__global__ __launch_bounds__(256) void gemm2_fused(
    const unsigned short* __restrict__ t1D, const unsigned short* __restrict__ t1U,
    const float* __restrict__ sumD, const float* __restrict__ sqD,
    const float* __restrict__ g1d, const float* __restrict__ bt1d,
    const float* __restrict__ sumU, const float* __restrict__ sqU,
    const float* __restrict__ g1u, const float* __restrict__ bt1u,
    const unsigned short* __restrict__ Wt2d, const unsigned short* __restrict__ Wt2u,
    const float* __restrict__ b2d, const float* __restrict__ b2u,
    const float* __restrict__ a1, const float* __restrict__ a2,
    const float* __restrict__ x, float* __restrict__ out,
    float* __restrict__ sumF, float* __restrict__ sqF)
{
    __shared__ unsigned short As[BM * BK];
    __shared__ unsigned short Bs[DIM * BK];
    __shared__ float scDl[DIM], shDl[DIM], scUl[DIM], shUl[DIM];
    int t = threadIdx.x;
    int w = t >> 6, l = t & 63, lrow = l & 15, kgrp = l >> 4;
    int bb = blockIdx.x;
    int row0 = bb * BM;

    bn_finalize(sumD, sqD, g1d, bt1d, scDl, shDl, t);
    bn_finalize(sumU, sqU, g1u, bt1u, scUl, shUl, t);
    float a1v = a1[0], a2v = a2[0];

    f32x4 acc[16], accO[16];
    #pragma unroll
    for (int i = 0; i < 16; ++i) acc[i] = (f32x4){0.f, 0.f, 0.f, 0.f};

    #pragma unroll
    for (int phase = 0; phase < 2; ++phase) {
        const unsigned short* t1 = phase == 0 ? t1D : t1U;
        const unsigned short* Wt = phase == 0 ? Wt2d : Wt2u;
        const float* scl = phase == 0 ? scDl : scUl;
        const float* shl = phase == 0 ? shDl : shUl;
        for (int k0 = 0; k0 < DIM; k0 += BK) {
            __syncthreads();
            #pragma unroll
            for (int it = 0; it < 8; ++it) {
                int g = it * 256 + t;
                gl16(Wt + (size_t)(g >> 3) * DIM + k0 + ((g & 7) << 3),
                     &Bs[g << 3]);
            }
            #pragma unroll
            for (int it = 0; it < 2; ++it) {
                int g = it * 256 + t, row = g >> 3, kg = g & 7;
                int gr = row0 + row;
                s16x8 pack = {0, 0, 0, 0, 0, 0, 0, 0};
                if (gr < N_NODES) {
                    s16x8 tv = *(const s16x8*)(t1 + (size_t)gr * DIM + k0 + kg * 8);
                    #pragma unroll
                    for (int j = 0; j < 8; ++j) {
                        int c = k0 + kg * 8 + j;
                        pack[j] = f2bf(fmaxf(fmaf(bf2f((unsigned short)tv[j]), scl[c], shl[c]), 0.f));
                    }
                }
                *(s16x8*)&As[swz(row, kg)] = pack;
            }
            __syncthreads();
            #pragma unroll
            for (int kk = 0; kk < 2; ++kk) {
                s16x8 af[4], bf[4];
                #pragma unroll
                for (int mi = 0; mi < 4; ++mi)
                    af[mi] = *(const s16x8*)&As[swz(mi * 16 + lrow, kk * 4 + kgrp)];
                #pragma unroll
                for (int ni = 0; ni < 4; ++ni)
                    bf[ni] = *(const s16x8*)&Bs[swz(w * 64 + ni * 16 + lrow, kk * 4 + kgrp)];
                #pragma unroll
                for (int mi = 0; mi < 4; ++mi)
                    #pragma unroll
                    for (int ni = 0; ni < 4; ++ni)
                        acc[mi * 4 + ni] = __builtin_amdgcn_mfma_f32_16x16x32_bf16(
                            af[mi], bf[ni], acc[mi * 4 + ni], 0, 0, 0);
            }
        }
        if (phase == 0) {
            #pragma unroll
            for (int ni = 0; ni < 4; ++ni) {
                float bv = b2d[w * 64 + ni * 16 + lrow];
                #pragma unroll
                for (int mi = 0; mi < 4; ++mi) {
                    #pragma unroll
                    for (int r = 0; r < 4; ++r)
                        accO[mi * 4 + ni][r] = a1v * (acc[mi * 4 + ni][r] + bv);
                    acc[mi * 4 + ni] = (f32x4){0.f, 0.f, 0.f, 0.f};
                }
            }
        }
    }

    int slot = bb & (NSLOT - 1);
    #pragma unroll
    for (int ni = 0; ni < 4; ++ni) {
        int col = w * 64 + ni * 16 + lrow;
        float bvU = b2u[col];
        float s = 0.f, q = 0.f;
        #pragma unroll
        for (int mi = 0; mi < 4; ++mi) {
            #pragma unroll
            for (int r = 0; r < 4; ++r) {
                int grow = row0 + mi * 16 + kgrp * 4 + r;
                if (grow < N_NODES) {
                    size_t o = (size_t)grow * DIM + col;
                    float v = x[o] + accO[mi * 4 + ni][r]
                            + a2v * (acc[mi * 4 + ni][r] + bvU);
                    out[o] = v;
                    s += v; q += v * v;
                }
            }
        }
        s += __shfl_xor(s, 16); q += __shfl_xor(q, 16);
        s += __shfl_xor(s, 32); q += __shfl_xor(q, 32);
        if (kgrp == 0) {
            atomicAdd(&sumF[slot * DIM + col], s);
            atomicAdd(&sqF[slot * DIM + col], q);
        }
    }
}

// ---------------------------------------------------------------------------
// final BN + ReLU with fused finalize
// ---------------------------------------------------------------------------
__global__ __launch_bounds__(256) void bnrelu_kernel(
    float* __restrict__ out,
    const float* __restrict__ sumF, const float* __restrict__ sqF,
    const float* __restrict__ bng, const float* __restrict__ bnb)
{
    __shared__ float scl[DIM], shl[DIM];
    bn_finalize(sumF, sqF, bng, bnb, scl, shl, threadIdx.x);
    __syncthreads();
    int idx = blockIdx.x * blockDim.x + threadIdx.x;
    const int total = N_NODES * (DIM / 4);
    for (int f = idx; f < total; f += gridDim.x * blockDim.x) {
        float4 v = ((float4*)out)[f];
        int c = (f * 4) & (DIM - 1);
        float4 sc = *(const float4*)(scl + c);
        float4 sh = *(const float4*)(shl + c);
        v.x = fmaxf(v.x * sc.x + sh.x, 0.0f);
        v.y = fmaxf(v.y * sc.y + sh.y, 0.0f);
        v.z = fmaxf(v.z * sc.z + sh.z, 0.0f);
        v.w = fmaxf(v.w * sc.w + sh.w, 0.0f);
        ((float4*)out)[f] = v;
    }
}

extern "C" void kernel_launch(void* const* d_in, const int* in_sizes, int n_in,
                              void* d_out, int out_size, void* d_ws, size_t ws_size,
                              hipStream_t stream)
{
    const float* x    = (const float*)d_in[0];
    const int*   ei   = (const int*)  d_in[1];
    const float* ea   = (const float*)d_in[2];
    const int*   vi   = (const int*)  d_in[3];
    const float* vea  = (const float*)d_in[4];
    const float* epsd = (const float*)d_in[5];
    const float* W1d  = (const float*)d_in[6];
    const float* b1d  = (const float*)d_in[7];
    const float* g1d  = (const float*)d_in[8];
    const float* bt1d = (const float*)d_in[9];
    const float* W2d  = (const float*)d_in[10];
    const float* b2d  = (const float*)d_in[11];
    const float* epsu = (const float*)d_in[12];
    const float* W1u  = (const float*)d_in[13];
    const float* b1u  = (const float*)d_in[14];
    const float* g1u  = (const float*)d_in[15];
    const float* bt1u = (const float*)d_in[16];
    const float* W2u  = (const float*)d_in[17];
    const float* b2u  = (const float*)d_in[18];
    const float* bng  = (const float*)d_in[19];
    const float* bnb  = (const float*)d_in[20];
    const float* a1   = (const float*)d_in[21];
    const float* a2   = (const float*)d_in[22];

    float* out = (float*)d_out;

    // ---- workspace layout ----
    char* p = (char*)d_ws;
    unsigned short* hD  = (unsigned short*)p;  p += (size_t)N_NODES * DIM * 2;
    unsigned short* hU  = (unsigned short*)p;  p += (size_t)N_NODES * DIM * 2;
    unsigned short* t1D = (unsigned short*)p;  p += (size_t)N_NODES * DIM * 2;
    unsigned short* t1U = (unsigned short*)p;  p += (size_t)N_NODES * DIM * 2;
    unsigned short* xb  = (unsigned short*)p;  p += (size_t)N_NODES * DIM * 2;
    unsigned short* Wt  = (unsigned short*)p;  p += (size_t)4 * DIM * DIM * 2;
    // zeroed region: stats (6 slices) + offsets
    char* zero_base = p;
    float* stats = (float*)p;                  p += (size_t)6 * NSLOT * DIM * 4;
    int* offD = (int*)p;                       p += (size_t)(N_NODES + 1) * 4;
    int* offU = (int*)p;                       p += (size_t)(N_NODES + 1) * 4;
    size_t zero_bytes = (size_t)(p - zero_base);
    int* curD = (int*)p;                       p += (size_t)N_NODES * 4;
    int* curU = (int*)p;                       p += (size_t)N_NODES * 4;
    char* union_base = p;
    int2* pairsD = (int2*)p;                   p += (size_t)NE * 8;
    int2* pairsU = (int2*)p;                   p += (size_t)NEV * 8;
    size_t need_csr = (size_t)(p - (char*)d_ws);
    float* aggr = (float*)union_base;          // fallback-only, overlaps pairs
    size_t need_fb = (size_t)(union_base - (char*)d_ws) + (size_t)N_NODES * DIM * 4;
    bool use_csr = ws_size >= need_csr;

    float* sumD = stats;
    float* sqD  = stats + 1 * NSLOT * DIM;
    float* sumU = stats + 2 * NSLOT * DIM;
    float* sqU  = stats + 3 * NSLOT * DIM;
    float* sumF = stats + 4 * NSLOT * DIM;
    float* sqF  = stats + 5 * NSLOT * DIM;

    unsigned short* Wt1d = Wt;
    unsigned short* Wt2d = Wt + 1 * (size_t)DIM * DIM;
    unsigned short* Wt1u = Wt + 2 * (size_t)DIM * DIM;
    unsigned short* Wt2u = Wt + 3 * (size_t)DIM * DIM;

    hipMemsetAsync(zero_base, 0, zero_bytes, stream);

    if (use_csr) {
        prep_kernel<<<PREP_W_BLOCKS + PREP_X_BLOCKS + HIST_BLOCKS, 256, 0, stream>>>(
            W1d, W2d, W1u, W2u, Wt, x, xb, ei, vi, offD, offU);
        scan2_kernel<<<2, 1024, 0, stream>>>(offD, curD, offU, curU);
        fill2_kernel<<<(NE + NEV + 255) / 256, 256, 0, stream>>>(
            ei, vi, curD, curU, pairsD, pairsU);
        gather2_kernel<<<N_NODES, 256, 0, stream>>>(
            xb, ea, vea, offD, pairsD, offU, pairsU, epsd, epsu, hD, hU);
    } else if (ws_size >= need_fb) {
        prep_kernel<<<PREP_W_BLOCKS + PREP_X_BLOCKS, 256, 0, stream>>>(
            W1d, W2d, W1u, W2u, Wt, x, xb, ei, vi, offD, offU);
        hipMemsetAsync(aggr, 0, (size_t)N_NODES * DIM * 4, stream);
        scatter_kernel<<<(NE + 3) / 4, 256, 0, stream>>>(x, ea, ei, NE, aggr);
        conv_kernel<<<2048, 256, 0, stream>>>(x, aggr, epsd, hD);
        hipMemsetAsync(aggr, 0, (size_t)N_NODES * DIM * 4, stream);
        scatter_kernel<<<(NEV + 3) / 4, 256, 0, stream>>>(x, vea, vi, NEV, aggr);
        conv_kernel<<<2048, 256, 0, stream>>>(x, aggr, epsu, hU);
    }

    gemm1_both<<<2 * GRID_PER, 256, 0, stream>>>(
        hD, hU, Wt1d, Wt1u, b1d, b1u, t1D, t1U, sumD, sqD, sumU, sqU);

    gemm2_fused<<<GRID_PER, 256, 0, stream>>>(
        t1D, t1U, sumD, sqD, g1d, bt1d, sumU, sqU, g1u, bt1u,
        Wt2d, Wt2u, b2d, b2u, a1, a2, x, out, sumF, sqF);

    bnrelu_kernel<<<2048, 256, 0, stream>>>(out, sumF, sqF, bng, bnb);
}